// Round 1
// baseline (1571.528 us; speedup 1.0000x reference)
//
#include <hip/hip_runtime.h>
#include <hip/hip_bf16.h>
#include <math.h>

// Problem constants
#define TOK  4096      // B*T = 2*2048
#define DM   1024      // d_model
#define DKC  1024      // DK total
#define DVC  2048      // DV total
#define NH   4         // heads
#define HDK_ 256
#define HDV_ 512
#define NCH  32        // chunks per (b,h)  (2048/64)
#define CHK  64

// ---------------------------------------------------------------------------
// Generic f32 GEMM  C[M,N] = A[M,K] @ B[K,N], tiles 128x128x16, 256 thr, 8x8/thr
// ---------------------------------------------------------------------------
__global__ __launch_bounds__(256) void gemm_f32(const float* __restrict__ A,
                                                const float* __restrict__ B,
                                                float* __restrict__ C,
                                                int M, int N, int K) {
    __shared__ float As[16][132];   // [k][m]  (transposed for b128 reads)
    __shared__ float Bs[16][132];   // [k][n]
    const int tid = threadIdx.x;
    const int tx = tid & 15, ty = tid >> 4;
    const int m0 = blockIdx.y * 128, n0 = blockIdx.x * 128;
    float acc[8][8];
#pragma unroll
    for (int i = 0; i < 8; ++i)
#pragma unroll
        for (int j = 0; j < 8; ++j) acc[i][j] = 0.f;

    for (int k0 = 0; k0 < K; k0 += 16) {
#pragma unroll
        for (int p = 0; p < 2; ++p) {            // A tile 128x16
            int idx = tid + p * 256;             // float4 id 0..511
            int r = idx >> 2;
            int kq = (idx & 3) << 2;
            float4 av = *reinterpret_cast<const float4*>(&A[(size_t)(m0 + r) * K + k0 + kq]);
            As[kq + 0][r] = av.x;
            As[kq + 1][r] = av.y;
            As[kq + 2][r] = av.z;
            As[kq + 3][r] = av.w;
        }
#pragma unroll
        for (int p = 0; p < 2; ++p) {            // B tile 16x128
            int idx = tid + p * 256;
            int r = idx >> 5;
            int cq = (idx & 31) << 2;
            *reinterpret_cast<float4*>(&Bs[r][cq]) =
                *reinterpret_cast<const float4*>(&B[(size_t)(k0 + r) * N + n0 + cq]);
        }
        __syncthreads();
#pragma unroll
        for (int kk = 0; kk < 16; ++kk) {
            float a[8], b[8];
            *reinterpret_cast<float4*>(&a[0]) = *reinterpret_cast<const float4*>(&As[kk][ty * 8]);
            *reinterpret_cast<float4*>(&a[4]) = *reinterpret_cast<const float4*>(&As[kk][ty * 8 + 4]);
            *reinterpret_cast<float4*>(&b[0]) = *reinterpret_cast<const float4*>(&Bs[kk][tx * 8]);
            *reinterpret_cast<float4*>(&b[4]) = *reinterpret_cast<const float4*>(&Bs[kk][tx * 8 + 4]);
#pragma unroll
            for (int i = 0; i < 8; ++i)
#pragma unroll
                for (int j = 0; j < 8; ++j) acc[i][j] = fmaf(a[i], b[j], acc[i][j]);
        }
        __syncthreads();
    }
#pragma unroll
    for (int i = 0; i < 8; ++i) {
        size_t row = (size_t)(m0 + ty * 8 + i) * N + n0 + tx * 8;
        *reinterpret_cast<float4*>(&C[row])     = make_float4(acc[i][0], acc[i][1], acc[i][2], acc[i][3]);
        *reinterpret_cast<float4*>(&C[row + 4]) = make_float4(acc[i][4], acc[i][5], acc[i][6], acc[i][7]);
    }
}

// ---------------------------------------------------------------------------
// t1 = x @ Wgk1   [4096,1024]@[1024,16]
// ---------------------------------------------------------------------------
__global__ __launch_bounds__(256) void lowrank1(const float* __restrict__ x,
                                                const float* __restrict__ W1,
                                                float* __restrict__ t1) {
    __shared__ float red[16][17];
    const int t = blockIdx.x;
    const int tid = threadIdx.x;
    const int o = tid & 15;        // output col
    const int p = tid >> 4;        // k-part (64 elems)
    float s = 0.f;
#pragma unroll 8
    for (int m = 0; m < 64; ++m) {
        int kk = p * 64 + m;
        s += x[(size_t)t * DM + kk] * W1[kk * 16 + o];
    }
    red[p][o] = s;
    __syncthreads();
    if (tid < 16) {
        float tot = 0.f;
#pragma unroll
        for (int pp = 0; pp < 16; ++pp) tot += red[pp][tid];
        t1[(size_t)t * 16 + tid] = tot;
    }
}

// ---------------------------------------------------------------------------
// g = log_sigmoid(t1 @ Wgk2 + b) / 16     [4096,1024]
// ---------------------------------------------------------------------------
__global__ __launch_bounds__(256) void gate_k(const float* __restrict__ t1,
                                              const float* __restrict__ W2,
                                              const float* __restrict__ b2,
                                              float* __restrict__ g) {
    const size_t idx = (size_t)blockIdx.x * 256 + threadIdx.x;
    const int t = (int)(idx >> 10), c = (int)(idx & 1023);
    float acc = b2[c];
#pragma unroll
    for (int r = 0; r < 16; ++r) acc += t1[(size_t)t * 16 + r] * W2[r * 1024 + c];
    float ls = fminf(acc, 0.f) - log1pf(expf(-fabsf(acc)));
    g[idx] = ls * (1.f / 16.f);
}

// ---------------------------------------------------------------------------
// Chunk-parallel GLA precompute: per (chunk, b, h):
//   bb = cumsum(g), dlast = exp(bb[63]), qg, kg to global,
//   A = tril(qg @ kd^T), o_intra = A @ vb  -> o
// ---------------------------------------------------------------------------
__global__ __launch_bounds__(256) void gla_chunk(const float* __restrict__ q,
                                                 const float* __restrict__ k,
                                                 const float* __restrict__ v,
                                                 const float* __restrict__ g,
                                                 float* __restrict__ qg,
                                                 float* __restrict__ kg,
                                                 float* __restrict__ o,
                                                 float* __restrict__ dlast) {
    __shared__ float bb[64][257];
    __shared__ float qt[64][65];   // [dd][i]
    __shared__ float kt[64][65];   // [dd][s]
    __shared__ float Am[64][68];   // A[t][s]
    __shared__ float vt[64][68];   // [s][c]
    const int chunk = blockIdx.x, bh = blockIdx.y;
    const int b = bh >> 2, h = bh & 3;
    const int t0 = b * 2048 + chunk * 64;
    const int tid = threadIdx.x;
    const float scale = 0.0625f;   // 256^-0.5

    // step 1: per-column cumsum + qg/kg global writes (thread = column d)
    {
        const int d = tid;
        float run = 0.f;
        for (int i = 0; i < 64; ++i) {
            run += g[(size_t)(t0 + i) * DKC + h * HDK_ + d];
            bb[i][d] = run;
        }
        dlast[((size_t)bh * NCH + chunk) * HDK_ + d] = expf(run);
        const float bl = run;
        for (int i = 0; i < 64; ++i) {
            float bv = bb[i][d];
            size_t gi = (size_t)(t0 + i) * DKC + h * HDK_ + d;
            qg[gi] = q[gi] * expf(bv) * scale;
            kg[gi] = k[gi] * expf(bl - bv);
        }
    }
    __syncthreads();

    // step 2: A = tril(qg @ kd^T), K-tiled by 64
    const int tx = tid & 15, ty = tid >> 4;
    float accA[4][4];
#pragma unroll
    for (int i = 0; i < 4; ++i)
#pragma unroll
        for (int j = 0; j < 4; ++j) accA[i][j] = 0.f;

    for (int d0 = 0; d0 < HDK_; d0 += 64) {
#pragma unroll
        for (int p = 0; p < 16; ++p) {
            int idx = tid + p * 256;
            int dd = idx & 63, i = idx >> 6;
            float bv = bb[i][d0 + dd];
            size_t gi = (size_t)(t0 + i) * DKC + h * HDK_ + d0 + dd;
            qt[dd][i] = q[gi] * expf(bv) * scale;
            kt[dd][i] = k[gi] * expf(-bv);
        }
        __syncthreads();
        for (int dd = 0; dd < 64; ++dd) {
            float a[4], c[4];
#pragma unroll
            for (int i = 0; i < 4; ++i) a[i] = qt[dd][ty * 4 + i];
#pragma unroll
            for (int j = 0; j < 4; ++j) c[j] = kt[dd][tx * 4 + j];
#pragma unroll
            for (int i = 0; i < 4; ++i)
#pragma unroll
                for (int j = 0; j < 4; ++j) accA[i][j] = fmaf(a[i], c[j], accA[i][j]);
        }
        __syncthreads();
    }
#pragma unroll
    for (int i = 0; i < 4; ++i)
#pragma unroll
        for (int j = 0; j < 4; ++j)
            Am[ty * 4 + i][tx * 4 + j] = (ty * 4 + i >= tx * 4 + j) ? accA[i][j] : 0.f;
    __syncthreads();

    // step 3: o_intra = A @ vb, 64-col chunks of the 512 v-cols
    for (int cb = 0; cb < 8; ++cb) {
#pragma unroll
        for (int p = 0; p < 16; ++p) {
            int idx = tid + p * 256;
            int c = idx & 63, s = idx >> 6;
            vt[s][c] = v[(size_t)(t0 + s) * DVC + h * HDV_ + cb * 64 + c];
        }
        __syncthreads();
        float accO[4][4];
#pragma unroll
        for (int i = 0; i < 4; ++i)
#pragma unroll
            for (int j = 0; j < 4; ++j) accO[i][j] = 0.f;
        for (int s = 0; s < 64; ++s) {
            float a[4], c[4];
#pragma unroll
            for (int i = 0; i < 4; ++i) a[i] = Am[ty * 4 + i][s];
#pragma unroll
            for (int j = 0; j < 4; ++j) c[j] = vt[s][tx * 4 + j];
#pragma unroll
            for (int i = 0; i < 4; ++i)
#pragma unroll
                for (int j = 0; j < 4; ++j) accO[i][j] = fmaf(a[i], c[j], accO[i][j]);
        }
#pragma unroll
        for (int i = 0; i < 4; ++i) {
            *reinterpret_cast<float4*>(
                &o[(size_t)(t0 + ty * 4 + i) * DVC + h * HDV_ + cb * 64 + tx * 4]) =
                make_float4(accO[i][0], accO[i][1], accO[i][2], accO[i][3]);
        }
        __syncthreads();
    }
}

// ---------------------------------------------------------------------------
// Sequential chunk scan: per (b,h,v-slice of 32): S in LDS, 32 chunks
//   o += qg @ S ; S = S*exp(b_last) + kg^T @ vb
// ---------------------------------------------------------------------------
__global__ __launch_bounds__(256) void gla_scan(const float* __restrict__ qg,
                                                const float* __restrict__ kg,
                                                const float* __restrict__ v,
                                                const float* __restrict__ dlast,
                                                float* __restrict__ o) {
    __shared__ float S[256][36];
    __shared__ float qk[64][257];
    __shared__ float vb[64][36];
    const int vs = blockIdx.x;     // 0..15
    const int bh = blockIdx.y;     // 0..7
    const int b = bh >> 2, h = bh & 3;
    const int tid = threadIdx.x;

#pragma unroll
    for (int c = 0; c < 36; ++c) S[tid][c] = 0.f;

    for (int cc = 0; cc < NCH; ++cc) {
        const int t0 = b * 2048 + cc * 64;
        // stage qg chunk [64][256]
#pragma unroll
        for (int p = 0; p < 16; ++p) {
            int idx = tid + p * 256;           // float4 id
            int dq = (idx & 63) << 2;
            int i = idx >> 6;
            float4 val = *reinterpret_cast<const float4*>(&qg[(size_t)(t0 + i) * DKC + h * HDK_ + dq]);
            qk[i][dq] = val.x; qk[i][dq + 1] = val.y; qk[i][dq + 2] = val.z; qk[i][dq + 3] = val.w;
        }
        // stage vb slice [64][32]
#pragma unroll
        for (int p = 0; p < 2; ++p) {
            int idx = tid + p * 256;           // float4 id 0..511
            int cq = (idx & 7) << 2;
            int i = idx >> 3;
            float4 val = *reinterpret_cast<const float4*>(&v[(size_t)(t0 + i) * DVC + h * HDV_ + vs * 32 + cq]);
            *reinterpret_cast<float4*>(&vb[i][cq]) = val;
        }
        __syncthreads();
        // phase 1: o += qg @ S
        {
            const int r = tid >> 2;
            const int cg = (tid & 3) * 8;
            float acc[8];
#pragma unroll
            for (int j = 0; j < 8; ++j) acc[j] = 0.f;
            for (int kk = 0; kk < 256; ++kk) {
                float qv = qk[r][kk];
#pragma unroll
                for (int j = 0; j < 8; ++j) acc[j] = fmaf(qv, S[kk][cg + j], acc[j]);
            }
            size_t oi = (size_t)(t0 + r) * DVC + h * HDV_ + vs * 32 + cg;
            float4 o0 = *reinterpret_cast<const float4*>(&o[oi]);
            float4 o1 = *reinterpret_cast<const float4*>(&o[oi + 4]);
            o0.x += acc[0]; o0.y += acc[1]; o0.z += acc[2]; o0.w += acc[3];
            o1.x += acc[4]; o1.y += acc[5]; o1.z += acc[6]; o1.w += acc[7];
            *reinterpret_cast<float4*>(&o[oi]) = o0;
            *reinterpret_cast<float4*>(&o[oi + 4]) = o1;
        }
        __syncthreads();
        // stage kg chunk into same buffer
#pragma unroll
        for (int p = 0; p < 16; ++p) {
            int idx = tid + p * 256;
            int dq = (idx & 63) << 2;
            int i = idx >> 6;
            float4 val = *reinterpret_cast<const float4*>(&kg[(size_t)(t0 + i) * DKC + h * HDK_ + dq]);
            qk[i][dq] = val.x; qk[i][dq + 1] = val.y; qk[i][dq + 2] = val.z; qk[i][dq + 3] = val.w;
        }
        __syncthreads();
        // phase 2: S = S*exp(b_last) + kg^T @ vb   (thread = k-dim d)
        {
            const int d = tid;
            const float ebl = dlast[((size_t)bh * NCH + cc) * HDK_ + d];
            float acc[32];
#pragma unroll
            for (int c = 0; c < 32; ++c) acc[c] = 0.f;
            for (int i = 0; i < 64; ++i) {
                float kv = qk[i][d];
#pragma unroll
                for (int c = 0; c < 32; ++c) acc[c] = fmaf(kv, vb[i][c], acc[c]);
            }
#pragma unroll
            for (int c = 0; c < 32; ++c) S[d][c] = S[d][c] * ebl + acc[c];
        }
        __syncthreads();
    }
}

// ---------------------------------------------------------------------------
// RMSNorm (per token,head over 512) * rms_w * silu(xg)  -> gated
// ---------------------------------------------------------------------------
__global__ __launch_bounds__(256) void rms_gate(const float* __restrict__ o,
                                                const float* __restrict__ xg,
                                                const float* __restrict__ rms_w,
                                                float* __restrict__ gated) {
    __shared__ float wsum[4];
    const int th = blockIdx.x;     // t*4 + h
    const int t = th >> 2, h = th & 3;
    const int tid = threadIdx.x;
    const size_t base = (size_t)t * DVC + h * HDV_;
    float v0 = o[base + tid], v1 = o[base + 256 + tid];
    float s = v0 * v0 + v1 * v1;
#pragma unroll
    for (int off = 32; off >= 1; off >>= 1) s += __shfl_down(s, off, 64);
    if ((tid & 63) == 0) wsum[tid >> 6] = s;
    __syncthreads();
    float tot = wsum[0] + wsum[1] + wsum[2] + wsum[3];
    float rms = rsqrtf(tot * (1.f / 512.f) + 1e-5f);
    float g0 = xg[base + tid], g1 = xg[base + 256 + tid];
    float s0 = g0 / (1.f + expf(-g0));
    float s1 = g1 / (1.f + expf(-g1));
    gated[base + tid]       = v0 * rms * rms_w[tid] * s0;
    gated[base + 256 + tid] = v1 * rms * rms_w[256 + tid] * s1;
}

// ---------------------------------------------------------------------------
extern "C" void kernel_launch(void* const* d_in, const int* in_sizes, int n_in,
                              void* d_out, int out_size, void* d_ws, size_t ws_size,
                              hipStream_t stream) {
    const float* x    = (const float*)d_in[0];
    const float* Wq   = (const float*)d_in[1];
    const float* Wk   = (const float*)d_in[2];
    const float* Wv   = (const float*)d_in[3];
    const float* Wg   = (const float*)d_in[4];
    const float* Wgk1 = (const float*)d_in[5];
    const float* Wgk2 = (const float*)d_in[6];
    const float* bgk2 = (const float*)d_in[7];
    const float* Wo   = (const float*)d_in[8];
    const float* rmsw = (const float*)d_in[9];
    float* out = (float*)d_out;
    float* ws = (float*)d_ws;

    const size_t M4 = 4ull << 20;   // 4096*1024 floats
    float* q     = ws;              // 4M
    float* kbuf  = ws + M4;         // 4M
    float* v     = ws + 2 * M4;     // 8M
    float* xg    = ws + 4 * M4;     // 8M
    float* g     = ws + 6 * M4;     // 4M
    float* qg    = ws + 7 * M4;     // 4M
    float* kg    = ws + 8 * M4;     // 4M
    float* o     = ws + 9 * M4;     // 8M
    float* t1    = ws + 11 * M4;            // 65536
    float* dlast = ws + 11 * M4 + 65536;    // 65536
    float* gated = ws;              // reuse q+k (dead after gla_chunk)

    gemm_f32<<<dim3(DKC / 128, TOK / 128), 256, 0, stream>>>(x, Wq, q,    TOK, DKC, DM);
    gemm_f32<<<dim3(DKC / 128, TOK / 128), 256, 0, stream>>>(x, Wk, kbuf, TOK, DKC, DM);
    gemm_f32<<<dim3(DVC / 128, TOK / 128), 256, 0, stream>>>(x, Wv, v,    TOK, DVC, DM);
    gemm_f32<<<dim3(DVC / 128, TOK / 128), 256, 0, stream>>>(x, Wg, xg,   TOK, DVC, DM);
    lowrank1<<<TOK, 256, 0, stream>>>(x, Wgk1, t1);
    gate_k<<<(TOK * DKC) / 256, 256, 0, stream>>>(t1, Wgk2, bgk2, g);
    gla_chunk<<<dim3(NCH, 8), 256, 0, stream>>>(q, kbuf, v, g, qg, kg, o, dlast);
    gla_scan<<<dim3(16, 8), 256, 0, stream>>>(qg, kg, v, dlast, o);
    rms_gate<<<TOK * NH, 256, 0, stream>>>(o, xg, rmsw, gated);
    gemm_f32<<<dim3(DM / 128, TOK / 128), 256, 0, stream>>>(gated, Wo, out, TOK, DM, DVC);
}

// Round 2
// 638.143 us; speedup vs baseline: 2.4627x; 2.4627x over previous
//
#include <hip/hip_runtime.h>
#include <hip/hip_bf16.h>
#include <math.h>

#define TOK  4096
#define DM   1024
#define DKC  1024
#define DVC  2048
#define NH   4
#define HDK_ 256
#define HDV_ 512
#define NCH  32
#define CHK  64

typedef __attribute__((ext_vector_type(8))) short bf16x8;
typedef __attribute__((ext_vector_type(4))) float f32x4;

__device__ inline float bf2f(short s) {
    unsigned int b = ((unsigned int)(unsigned short)s) << 16;
    return __uint_as_float(b);
}

// ---------------------------------------------------------------------------
// f32 GEMM (kept for the final Wo projection)  C[M,N] = A[M,K] @ B[K,N]
// ---------------------------------------------------------------------------
__global__ __launch_bounds__(256) void gemm_f32(const float* __restrict__ A,
                                                const float* __restrict__ B,
                                                float* __restrict__ C,
                                                int M, int N, int K) {
    __shared__ float As[16][132];
    __shared__ float Bs[16][132];
    const int tid = threadIdx.x;
    const int tx = tid & 15, ty = tid >> 4;
    const int m0 = blockIdx.y * 128, n0 = blockIdx.x * 128;
    float acc[8][8];
#pragma unroll
    for (int i = 0; i < 8; ++i)
#pragma unroll
        for (int j = 0; j < 8; ++j) acc[i][j] = 0.f;

    for (int k0 = 0; k0 < K; k0 += 16) {
#pragma unroll
        for (int p = 0; p < 2; ++p) {
            int idx = tid + p * 256;
            int r = idx >> 2;
            int kq = (idx & 3) << 2;
            float4 av = *reinterpret_cast<const float4*>(&A[(size_t)(m0 + r) * K + k0 + kq]);
            As[kq + 0][r] = av.x;
            As[kq + 1][r] = av.y;
            As[kq + 2][r] = av.z;
            As[kq + 3][r] = av.w;
        }
#pragma unroll
        for (int p = 0; p < 2; ++p) {
            int idx = tid + p * 256;
            int r = idx >> 5;
            int cq = (idx & 31) << 2;
            *reinterpret_cast<float4*>(&Bs[r][cq]) =
                *reinterpret_cast<const float4*>(&B[(size_t)(k0 + r) * N + n0 + cq]);
        }
        __syncthreads();
#pragma unroll
        for (int kk = 0; kk < 16; ++kk) {
            float a[8], b[8];
            *reinterpret_cast<float4*>(&a[0]) = *reinterpret_cast<const float4*>(&As[kk][ty * 8]);
            *reinterpret_cast<float4*>(&a[4]) = *reinterpret_cast<const float4*>(&As[kk][ty * 8 + 4]);
            *reinterpret_cast<float4*>(&b[0]) = *reinterpret_cast<const float4*>(&Bs[kk][tx * 8]);
            *reinterpret_cast<float4*>(&b[4]) = *reinterpret_cast<const float4*>(&Bs[kk][tx * 8 + 4]);
#pragma unroll
            for (int i = 0; i < 8; ++i)
#pragma unroll
                for (int j = 0; j < 8; ++j) acc[i][j] = fmaf(a[i], b[j], acc[i][j]);
        }
        __syncthreads();
    }
#pragma unroll
    for (int i = 0; i < 8; ++i) {
        size_t row = (size_t)(m0 + ty * 8 + i) * N + n0 + tx * 8;
        *reinterpret_cast<float4*>(&C[row])     = make_float4(acc[i][0], acc[i][1], acc[i][2], acc[i][3]);
        *reinterpret_cast<float4*>(&C[row + 4]) = make_float4(acc[i][4], acc[i][5], acc[i][6], acc[i][7]);
    }
}

// ---------------------------------------------------------------------------
// x (f32) -> bf16 copy
// ---------------------------------------------------------------------------
__global__ __launch_bounds__(256) void conv_bf16(const float* __restrict__ in,
                                                 __hip_bfloat16* __restrict__ out) {
    size_t i = ((size_t)blockIdx.x * 256 + threadIdx.x) * 4;
    float4 v = *reinterpret_cast<const float4*>(&in[i]);
    out[i + 0] = __float2bfloat16(v.x);
    out[i + 1] = __float2bfloat16(v.y);
    out[i + 2] = __float2bfloat16(v.z);
    out[i + 3] = __float2bfloat16(v.w);
}

// ---------------------------------------------------------------------------
// W[K][N] f32 -> Wt[N][K] bf16 (tiled transpose)
// ---------------------------------------------------------------------------
__global__ __launch_bounds__(256) void convT(const float* __restrict__ W,
                                             __hip_bfloat16* __restrict__ Wt,
                                             int K, int N) {
    __shared__ float tile[32][33];
    int n0 = blockIdx.x * 32, k0 = blockIdx.y * 32;
    int tx = threadIdx.x & 31, ty = threadIdx.x >> 5;
#pragma unroll
    for (int i = 0; i < 32; i += 8)
        tile[ty + i][tx] = W[(size_t)(k0 + ty + i) * N + n0 + tx];
    __syncthreads();
#pragma unroll
    for (int i = 0; i < 32; i += 8)
        Wt[(size_t)(n0 + ty + i) * K + k0 + tx] = __float2bfloat16(tile[tx][ty + i]);
}

// ---------------------------------------------------------------------------
// bf16 MFMA GEMM: C[M,N] f32 = A[M,K]bf16 @ Wt[N,K]bf16^T
// 128x128 tile, BK=64, 4 waves (2x2), each wave 64x64 via 4x4 frags 16x16x32
// ---------------------------------------------------------------------------
__global__ __launch_bounds__(256) void gemm_bf16(const __hip_bfloat16* __restrict__ A,
                                                 const __hip_bfloat16* __restrict__ Wt,
                                                 float* __restrict__ C,
                                                 int M, int N, int K) {
    __shared__ short Al[128][72];   // +8 pad: stride 36 dwords -> conflict-free frag reads
    __shared__ short Bl[128][72];
    const int tid = threadIdx.x;
    const int wave = tid >> 6, lane = tid & 63;
    const int wr = wave >> 1, wc = wave & 1;
    const int m0 = blockIdx.y * 128, n0 = blockIdx.x * 128;
    const int l15 = lane & 15, kb = lane >> 4;
    f32x4 acc[4][4];
#pragma unroll
    for (int mf = 0; mf < 4; ++mf)
#pragma unroll
        for (int nf = 0; nf < 4; ++nf) acc[mf][nf] = (f32x4){0.f, 0.f, 0.f, 0.f};

    for (int k0 = 0; k0 < K; k0 += 64) {
#pragma unroll
        for (int i = 0; i < 4; ++i) {      // 1024 segs of 8 bf16 per matrix
            int idx = tid + i * 256;
            int r = idx >> 3, seg = (idx & 7) * 8;
            *reinterpret_cast<bf16x8*>(&Al[r][seg]) =
                *reinterpret_cast<const bf16x8*>(&A[(size_t)(m0 + r) * K + k0 + seg]);
            *reinterpret_cast<bf16x8*>(&Bl[r][seg]) =
                *reinterpret_cast<const bf16x8*>(&Wt[(size_t)(n0 + r) * K + k0 + seg]);
        }
        __syncthreads();
#pragma unroll
        for (int kk = 0; kk < 2; ++kk) {
            bf16x8 af[4], bfr[4];
#pragma unroll
            for (int mf = 0; mf < 4; ++mf)
                af[mf] = *reinterpret_cast<const bf16x8*>(&Al[wr * 64 + mf * 16 + l15][kk * 32 + kb * 8]);
#pragma unroll
            for (int nf = 0; nf < 4; ++nf)
                bfr[nf] = *reinterpret_cast<const bf16x8*>(&Bl[wc * 64 + nf * 16 + l15][kk * 32 + kb * 8]);
#pragma unroll
            for (int mf = 0; mf < 4; ++mf)
#pragma unroll
                for (int nf = 0; nf < 4; ++nf)
                    acc[mf][nf] = __builtin_amdgcn_mfma_f32_16x16x32_bf16(af[mf], bfr[nf], acc[mf][nf], 0, 0, 0);
        }
        __syncthreads();
    }
#pragma unroll
    for (int mf = 0; mf < 4; ++mf)
#pragma unroll
        for (int nf = 0; nf < 4; ++nf)
#pragma unroll
            for (int r = 0; r < 4; ++r)
                C[(size_t)(m0 + wr * 64 + mf * 16 + kb * 4 + r) * N + n0 + wc * 64 + nf * 16 + l15] =
                    acc[mf][nf][r];
}

// ---------------------------------------------------------------------------
// t1 = x @ Wgk1
// ---------------------------------------------------------------------------
__global__ __launch_bounds__(256) void lowrank1(const float* __restrict__ x,
                                                const float* __restrict__ W1,
                                                float* __restrict__ t1) {
    __shared__ float red[16][17];
    const int t = blockIdx.x;
    const int tid = threadIdx.x;
    const int o = tid & 15;
    const int p = tid >> 4;
    float s = 0.f;
#pragma unroll 8
    for (int m = 0; m < 64; ++m) {
        int kk = p * 64 + m;
        s += x[(size_t)t * DM + kk] * W1[kk * 16 + o];
    }
    red[p][o] = s;
    __syncthreads();
    if (tid < 16) {
        float tot = 0.f;
#pragma unroll
        for (int pp = 0; pp < 16; ++pp) tot += red[pp][tid];
        t1[(size_t)t * 16 + tid] = tot;
    }
}

// ---------------------------------------------------------------------------
// g = log_sigmoid(t1 @ Wgk2 + b) / 16
// ---------------------------------------------------------------------------
__global__ __launch_bounds__(256) void gate_k(const float* __restrict__ t1,
                                              const float* __restrict__ W2,
                                              const float* __restrict__ b2,
                                              float* __restrict__ g) {
    const size_t idx = (size_t)blockIdx.x * 256 + threadIdx.x;
    const int t = (int)(idx >> 10), c = (int)(idx & 1023);
    float acc = b2[c];
#pragma unroll
    for (int r = 0; r < 16; ++r) acc += t1[(size_t)t * 16 + r] * W2[r * 1024 + c];
    float ls = fminf(acc, 0.f) - log1pf(expf(-fabsf(acc)));
    g[idx] = ls * (1.f / 16.f);
}

// ---------------------------------------------------------------------------
// Chunk-parallel GLA precompute (unchanged from R0)
// ---------------------------------------------------------------------------
__global__ __launch_bounds__(256) void gla_chunk(const float* __restrict__ q,
                                                 const float* __restrict__ k,
                                                 const float* __restrict__ v,
                                                 const float* __restrict__ g,
                                                 float* __restrict__ qg,
                                                 float* __restrict__ kg,
                                                 float* __restrict__ o,
                                                 float* __restrict__ dlast) {
    __shared__ float bb[64][257];
    __shared__ float qt[64][65];
    __shared__ float kt[64][65];
    __shared__ float Am[64][68];
    __shared__ float vt[64][68];
    const int chunk = blockIdx.x, bh = blockIdx.y;
    const int b = bh >> 2, h = bh & 3;
    const int t0 = b * 2048 + chunk * 64;
    const int tid = threadIdx.x;
    const float scale = 0.0625f;

    {
        const int d = tid;
        float run = 0.f;
        for (int i = 0; i < 64; ++i) {
            run += g[(size_t)(t0 + i) * DKC + h * HDK_ + d];
            bb[i][d] = run;
        }
        dlast[((size_t)bh * NCH + chunk) * HDK_ + d] = expf(run);
        const float bl = run;
        for (int i = 0; i < 64; ++i) {
            float bv = bb[i][d];
            size_t gi = (size_t)(t0 + i) * DKC + h * HDK_ + d;
            qg[gi] = q[gi] * expf(bv) * scale;
            kg[gi] = k[gi] * expf(bl - bv);
        }
    }
    __syncthreads();

    const int tx = tid & 15, ty = tid >> 4;
    float accA[4][4];
#pragma unroll
    for (int i = 0; i < 4; ++i)
#pragma unroll
        for (int j = 0; j < 4; ++j) accA[i][j] = 0.f;

    for (int d0 = 0; d0 < HDK_; d0 += 64) {
#pragma unroll
        for (int p = 0; p < 16; ++p) {
            int idx = tid + p * 256;
            int dd = idx & 63, i = idx >> 6;
            float bv = bb[i][d0 + dd];
            size_t gi = (size_t)(t0 + i) * DKC + h * HDK_ + d0 + dd;
            qt[dd][i] = q[gi] * expf(bv) * scale;
            kt[dd][i] = k[gi] * expf(-bv);
        }
        __syncthreads();
        for (int dd = 0; dd < 64; ++dd) {
            float a[4], c[4];
#pragma unroll
            for (int i = 0; i < 4; ++i) a[i] = qt[dd][ty * 4 + i];
#pragma unroll
            for (int j = 0; j < 4; ++j) c[j] = kt[dd][tx * 4 + j];
#pragma unroll
            for (int i = 0; i < 4; ++i)
#pragma unroll
                for (int j = 0; j < 4; ++j) accA[i][j] = fmaf(a[i], c[j], accA[i][j]);
        }
        __syncthreads();
    }
#pragma unroll
    for (int i = 0; i < 4; ++i)
#pragma unroll
        for (int j = 0; j < 4; ++j)
            Am[ty * 4 + i][tx * 4 + j] = (ty * 4 + i >= tx * 4 + j) ? accA[i][j] : 0.f;
    __syncthreads();

    for (int cb = 0; cb < 8; ++cb) {
#pragma unroll
        for (int p = 0; p < 16; ++p) {
            int idx = tid + p * 256;
            int c = idx & 63, s = idx >> 6;
            vt[s][c] = v[(size_t)(t0 + s) * DVC + h * HDV_ + cb * 64 + c];
        }
        __syncthreads();
        float accO[4][4];
#pragma unroll
        for (int i = 0; i < 4; ++i)
#pragma unroll
            for (int j = 0; j < 4; ++j) accO[i][j] = 0.f;
        for (int s = 0; s < 64; ++s) {
            float a[4], c[4];
#pragma unroll
            for (int i = 0; i < 4; ++i) a[i] = Am[ty * 4 + i][s];
#pragma unroll
            for (int j = 0; j < 4; ++j) c[j] = vt[s][tx * 4 + j];
#pragma unroll
            for (int i = 0; i < 4; ++i)
#pragma unroll
                for (int j = 0; j < 4; ++j) accO[i][j] = fmaf(a[i], c[j], accO[i][j]);
        }
#pragma unroll
        for (int i = 0; i < 4; ++i) {
            *reinterpret_cast<float4*>(
                &o[(size_t)(t0 + ty * 4 + i) * DVC + h * HDV_ + cb * 64 + tx * 4]) =
                make_float4(accO[i][0], accO[i][1], accO[i][2], accO[i][3]);
        }
        __syncthreads();
    }
}

// ---------------------------------------------------------------------------
// u_pass: U[bh][c][d][v] (bf16) = sum_t kg[t][d] * v[t][v]   (per chunk)
// grid: x = dt(4)*vt(4), y = c(32), z = bh(8); 256 thr, 4x8 acc
// ---------------------------------------------------------------------------
__global__ __launch_bounds__(256) void u_pass(const float* __restrict__ kg,
                                              const float* __restrict__ v,
                                              __hip_bfloat16* __restrict__ U) {
    __shared__ float kgs[64][68];
    __shared__ float vbs[64][132];
    const int dt = blockIdx.x >> 2, vt = blockIdx.x & 3;
    const int c = blockIdx.y, bh = blockIdx.z;
    const int b = bh >> 2, h = bh & 3;
    const int t0 = b * 2048 + c * 64;
    const int tid = threadIdx.x, tx = tid & 15, ty = tid >> 4;
#pragma unroll
    for (int i = 0; i < 4; ++i) {
        int idx = tid + i * 256;
        int t = idx >> 4, dq = (idx & 15) * 4;
        *reinterpret_cast<float4*>(&kgs[t][dq]) =
            *reinterpret_cast<const float4*>(&kg[(size_t)(t0 + t) * DKC + h * HDK_ + dt * 64 + dq]);
    }
#pragma unroll
    for (int i = 0; i < 8; ++i) {
        int idx = tid + i * 256;
        int t = idx >> 5, vq = (idx & 31) * 4;
        *reinterpret_cast<float4*>(&vbs[t][vq]) =
            *reinterpret_cast<const float4*>(&v[(size_t)(t0 + t) * DVC + h * HDV_ + vt * 128 + vq]);
    }
    __syncthreads();
    float acc[4][8];
#pragma unroll
    for (int i = 0; i < 4; ++i)
#pragma unroll
        for (int j = 0; j < 8; ++j) acc[i][j] = 0.f;
    for (int t = 0; t < 64; ++t) {
        float a[4], bv[8];
#pragma unroll
        for (int i = 0; i < 4; ++i) a[i] = kgs[t][ty * 4 + i];
        *reinterpret_cast<float4*>(&bv[0]) = *reinterpret_cast<const float4*>(&vbs[t][tx * 8]);
        *reinterpret_cast<float4*>(&bv[4]) = *reinterpret_cast<const float4*>(&vbs[t][tx * 8 + 4]);
#pragma unroll
        for (int i = 0; i < 4; ++i)
#pragma unroll
            for (int j = 0; j < 8; ++j) acc[i][j] = fmaf(a[i], bv[j], acc[i][j]);
    }
    size_t Ub = ((size_t)bh * NCH + c) * 131072;
#pragma unroll
    for (int i = 0; i < 4; ++i) {
        int d = dt * 64 + ty * 4 + i, vv = vt * 128 + tx * 8;
#pragma unroll
        for (int j = 0; j < 8; ++j)
            U[Ub + (size_t)d * 512 + vv + j] = __float2bfloat16(acc[i][j]);
    }
}

// ---------------------------------------------------------------------------
// scan_pass: in-place exclusive scan over chunks:
//   out_c = S (state BEFORE chunk c);  S = S*exp(b_last_c)[d] + U_c
// thread per (bh, d, 8-v group); S kept f32 across chunks
// ---------------------------------------------------------------------------
__global__ __launch_bounds__(256) void scan_pass(__hip_bfloat16* __restrict__ U,
                                                 const float* __restrict__ dlast) {
    int gid = blockIdx.x * 256 + threadIdx.x;   // 131072 threads
    int bh = gid >> 14, rem = gid & 16383;
    int d = rem >> 6, vg = (rem & 63) * 8;
    float S[8];
#pragma unroll
    for (int j = 0; j < 8; ++j) S[j] = 0.f;
    size_t base = (size_t)bh * NCH * 131072 + (size_t)d * 512 + vg;
    for (int c = 0; c < NCH; ++c) {
        __hip_bfloat16* p = U + base + (size_t)c * 131072;
        bf16x8 u = *reinterpret_cast<bf16x8*>(p);
        float e = dlast[((size_t)bh * NCH + c) * HDK_ + d];
        bf16x8 outv;
#pragma unroll
        for (int j = 0; j < 8; ++j) {
            __hip_bfloat16 sb = __float2bfloat16(S[j]);
            outv[j] = *reinterpret_cast<short*>(&sb);
            S[j] = S[j] * e + bf2f(u[j]);
        }
        *reinterpret_cast<bf16x8*>(p) = outv;
    }
}

// ---------------------------------------------------------------------------
// o_pass: o[t][v] += sum_d qg[t][d] * Sin[bh][c][d][v]
// grid: x = vt(4), y = c(32), z = bh(8); 256 thr, 4x8 acc, K=256 in 4 slices
// ---------------------------------------------------------------------------
__global__ __launch_bounds__(256) void o_pass(const float* __restrict__ qg,
                                              const __hip_bfloat16* __restrict__ U,
                                              float* __restrict__ o) {
    __shared__ float qgs[64][68];
    __shared__ float Ss[64][132];
    const int vt = blockIdx.x, c = blockIdx.y, bh = blockIdx.z;
    const int b = bh >> 2, h = bh & 3;
    const int t0 = b * 2048 + c * 64;
    const int tid = threadIdx.x, tx = tid & 15, ty = tid >> 4;
    float acc[4][8];
#pragma unroll
    for (int i = 0; i < 4; ++i)
#pragma unroll
        for (int j = 0; j < 8; ++j) acc[i][j] = 0.f;
    const size_t Ub = ((size_t)bh * NCH + c) * 131072 + vt * 128;
    for (int d0 = 0; d0 < HDK_; d0 += 64) {
#pragma unroll
        for (int i = 0; i < 4; ++i) {
            int idx = tid + i * 256;
            int t = idx >> 4, dq = (idx & 15) * 4;
            *reinterpret_cast<float4*>(&qgs[t][dq]) =
                *reinterpret_cast<const float4*>(&qg[(size_t)(t0 + t) * DKC + h * HDK_ + d0 + dq]);
        }
#pragma unroll
        for (int i = 0; i < 4; ++i) {
            int idx = tid + i * 256;
            int dd = idx >> 4, vq = (idx & 15) * 8;
            bf16x8 s = *reinterpret_cast<const bf16x8*>(&U[Ub + (size_t)(d0 + dd) * 512 + vq]);
#pragma unroll
            for (int j = 0; j < 8; ++j) Ss[dd][vq + j] = bf2f(s[j]);
        }
        __syncthreads();
        for (int dd = 0; dd < 64; ++dd) {
            float a[4], bv[8];
#pragma unroll
            for (int i = 0; i < 4; ++i) a[i] = qgs[ty * 4 + i][dd];
            *reinterpret_cast<float4*>(&bv[0]) = *reinterpret_cast<const float4*>(&Ss[dd][tx * 8]);
            *reinterpret_cast<float4*>(&bv[4]) = *reinterpret_cast<const float4*>(&Ss[dd][tx * 8 + 4]);
#pragma unroll
            for (int i = 0; i < 4; ++i)
#pragma unroll
                for (int j = 0; j < 8; ++j) acc[i][j] = fmaf(a[i], bv[j], acc[i][j]);
        }
        __syncthreads();
    }
#pragma unroll
    for (int i = 0; i < 4; ++i) {
        size_t oi = (size_t)(t0 + ty * 4 + i) * DVC + h * HDV_ + vt * 128 + tx * 8;
        float4 o0 = *reinterpret_cast<const float4*>(&o[oi]);
        float4 o1 = *reinterpret_cast<const float4*>(&o[oi + 4]);
        o0.x += acc[i][0]; o0.y += acc[i][1]; o0.z += acc[i][2]; o0.w += acc[i][3];
        o1.x += acc[i][4]; o1.y += acc[i][5]; o1.z += acc[i][6]; o1.w += acc[i][7];
        *reinterpret_cast<float4*>(&o[oi]) = o0;
        *reinterpret_cast<float4*>(&o[oi + 4]) = o1;
    }
}

// ---------------------------------------------------------------------------
// RMSNorm * rms_w * silu(xg)
// ---------------------------------------------------------------------------
__global__ __launch_bounds__(256) void rms_gate(const float* __restrict__ o,
                                                const float* __restrict__ xg,
                                                const float* __restrict__ rms_w,
                                                float* __restrict__ gated) {
    __shared__ float wsum[4];
    const int th = blockIdx.x;
    const int t = th >> 2, h = th & 3;
    const int tid = threadIdx.x;
    const size_t base = (size_t)t * DVC + h * HDV_;
    float v0 = o[base + tid], v1 = o[base + 256 + tid];
    float s = v0 * v0 + v1 * v1;
#pragma unroll
    for (int off = 32; off >= 1; off >>= 1) s += __shfl_down(s, off, 64);
    if ((tid & 63) == 0) wsum[tid >> 6] = s;
    __syncthreads();
    float tot = wsum[0] + wsum[1] + wsum[2] + wsum[3];
    float rms = rsqrtf(tot * (1.f / 512.f) + 1e-5f);
    float g0 = xg[base + tid], g1 = xg[base + 256 + tid];
    float s0 = g0 / (1.f + expf(-g0));
    float s1 = g1 / (1.f + expf(-g1));
    gated[base + tid]       = v0 * rms * rms_w[tid] * s0;
    gated[base + 256 + tid] = v1 * rms * rms_w[256 + tid] * s1;
}

// ---------------------------------------------------------------------------
extern "C" void kernel_launch(void* const* d_in, const int* in_sizes, int n_in,
                              void* d_out, int out_size, void* d_ws, size_t ws_size,
                              hipStream_t stream) {
    const float* x    = (const float*)d_in[0];
    const float* Wq   = (const float*)d_in[1];
    const float* Wk   = (const float*)d_in[2];
    const float* Wv   = (const float*)d_in[3];
    const float* Wg   = (const float*)d_in[4];
    const float* Wgk1 = (const float*)d_in[5];
    const float* Wgk2 = (const float*)d_in[6];
    const float* bgk2 = (const float*)d_in[7];
    const float* Wo   = (const float*)d_in[8];
    const float* rmsw = (const float*)d_in[9];
    float* out = (float*)d_out;
    float* ws = (float*)d_ws;

    const size_t M1 = 1ull << 20;   // floats
    // Region [0,17M): q,k,g,xb,Wt* early; U (bf16, 16M floats = 64 MB) overlays
    // [0,16M) after gla_chunk; gated overlays [0,8M) after o_pass.
    float* q   = ws;                 // [0,4M)
    float* kbf = ws + 4 * M1;        // [4M,8M)
    float* g   = ws + 8 * M1;        // [8M,12M)
    __hip_bfloat16* xb  = (__hip_bfloat16*)(ws + 12 * M1);            // 8 MB
    __hip_bfloat16* Wtq = (__hip_bfloat16*)(ws + 14 * M1);            // 2 MB
    __hip_bfloat16* Wtk = (__hip_bfloat16*)(ws + 14 * M1 + 524288);   // 2 MB
    __hip_bfloat16* Wtv = (__hip_bfloat16*)(ws + 15 * M1);            // 4 MB
    __hip_bfloat16* Wtg = (__hip_bfloat16*)(ws + 16 * M1);            // 4 MB
    __hip_bfloat16* U   = (__hip_bfloat16*)ws;                        // [0,16M floats)
    float* v    = ws + 17 * M1;      // [17M,25M)
    float* xg   = ws + 25 * M1;      // [25M,33M)
    float* qg   = ws + 33 * M1;      // [33M,37M)
    float* kg   = ws + 37 * M1;      // [37M,41M)
    float* o    = ws + 41 * M1;      // [41M,49M)
    float* t1   = ws + 49 * M1;             // 256 KB
    float* dlast = ws + 49 * M1 + 65536;    // 256 KB
    float* gated = ws;               // [0,8M), after o_pass

    conv_bf16<<<4096, 256, 0, stream>>>(x, xb);
    convT<<<dim3(32, 32), 256, 0, stream>>>(Wq, Wtq, DM, DKC);
    convT<<<dim3(32, 32), 256, 0, stream>>>(Wk, Wtk, DM, DKC);
    convT<<<dim3(64, 32), 256, 0, stream>>>(Wv, Wtv, DM, DVC);
    convT<<<dim3(64, 32), 256, 0, stream>>>(Wg, Wtg, DM, DVC);

    gemm_bf16<<<dim3(8, 32),  256, 0, stream>>>(xb, Wtq, q,   TOK, DKC, DM);
    gemm_bf16<<<dim3(8, 32),  256, 0, stream>>>(xb, Wtk, kbf, TOK, DKC, DM);
    gemm_bf16<<<dim3(16, 32), 256, 0, stream>>>(xb, Wtv, v,   TOK, DVC, DM);
    gemm_bf16<<<dim3(16, 32), 256, 0, stream>>>(xb, Wtg, xg,  TOK, DVC, DM);

    lowrank1<<<TOK, 256, 0, stream>>>(x, Wgk1, t1);
    gate_k<<<(TOK * DKC) / 256, 256, 0, stream>>>(t1, Wgk2, bgk2, g);
    gla_chunk<<<dim3(NCH, 8), 256, 0, stream>>>(q, kbf, v, g, qg, kg, o, dlast);

    u_pass<<<dim3(16, NCH, 8), 256, 0, stream>>>(kg, v, U);
    scan_pass<<<512, 256, 0, stream>>>(U, dlast);
    o_pass<<<dim3(4, NCH, 8), 256, 0, stream>>>(qg, U, o);

    rms_gate<<<TOK * NH, 256, 0, stream>>>(o, xg, rmsw, gated);
    gemm_f32<<<dim3(DM / 128, TOK / 128), 256, 0, stream>>>(gated, Wo, out, TOK, DM, DVC);
}

// Round 4
// 420.213 us; speedup vs baseline: 3.7398x; 1.5186x over previous
//
#include <hip/hip_runtime.h>
#include <hip/hip_bf16.h>
#include <math.h>

#define TOK  4096
#define DM   1024
#define DKC  1024
#define DVC  2048
#define NH   4
#define HDK_ 256
#define HDV_ 512
#define NCH  32
#define CHK  64

typedef __attribute__((ext_vector_type(8))) short bf16x8;
typedef __attribute__((ext_vector_type(4))) float f32x4;

__device__ inline float bf2f(short s) {
    unsigned int b = ((unsigned int)(unsigned short)s) << 16;
    return __uint_as_float(b);
}

// ---------------------------------------------------------------------------
// x (f32) -> bf16 copy
// ---------------------------------------------------------------------------
__global__ __launch_bounds__(256) void conv_bf16(const float* __restrict__ in,
                                                 __hip_bfloat16* __restrict__ out) {
    size_t i = ((size_t)blockIdx.x * 256 + threadIdx.x) * 4;
    float4 v = *reinterpret_cast<const float4*>(&in[i]);
    out[i + 0] = __float2bfloat16(v.x);
    out[i + 1] = __float2bfloat16(v.y);
    out[i + 2] = __float2bfloat16(v.z);
    out[i + 3] = __float2bfloat16(v.w);
}

// ---------------------------------------------------------------------------
// W[K][N] f32 -> Wt[N][K] bf16 (tiled transpose); grid = dim3(N/32, K/32)
// ---------------------------------------------------------------------------
__global__ __launch_bounds__(256) void convT(const float* __restrict__ W,
                                             __hip_bfloat16* __restrict__ Wt,
                                             int K, int N) {
    __shared__ float tile[32][33];
    int n0 = blockIdx.x * 32, k0 = blockIdx.y * 32;
    int tx = threadIdx.x & 31, ty = threadIdx.x >> 5;
#pragma unroll
    for (int i = 0; i < 32; i += 8)
        tile[ty + i][tx] = W[(size_t)(k0 + ty + i) * N + n0 + tx];
    __syncthreads();
#pragma unroll
    for (int i = 0; i < 32; i += 8)
        Wt[(size_t)(n0 + ty + i) * K + k0 + tx] = __float2bfloat16(tile[tx][ty + i]);
}

// ---------------------------------------------------------------------------
// bf16 MFMA GEMM: C[M,N] f32 = A[M,K]bf16 @ Wt[N,K]bf16^T
// 128x128 tile, BK=64, 4 waves (2x2), each wave 64x64 via 4x4 frags 16x16x32
// ---------------------------------------------------------------------------
__global__ __launch_bounds__(256) void gemm_bf16(const __hip_bfloat16* __restrict__ A,
                                                 const __hip_bfloat16* __restrict__ Wt,
                                                 float* __restrict__ C,
                                                 int M, int N, int K) {
    __shared__ short Al[128][72];
    __shared__ short Bl[128][72];
    const int tid = threadIdx.x;
    const int wave = tid >> 6, lane = tid & 63;
    const int wr = wave >> 1, wc = wave & 1;
    const int m0 = blockIdx.y * 128, n0 = blockIdx.x * 128;
    const int l15 = lane & 15, kb = lane >> 4;
    f32x4 acc[4][4];
#pragma unroll
    for (int mf = 0; mf < 4; ++mf)
#pragma unroll
        for (int nf = 0; nf < 4; ++nf) acc[mf][nf] = (f32x4){0.f, 0.f, 0.f, 0.f};

    for (int k0 = 0; k0 < K; k0 += 64) {
#pragma unroll
        for (int i = 0; i < 4; ++i) {
            int idx = tid + i * 256;
            int r = idx >> 3, seg = (idx & 7) * 8;
            *reinterpret_cast<bf16x8*>(&Al[r][seg]) =
                *reinterpret_cast<const bf16x8*>(&A[(size_t)(m0 + r) * K + k0 + seg]);
            *reinterpret_cast<bf16x8*>(&Bl[r][seg]) =
                *reinterpret_cast<const bf16x8*>(&Wt[(size_t)(n0 + r) * K + k0 + seg]);
        }
        __syncthreads();
#pragma unroll
        for (int kk = 0; kk < 2; ++kk) {
            bf16x8 af[4], bfr[4];
#pragma unroll
            for (int mf = 0; mf < 4; ++mf)
                af[mf] = *reinterpret_cast<const bf16x8*>(&Al[wr * 64 + mf * 16 + l15][kk * 32 + kb * 8]);
#pragma unroll
            for (int nf = 0; nf < 4; ++nf)
                bfr[nf] = *reinterpret_cast<const bf16x8*>(&Bl[wc * 64 + nf * 16 + l15][kk * 32 + kb * 8]);
#pragma unroll
            for (int mf = 0; mf < 4; ++mf)
#pragma unroll
                for (int nf = 0; nf < 4; ++nf)
                    acc[mf][nf] = __builtin_amdgcn_mfma_f32_16x16x32_bf16(af[mf], bfr[nf], acc[mf][nf], 0, 0, 0);
        }
        __syncthreads();
    }
#pragma unroll
    for (int mf = 0; mf < 4; ++mf)
#pragma unroll
        for (int nf = 0; nf < 4; ++nf)
#pragma unroll
            for (int r = 0; r < 4; ++r)
                C[(size_t)(m0 + wr * 64 + mf * 16 + kb * 4 + r) * N + n0 + wc * 64 + nf * 16 + l15] =
                    acc[mf][nf][r];
}

// ---------------------------------------------------------------------------
// t1 = x @ Wgk1
// ---------------------------------------------------------------------------
__global__ __launch_bounds__(256) void lowrank1(const float* __restrict__ x,
                                                const float* __restrict__ W1,
                                                float* __restrict__ t1) {
    __shared__ float red[16][17];
    const int t = blockIdx.x;
    const int tid = threadIdx.x;
    const int o = tid & 15;
    const int p = tid >> 4;
    float s = 0.f;
#pragma unroll 8
    for (int m = 0; m < 64; ++m) {
        int kk = p * 64 + m;
        s += x[(size_t)t * DM + kk] * W1[kk * 16 + o];
    }
    red[p][o] = s;
    __syncthreads();
    if (tid < 16) {
        float tot = 0.f;
#pragma unroll
        for (int pp = 0; pp < 16; ++pp) tot += red[pp][tid];
        t1[(size_t)t * 16 + tid] = tot;
    }
}

// ---------------------------------------------------------------------------
// g = log_sigmoid(t1 @ Wgk2 + b) / 16
// ---------------------------------------------------------------------------
__global__ __launch_bounds__(256) void gate_k(const float* __restrict__ t1,
                                              const float* __restrict__ W2,
                                              const float* __restrict__ b2,
                                              float* __restrict__ g) {
    const size_t idx = (size_t)blockIdx.x * 256 + threadIdx.x;
    const int t = (int)(idx >> 10), c = (int)(idx & 1023);
    float acc = b2[c];
#pragma unroll
    for (int r = 0; r < 16; ++r) acc += t1[(size_t)t * 16 + r] * W2[r * 1024 + c];
    float ls = fminf(acc, 0.f) - log1pf(expf(-fabsf(acc)));
    g[idx] = ls * (1.f / 16.f);
}

// ---------------------------------------------------------------------------
// Chunk-parallel GLA precompute
// ---------------------------------------------------------------------------
__global__ __launch_bounds__(256) void gla_chunk(const float* __restrict__ q,
                                                 const float* __restrict__ k,
                                                 const float* __restrict__ v,
                                                 const float* __restrict__ g,
                                                 float* __restrict__ qg,
                                                 float* __restrict__ kg,
                                                 float* __restrict__ o,
                                                 float* __restrict__ dlast) {
    __shared__ float bb[64][257];
    __shared__ float qt[64][65];
    __shared__ float kt[64][65];
    __shared__ float Am[64][68];
    __shared__ float vt[64][68];
    const int chunk = blockIdx.x, bh = blockIdx.y;
    const int b = bh >> 2, h = bh & 3;
    const int t0 = b * 2048 + chunk * 64;
    const int tid = threadIdx.x;
    const float scale = 0.0625f;

    {
        const int d = tid;
        float run = 0.f;
        for (int i = 0; i < 64; ++i) {
            run += g[(size_t)(t0 + i) * DKC + h * HDK_ + d];
            bb[i][d] = run;
        }
        dlast[((size_t)bh * NCH + chunk) * HDK_ + d] = expf(run);
        const float bl = run;
        for (int i = 0; i < 64; ++i) {
            float bv = bb[i][d];
            size_t gi = (size_t)(t0 + i) * DKC + h * HDK_ + d;
            qg[gi] = q[gi] * expf(bv) * scale;
            kg[gi] = k[gi] * expf(bl - bv);
        }
    }
    __syncthreads();

    const int tx = tid & 15, ty = tid >> 4;
    float accA[4][4];
#pragma unroll
    for (int i = 0; i < 4; ++i)
#pragma unroll
        for (int j = 0; j < 4; ++j) accA[i][j] = 0.f;

    for (int d0 = 0; d0 < HDK_; d0 += 64) {
#pragma unroll
        for (int p = 0; p < 16; ++p) {
            int idx = tid + p * 256;
            int dd = idx & 63, i = idx >> 6;
            float bv = bb[i][d0 + dd];
            size_t gi = (size_t)(t0 + i) * DKC + h * HDK_ + d0 + dd;
            qt[dd][i] = q[gi] * expf(bv) * scale;
            kt[dd][i] = k[gi] * expf(-bv);
        }
        __syncthreads();
        for (int dd = 0; dd < 64; ++dd) {
            float a[4], c[4];
#pragma unroll
            for (int i = 0; i < 4; ++i) a[i] = qt[dd][ty * 4 + i];
#pragma unroll
            for (int j = 0; j < 4; ++j) c[j] = kt[dd][tx * 4 + j];
#pragma unroll
            for (int i = 0; i < 4; ++i)
#pragma unroll
                for (int j = 0; j < 4; ++j) accA[i][j] = fmaf(a[i], c[j], accA[i][j]);
        }
        __syncthreads();
    }
#pragma unroll
    for (int i = 0; i < 4; ++i)
#pragma unroll
        for (int j = 0; j < 4; ++j)
            Am[ty * 4 + i][tx * 4 + j] = (ty * 4 + i >= tx * 4 + j) ? accA[i][j] : 0.f;
    __syncthreads();

    for (int cb = 0; cb < 8; ++cb) {
#pragma unroll
        for (int p = 0; p < 16; ++p) {
            int idx = tid + p * 256;
            int c = idx & 63, s = idx >> 6;
            vt[s][c] = v[(size_t)(t0 + s) * DVC + h * HDV_ + cb * 64 + c];
        }
        __syncthreads();
        float accO[4][4];
#pragma unroll
        for (int i = 0; i < 4; ++i)
#pragma unroll
            for (int j = 0; j < 4; ++j) accO[i][j] = 0.f;
        for (int s = 0; s < 64; ++s) {
            float a[4], c[4];
#pragma unroll
            for (int i = 0; i < 4; ++i) a[i] = Am[ty * 4 + i][s];
#pragma unroll
            for (int j = 0; j < 4; ++j) c[j] = vt[s][tx * 4 + j];
#pragma unroll
            for (int i = 0; i < 4; ++i)
#pragma unroll
                for (int j = 0; j < 4; ++j) accO[i][j] = fmaf(a[i], c[j], accO[i][j]);
        }
#pragma unroll
        for (int i = 0; i < 4; ++i) {
            *reinterpret_cast<float4*>(
                &o[(size_t)(t0 + ty * 4 + i) * DVC + h * HDV_ + cb * 64 + tx * 4]) =
                make_float4(accO[i][0], accO[i][1], accO[i][2], accO[i][3]);
        }
        __syncthreads();
    }
}

// ---------------------------------------------------------------------------
// u_pass: U[bh][c][d][v] (bf16) = sum_t kg[t][d] * v[t][v]   (per chunk)
// ---------------------------------------------------------------------------
__global__ __launch_bounds__(256) void u_pass(const float* __restrict__ kg,
                                              const float* __restrict__ v,
                                              __hip_bfloat16* __restrict__ U) {
    __shared__ float kgs[64][68];
    __shared__ float vbs[64][132];
    const int dt = blockIdx.x >> 2, vt = blockIdx.x & 3;
    const int c = blockIdx.y, bh = blockIdx.z;
    const int b = bh >> 2, h = bh & 3;
    const int t0 = b * 2048 + c * 64;
    const int tid = threadIdx.x, tx = tid & 15, ty = tid >> 4;
#pragma unroll
    for (int i = 0; i < 4; ++i) {
        int idx = tid + i * 256;
        int t = idx >> 4, dq = (idx & 15) * 4;
        *reinterpret_cast<float4*>(&kgs[t][dq]) =
            *reinterpret_cast<const float4*>(&kg[(size_t)(t0 + t) * DKC + h * HDK_ + dt * 64 + dq]);
    }
#pragma unroll
    for (int i = 0; i < 8; ++i) {
        int idx = tid + i * 256;
        int t = idx >> 5, vq = (idx & 31) * 4;
        *reinterpret_cast<float4*>(&vbs[t][vq]) =
            *reinterpret_cast<const float4*>(&v[(size_t)(t0 + t) * DVC + h * HDV_ + vt * 128 + vq]);
    }
    __syncthreads();
    float acc[4][8];
#pragma unroll
    for (int i = 0; i < 4; ++i)
#pragma unroll
        for (int j = 0; j < 8; ++j) acc[i][j] = 0.f;
    for (int t = 0; t < 64; ++t) {
        float a[4], bv[8];
#pragma unroll
        for (int i = 0; i < 4; ++i) a[i] = kgs[t][ty * 4 + i];
        *reinterpret_cast<float4*>(&bv[0]) = *reinterpret_cast<const float4*>(&vbs[t][tx * 8]);
        *reinterpret_cast<float4*>(&bv[4]) = *reinterpret_cast<const float4*>(&vbs[t][tx * 8 + 4]);
#pragma unroll
        for (int i = 0; i < 4; ++i)
#pragma unroll
            for (int j = 0; j < 8; ++j) acc[i][j] = fmaf(a[i], bv[j], acc[i][j]);
    }
    size_t Ub = ((size_t)bh * NCH + c) * 131072;
#pragma unroll
    for (int i = 0; i < 4; ++i) {
        int d = dt * 64 + ty * 4 + i, vv = vt * 128 + tx * 8;
#pragma unroll
        for (int j = 0; j < 8; ++j)
            U[Ub + (size_t)d * 512 + vv + j] = __float2bfloat16(acc[i][j]);
    }
}

// ---------------------------------------------------------------------------
// scan_pass: in-place exclusive scan over chunks
// ---------------------------------------------------------------------------
__global__ __launch_bounds__(256) void scan_pass(__hip_bfloat16* __restrict__ U,
                                                 const float* __restrict__ dlast) {
    int gid = blockIdx.x * 256 + threadIdx.x;
    int bh = gid >> 14, rem = gid & 16383;
    int d = rem >> 6, vg = (rem & 63) * 8;
    float S[8];
#pragma unroll
    for (int j = 0; j < 8; ++j) S[j] = 0.f;
    size_t base = (size_t)bh * NCH * 131072 + (size_t)d * 512 + vg;
    for (int c = 0; c < NCH; ++c) {
        __hip_bfloat16* p = U + base + (size_t)c * 131072;
        bf16x8 u = *reinterpret_cast<bf16x8*>(p);
        float e = dlast[((size_t)bh * NCH + c) * HDK_ + d];
        bf16x8 outv;
#pragma unroll
        for (int j = 0; j < 8; ++j) {
            __hip_bfloat16 sb = __float2bfloat16(S[j]);
            outv[j] = *reinterpret_cast<short*>(&sb);
            S[j] = S[j] * e + bf2f(u[j]);
        }
        *reinterpret_cast<bf16x8*>(p) = outv;
    }
}

// ---------------------------------------------------------------------------
// o_pass: o[t][v] += sum_d qg[t][d] * Sin[bh][c][d][v]
// ---------------------------------------------------------------------------
__global__ __launch_bounds__(256) void o_pass(const float* __restrict__ qg,
                                              const __hip_bfloat16* __restrict__ U,
                                              float* __restrict__ o) {
    __shared__ float qgs[64][68];
    __shared__ float Ss[64][132];
    const int vt = blockIdx.x, c = blockIdx.y, bh = blockIdx.z;
    const int b = bh >> 2, h = bh & 3;
    const int t0 = b * 2048 + c * 64;
    const int tid = threadIdx.x, tx = tid & 15, ty = tid >> 4;
    float acc[4][8];
#pragma unroll
    for (int i = 0; i < 4; ++i)
#pragma unroll
        for (int j = 0; j < 8; ++j) acc[i][j] = 0.f;
    const size_t Ub = ((size_t)bh * NCH + c) * 131072 + vt * 128;
    for (int d0 = 0; d0 < HDK_; d0 += 64) {
#pragma unroll
        for (int i = 0; i < 4; ++i) {
            int idx = tid + i * 256;
            int t = idx >> 4, dq = (idx & 15) * 4;
            *reinterpret_cast<float4*>(&qgs[t][dq]) =
                *reinterpret_cast<const float4*>(&qg[(size_t)(t0 + t) * DKC + h * HDK_ + d0 + dq]);
        }
#pragma unroll
        for (int i = 0; i < 4; ++i) {
            int idx = tid + i * 256;
            int dd = idx >> 4, vq = (idx & 15) * 8;
            bf16x8 s = *reinterpret_cast<const bf16x8*>(&U[Ub + (size_t)(d0 + dd) * 512 + vq]);
#pragma unroll
            for (int j = 0; j < 8; ++j) Ss[dd][vq + j] = bf2f(s[j]);
        }
        __syncthreads();
        for (int dd = 0; dd < 64; ++dd) {
            float a[4], bv[8];
#pragma unroll
            for (int i = 0; i < 4; ++i) a[i] = qgs[ty * 4 + i][dd];
            *reinterpret_cast<float4*>(&bv[0]) = *reinterpret_cast<const float4*>(&Ss[dd][tx * 8]);
            *reinterpret_cast<float4*>(&bv[4]) = *reinterpret_cast<const float4*>(&Ss[dd][tx * 8 + 4]);
#pragma unroll
            for (int i = 0; i < 4; ++i)
#pragma unroll
                for (int j = 0; j < 8; ++j) acc[i][j] = fmaf(a[i], bv[j], acc[i][j]);
        }
        __syncthreads();
    }
#pragma unroll
    for (int i = 0; i < 4; ++i) {
        size_t oi = (size_t)(t0 + ty * 4 + i) * DVC + h * HDV_ + vt * 128 + tx * 8;
        float4 o0 = *reinterpret_cast<const float4*>(&o[oi]);
        float4 o1 = *reinterpret_cast<const float4*>(&o[oi + 4]);
        o0.x += acc[i][0]; o0.y += acc[i][1]; o0.z += acc[i][2]; o0.w += acc[i][3];
        o1.x += acc[i][4]; o1.y += acc[i][5]; o1.z += acc[i][6]; o1.w += acc[i][7];
        *reinterpret_cast<float4*>(&o[oi]) = o0;
        *reinterpret_cast<float4*>(&o[oi + 4]) = o1;
    }
}

// ---------------------------------------------------------------------------
// RMSNorm * rms_w * silu(xg)  ->  gated (bf16)
// ---------------------------------------------------------------------------
__global__ __launch_bounds__(256) void rms_gate(const float* __restrict__ o,
                                                const float* __restrict__ xg,
                                                const float* __restrict__ rms_w,
                                                __hip_bfloat16* __restrict__ gated) {
    __shared__ float wsum[4];
    const int th = blockIdx.x;
    const int t = th >> 2, h = th & 3;
    const int tid = threadIdx.x;
    const size_t base = (size_t)t * DVC + h * HDV_;
    float v0 = o[base + tid], v1 = o[base + 256 + tid];
    float s = v0 * v0 + v1 * v1;
#pragma unroll
    for (int off = 32; off >= 1; off >>= 1) s += __shfl_down(s, off, 64);
    if ((tid & 63) == 0) wsum[tid >> 6] = s;
    __syncthreads();
    float tot = wsum[0] + wsum[1] + wsum[2] + wsum[3];
    float rms = rsqrtf(tot * (1.f / 512.f) + 1e-5f);
    float g0 = xg[base + tid], g1 = xg[base + 256 + tid];
    float s0 = g0 / (1.f + expf(-g0));
    float s1 = g1 / (1.f + expf(-g1));
    gated[base + tid]       = __float2bfloat16(v0 * rms * rms_w[tid] * s0);
    gated[base + 256 + tid] = __float2bfloat16(v1 * rms * rms_w[256 + tid] * s1);
}

// ---------------------------------------------------------------------------
extern "C" void kernel_launch(void* const* d_in, const int* in_sizes, int n_in,
                              void* d_out, int out_size, void* d_ws, size_t ws_size,
                              hipStream_t stream) {
    const float* x    = (const float*)d_in[0];
    const float* Wq   = (const float*)d_in[1];
    const float* Wk   = (const float*)d_in[2];
    const float* Wv   = (const float*)d_in[3];
    const float* Wg   = (const float*)d_in[4];
    const float* Wgk1 = (const float*)d_in[5];
    const float* Wgk2 = (const float*)d_in[6];
    const float* bgk2 = (const float*)d_in[7];
    const float* Wo   = (const float*)d_in[8];
    const float* rmsw = (const float*)d_in[9];
    float* out = (float*)d_out;
    float* ws = (float*)d_ws;

    const size_t M1 = 1ull << 20;   // floats
    float* q   = ws;                 // [0,4M)
    float* kbf = ws + 4 * M1;        // [4M,8M)
    float* g   = ws + 8 * M1;        // [8M,12M)
    __hip_bfloat16* xb  = (__hip_bfloat16*)(ws + 12 * M1);            // 8 MB
    __hip_bfloat16* Wtq = (__hip_bfloat16*)(ws + 14 * M1);            // 2 MB
    __hip_bfloat16* Wtk = (__hip_bfloat16*)(ws + 14 * M1 + 524288);   // 2 MB
    __hip_bfloat16* Wtv = (__hip_bfloat16*)(ws + 15 * M1);            // 4 MB
    __hip_bfloat16* Wtg = (__hip_bfloat16*)(ws + 16 * M1);            // 4 MB
    __hip_bfloat16* U   = (__hip_bfloat16*)ws;                        // [0,16M floats)
    float* v    = ws + 17 * M1;      // [17M,25M)
    float* xg   = ws + 25 * M1;      // [25M,33M)
    float* qg   = ws + 33 * M1;      // [33M,37M)
    float* kg   = ws + 37 * M1;      // [37M,41M)
    float* o    = ws + 41 * M1;      // [41M,49M)
    float* t1   = ws + 49 * M1;             // 256 KB
    float* dlast = ws + 49 * M1 + 65536;    // 256 KB
    __hip_bfloat16* gated = (__hip_bfloat16*)ws;              // [0,4M floats) after o_pass
    __hip_bfloat16* WtO   = (__hip_bfloat16*)(ws + 4 * M1);   // [4M,5M floats) after o_pass

    conv_bf16<<<4096, 256, 0, stream>>>(x, xb);
    convT<<<dim3(32, 32), 256, 0, stream>>>(Wq, Wtq, DM, DKC);
    convT<<<dim3(32, 32), 256, 0, stream>>>(Wk, Wtk, DM, DKC);
    convT<<<dim3(64, 32), 256, 0, stream>>>(Wv, Wtv, DM, DVC);
    convT<<<dim3(64, 32), 256, 0, stream>>>(Wg, Wtg, DM, DVC);

    gemm_bf16<<<dim3(8, 32),  256, 0, stream>>>(xb, Wtq, q,   TOK, DKC, DM);
    gemm_bf16<<<dim3(8, 32),  256, 0, stream>>>(xb, Wtk, kbf, TOK, DKC, DM);
    gemm_bf16<<<dim3(16, 32), 256, 0, stream>>>(xb, Wtv, v,   TOK, DVC, DM);
    gemm_bf16<<<dim3(16, 32), 256, 0, stream>>>(xb, Wtg, xg,  TOK, DVC, DM);

    lowrank1<<<TOK, 256, 0, stream>>>(x, Wgk1, t1);
    gate_k<<<(TOK * DKC) / 256, 256, 0, stream>>>(t1, Wgk2, bgk2, g);
    gla_chunk<<<dim3(NCH, 8), 256, 0, stream>>>(q, kbf, v, g, qg, kg, o, dlast);

    u_pass<<<dim3(16, NCH, 8), 256, 0, stream>>>(kg, v, U);
    scan_pass<<<512, 256, 0, stream>>>(U, dlast);
    o_pass<<<dim3(4, NCH, 8), 256, 0, stream>>>(qg, U, o);

    // U dead from here: overlay gated + WtO.  Grid for convT = (N/32, K/32)!
    convT<<<dim3(32, 64), 256, 0, stream>>>(Wo, WtO, DVC, DM);
    rms_gate<<<TOK * NH, 256, 0, stream>>>(o, xg, rmsw, gated);
    gemm_bf16<<<dim3(8, 32), 256, 0, stream>>>(gated, WtO, out, TOK, DM, DVC);
}

// Round 5
// 403.853 us; speedup vs baseline: 3.8913x; 1.0405x over previous
//
#include <hip/hip_runtime.h>
#include <hip/hip_bf16.h>
#include <math.h>

#define TOK  4096
#define DM   1024
#define DKC  1024
#define DVC  2048
#define NH   4
#define HDK_ 256
#define HDV_ 512
#define NCH  32
#define CHK  64

typedef __attribute__((ext_vector_type(8))) short bf16x8;
typedef __attribute__((ext_vector_type(4))) float f32x4;

__device__ inline float bf2f(short s) {
    unsigned int b = ((unsigned int)(unsigned short)s) << 16;
    return __uint_as_float(b);
}
__device__ inline short f2bf_bits(float f) {
    __hip_bfloat16 h = __float2bfloat16(f);
    return *reinterpret_cast<short*>(&h);
}

// async global->LDS, 16B per lane; lds dest = base + lane*16 (wave-uniform base)
__device__ __forceinline__ void gl_lds16(const void* g, void* l) {
    __builtin_amdgcn_global_load_lds((const __attribute__((address_space(1))) void*)g,
                                     (__attribute__((address_space(3))) void*)l, 16, 0, 0);
}

// ---------------------------------------------------------------------------
// x (f32) -> bf16 copy
// ---------------------------------------------------------------------------
__global__ __launch_bounds__(256) void conv_bf16(const float* __restrict__ in,
                                                 __hip_bfloat16* __restrict__ out) {
    size_t i = ((size_t)blockIdx.x * 256 + threadIdx.x) * 4;
    float4 v = *reinterpret_cast<const float4*>(&in[i]);
    out[i + 0] = __float2bfloat16(v.x);
    out[i + 1] = __float2bfloat16(v.y);
    out[i + 2] = __float2bfloat16(v.z);
    out[i + 3] = __float2bfloat16(v.w);
}

// ---------------------------------------------------------------------------
// W[K][N] f32 -> Wt[N][K] bf16 (tiled transpose); grid = dim3(N/32, K/32)
// ---------------------------------------------------------------------------
__global__ __launch_bounds__(256) void convT(const float* __restrict__ W,
                                             __hip_bfloat16* __restrict__ Wt,
                                             int K, int N) {
    __shared__ float tile[32][33];
    int n0 = blockIdx.x * 32, k0 = blockIdx.y * 32;
    int tx = threadIdx.x & 31, ty = threadIdx.x >> 5;
#pragma unroll
    for (int i = 0; i < 32; i += 8)
        tile[ty + i][tx] = W[(size_t)(k0 + ty + i) * N + n0 + tx];
    __syncthreads();
#pragma unroll
    for (int i = 0; i < 32; i += 8)
        Wt[(size_t)(n0 + ty + i) * K + k0 + tx] = __float2bfloat16(tile[tx][ty + i]);
}

// ---------------------------------------------------------------------------
// v f32 [4096t][2048vcg] -> vT bf16 [bh=8][512vc][2048t]
// grid (2048/32=64, 4096/32=128)
// ---------------------------------------------------------------------------
__global__ __launch_bounds__(256) void transpose_v(const float* __restrict__ v,
                                                   __hip_bfloat16* __restrict__ vT) {
    __shared__ float tile[32][33];
    const int tg0 = blockIdx.y * 32;   // global token
    const int vg0 = blockIdx.x * 32;   // global v-col
    const int tx = threadIdx.x & 31, ty = threadIdx.x >> 5;
#pragma unroll
    for (int i = 0; i < 32; i += 8)
        tile[ty + i][tx] = v[(size_t)(tg0 + ty + i) * DVC + vg0 + tx];
    __syncthreads();
    const int b = tg0 >> 11, tl0 = tg0 & 2047;
    const int h = vg0 >> 9, vl0 = vg0 & 511;
    const int bh = b * NH + h;
#pragma unroll
    for (int i = 0; i < 32; i += 8)
        vT[((size_t)bh * 512 + vl0 + ty + i) * 2048 + tl0 + tx] =
            __float2bfloat16(tile[tx][ty + i]);
}

// ---------------------------------------------------------------------------
// bf16 MFMA GEMM (m97-style): C[M,N] f32 = A[M,K]bf16 @ Wt[N,K]bf16^T
// 128x128 tile, BK=64, linear LDS, global_load_lds width 16
// ---------------------------------------------------------------------------
__global__ __launch_bounds__(256) void gemm_bf16(const __hip_bfloat16* __restrict__ A,
                                                 const __hip_bfloat16* __restrict__ Wt,
                                                 float* __restrict__ C,
                                                 int M, int N, int K) {
    __shared__ __align__(16) short Al[128 * 64];
    __shared__ __align__(16) short Bl[128 * 64];
    const int tid = threadIdx.x;
    const int wave = tid >> 6, lane = tid & 63;
    const int wr = wave >> 1, wc = wave & 1;
    const int m0 = blockIdx.y * 128, n0 = blockIdx.x * 128;
    const int l15 = lane & 15, kb = lane >> 4;
    const int lr8 = lane >> 3, lc8 = (lane & 7) * 8;
    f32x4 acc[4][4];
#pragma unroll
    for (int mf = 0; mf < 4; ++mf)
#pragma unroll
        for (int nf = 0; nf < 4; ++nf) acc[mf][nf] = (f32x4){0.f, 0.f, 0.f, 0.f};

    for (int k0 = 0; k0 < K; k0 += 64) {
#pragma unroll
        for (int j = 0; j < 4; ++j) {
            int inst = wave * 4 + j;
            int r = inst * 8 + lr8;
            gl_lds16(&A[(size_t)(m0 + r) * K + k0 + lc8], &Al[inst * 512]);
            gl_lds16(&Wt[(size_t)(n0 + r) * K + k0 + lc8], &Bl[inst * 512]);
        }
        __syncthreads();
#pragma unroll
        for (int kk = 0; kk < 2; ++kk) {
            bf16x8 af[4], bfr[4];
#pragma unroll
            for (int mf = 0; mf < 4; ++mf)
                af[mf] = *reinterpret_cast<const bf16x8*>(&Al[(wr * 64 + mf * 16 + l15) * 64 + kk * 32 + kb * 8]);
#pragma unroll
            for (int nf = 0; nf < 4; ++nf)
                bfr[nf] = *reinterpret_cast<const bf16x8*>(&Bl[(wc * 64 + nf * 16 + l15) * 64 + kk * 32 + kb * 8]);
#pragma unroll
            for (int mf = 0; mf < 4; ++mf)
#pragma unroll
                for (int nf = 0; nf < 4; ++nf)
                    acc[mf][nf] = __builtin_amdgcn_mfma_f32_16x16x32_bf16(af[mf], bfr[nf], acc[mf][nf], 0, 0, 0);
        }
        __syncthreads();
    }
#pragma unroll
    for (int mf = 0; mf < 4; ++mf)
#pragma unroll
        for (int nf = 0; nf < 4; ++nf)
#pragma unroll
            for (int r = 0; r < 4; ++r)
                C[(size_t)(m0 + wr * 64 + mf * 16 + kb * 4 + r) * N + n0 + wc * 64 + nf * 16 + l15] =
                    acc[mf][nf][r];
}

// ---------------------------------------------------------------------------
// t1 = x @ Wgk1
// ---------------------------------------------------------------------------
__global__ __launch_bounds__(256) void lowrank1(const float* __restrict__ x,
                                                const float* __restrict__ W1,
                                                float* __restrict__ t1) {
    __shared__ float red[16][17];
    const int t = blockIdx.x;
    const int tid = threadIdx.x;
    const int o = tid & 15;
    const int p = tid >> 4;
    float s = 0.f;
#pragma unroll 8
    for (int m = 0; m < 64; ++m) {
        int kk = p * 64 + m;
        s += x[(size_t)t * DM + kk] * W1[kk * 16 + o];
    }
    red[p][o] = s;
    __syncthreads();
    if (tid < 16) {
        float tot = 0.f;
#pragma unroll
        for (int pp = 0; pp < 16; ++pp) tot += red[pp][tid];
        t1[(size_t)t * 16 + tid] = tot;
    }
}

// ---------------------------------------------------------------------------
// g = log_sigmoid(t1 @ Wgk2 + b) / 16
// ---------------------------------------------------------------------------
__global__ __launch_bounds__(256) void gate_k(const float* __restrict__ t1,
                                              const float* __restrict__ W2,
                                              const float* __restrict__ b2,
                                              float* __restrict__ g) {
    const size_t idx = (size_t)blockIdx.x * 256 + threadIdx.x;
    const int t = (int)(idx >> 10), c = (int)(idx & 1023);
    float acc = b2[c];
#pragma unroll
    for (int r = 0; r < 16; ++r) acc += t1[(size_t)t * 16 + r] * W2[r * 1024 + c];
    float ls = fminf(acc, 0.f) - log1pf(expf(-fabsf(acc)));
    g[idx] = ls * (1.f / 16.f);
}

// ---------------------------------------------------------------------------
// Chunk-parallel GLA precompute; writes qg bf16 [t][dg], kgT bf16 [bh][d][t],
// o (intra) f32, dlast f32
// ---------------------------------------------------------------------------
__global__ __launch_bounds__(256) void gla_chunk(const float* __restrict__ q,
                                                 const float* __restrict__ k,
                                                 const float* __restrict__ v,
                                                 const float* __restrict__ g,
                                                 __hip_bfloat16* __restrict__ qg,
                                                 __hip_bfloat16* __restrict__ kgT,
                                                 float* __restrict__ o,
                                                 float* __restrict__ dlast) {
    __shared__ float bb[64][257];
    __shared__ float qt[64][65];
    __shared__ float kt[64][65];
    __shared__ float Am[64][68];
    __shared__ float vt[64][68];
    const int chunk = blockIdx.x, bh = blockIdx.y;
    const int b = bh >> 2, h = bh & 3;
    const int t0 = b * 2048 + chunk * 64;
    const int tid = threadIdx.x;
    const float scale = 0.0625f;

    {
        const int d = tid;
        float run = 0.f;
        for (int i = 0; i < 64; ++i) {
            run += g[(size_t)(t0 + i) * DKC + h * HDK_ + d];
            bb[i][d] = run;
        }
        dlast[((size_t)bh * NCH + chunk) * HDK_ + d] = expf(run);
        const float bl = run;
        bf16x8 kreg[8];
#pragma unroll
        for (int i = 0; i < 64; ++i) {
            float bv = bb[i][d];
            size_t gi = (size_t)(t0 + i) * DKC + h * HDK_ + d;
            qg[gi] = __float2bfloat16(q[gi] * expf(bv) * scale);
            kreg[i >> 3][i & 7] = f2bf_bits(k[gi] * expf(bl - bv));
        }
        __hip_bfloat16* kdst = kgT + ((size_t)(bh * HDK_ + d)) * 2048 + chunk * 64;
#pragma unroll
        for (int j = 0; j < 8; ++j)
            *reinterpret_cast<bf16x8*>(&kdst[j * 8]) = kreg[j];
    }
    __syncthreads();

    const int tx = tid & 15, ty = tid >> 4;
    float accA[4][4];
#pragma unroll
    for (int i = 0; i < 4; ++i)
#pragma unroll
        for (int j = 0; j < 4; ++j) accA[i][j] = 0.f;

    for (int d0 = 0; d0 < HDK_; d0 += 64) {
#pragma unroll
        for (int p = 0; p < 16; ++p) {
            int idx = tid + p * 256;
            int dd = idx & 63, i = idx >> 6;
            float bv = bb[i][d0 + dd];
            size_t gi = (size_t)(t0 + i) * DKC + h * HDK_ + d0 + dd;
            qt[dd][i] = q[gi] * expf(bv) * scale;
            kt[dd][i] = k[gi] * expf(-bv);
        }
        __syncthreads();
        for (int dd = 0; dd < 64; ++dd) {
            float a[4], c[4];
#pragma unroll
            for (int i = 0; i < 4; ++i) a[i] = qt[dd][ty * 4 + i];
#pragma unroll
            for (int j = 0; j < 4; ++j) c[j] = kt[dd][tx * 4 + j];
#pragma unroll
            for (int i = 0; i < 4; ++i)
#pragma unroll
                for (int j = 0; j < 4; ++j) accA[i][j] = fmaf(a[i], c[j], accA[i][j]);
        }
        __syncthreads();
    }
#pragma unroll
    for (int i = 0; i < 4; ++i)
#pragma unroll
        for (int j = 0; j < 4; ++j)
            Am[ty * 4 + i][tx * 4 + j] = (ty * 4 + i >= tx * 4 + j) ? accA[i][j] : 0.f;
    __syncthreads();

    for (int cb = 0; cb < 8; ++cb) {
#pragma unroll
        for (int p = 0; p < 16; ++p) {
            int idx = tid + p * 256;
            int c = idx & 63, s = idx >> 6;
            vt[s][c] = v[(size_t)(t0 + s) * DVC + h * HDV_ + cb * 64 + c];
        }
        __syncthreads();
        float accO[4][4];
#pragma unroll
        for (int i = 0; i < 4; ++i)
#pragma unroll
            for (int j = 0; j < 4; ++j) accO[i][j] = 0.f;
        for (int s = 0; s < 64; ++s) {
            float a[4], c[4];
#pragma unroll
            for (int i = 0; i < 4; ++i) a[i] = Am[ty * 4 + i][s];
#pragma unroll
            for (int j = 0; j < 4; ++j) c[j] = vt[s][tx * 4 + j];
#pragma unroll
            for (int i = 0; i < 4; ++i)
#pragma unroll
                for (int j = 0; j < 4; ++j) accO[i][j] = fmaf(a[i], c[j], accO[i][j]);
        }
#pragma unroll
        for (int i = 0; i < 4; ++i) {
            *reinterpret_cast<float4*>(
                &o[(size_t)(t0 + ty * 4 + i) * DVC + h * HDV_ + cb * 64 + tx * 4]) =
                make_float4(accO[i][0], accO[i][1], accO[i][2], accO[i][3]);
        }
        __syncthreads();
    }
}

// ---------------------------------------------------------------------------
// u_pass (MFMA): U'[bh][c][vc][d] bf16 = sum_t v[t][vc]*kg[t][d]
//   = mfma(A = vT[vc][t], B = kgT[d][t] as B[t][d])
// grid (8 = 4vt x 2dt, 32 c, 8 bh), K = 64 (one stage)
// ---------------------------------------------------------------------------
__global__ __launch_bounds__(256) void u_pass(const __hip_bfloat16* __restrict__ vT,
                                              const __hip_bfloat16* __restrict__ kgT,
                                              __hip_bfloat16* __restrict__ U) {
    __shared__ __align__(16) short Av[128 * 64];
    __shared__ __align__(16) short Bv[128 * 64];
    const int bx = blockIdx.x, c = blockIdx.y, bh = blockIdx.z;
    const int vc0 = (bx >> 1) * 128, d0 = (bx & 1) * 128;
    const int tid = threadIdx.x;
    const int wave = tid >> 6, lane = tid & 63;
    const int wr = wave >> 1, wc = wave & 1;
    const int l15 = lane & 15, kb = lane >> 4;
    const int lr8 = lane >> 3, lc8 = (lane & 7) * 8;

#pragma unroll
    for (int j = 0; j < 4; ++j) {
        int inst = wave * 4 + j;
        int r = inst * 8 + lr8;
        gl_lds16(&vT[((size_t)bh * 512 + vc0 + r) * 2048 + c * 64 + lc8], &Av[inst * 512]);
        gl_lds16(&kgT[((size_t)bh * HDK_ + d0 + r) * 2048 + c * 64 + lc8], &Bv[inst * 512]);
    }
    __syncthreads();

    f32x4 acc[4][4];
#pragma unroll
    for (int mf = 0; mf < 4; ++mf)
#pragma unroll
        for (int nf = 0; nf < 4; ++nf) acc[mf][nf] = (f32x4){0.f, 0.f, 0.f, 0.f};
#pragma unroll
    for (int kk = 0; kk < 2; ++kk) {
        bf16x8 af[4], bfr[4];
#pragma unroll
        for (int mf = 0; mf < 4; ++mf)
            af[mf] = *reinterpret_cast<const bf16x8*>(&Av[(wr * 64 + mf * 16 + l15) * 64 + kk * 32 + kb * 8]);
#pragma unroll
        for (int nf = 0; nf < 4; ++nf)
            bfr[nf] = *reinterpret_cast<const bf16x8*>(&Bv[(wc * 64 + nf * 16 + l15) * 64 + kk * 32 + kb * 8]);
#pragma unroll
        for (int mf = 0; mf < 4; ++mf)
#pragma unroll
            for (int nf = 0; nf < 4; ++nf)
                acc[mf][nf] = __builtin_amdgcn_mfma_f32_16x16x32_bf16(af[mf], bfr[nf], acc[mf][nf], 0, 0, 0);
    }
    const size_t Ub = ((size_t)bh * NCH + c) * 131072;
#pragma unroll
    for (int mf = 0; mf < 4; ++mf)
#pragma unroll
        for (int nf = 0; nf < 4; ++nf)
#pragma unroll
            for (int r = 0; r < 4; ++r) {
                int vc = vc0 + wr * 64 + mf * 16 + kb * 4 + r;
                int d = d0 + wc * 64 + nf * 16 + l15;
                U[Ub + (size_t)vc * 256 + d] = __float2bfloat16(acc[mf][nf][r]);
            }
}

// ---------------------------------------------------------------------------
// scan_pass on U'[bh][c][vc][d]: exclusive scan over chunks, decay e(d)
// ---------------------------------------------------------------------------
__global__ __launch_bounds__(256) void scan_pass(__hip_bfloat16* __restrict__ U,
                                                 const float* __restrict__ dlast) {
    int gid = blockIdx.x * 256 + threadIdx.x;   // 131072
    int bh = gid >> 14;
    int rem = gid & 16383;
    int vc = rem >> 5;
    int dg = rem & 31;
    float S[8];
#pragma unroll
    for (int j = 0; j < 8; ++j) S[j] = 0.f;
    size_t base = (size_t)bh * NCH * 131072 + (size_t)vc * 256 + dg * 8;
    for (int c = 0; c < NCH; ++c) {
        __hip_bfloat16* p = U + base + (size_t)c * 131072;
        bf16x8 u = *reinterpret_cast<bf16x8*>(p);
        const float* dl = &dlast[((size_t)bh * NCH + c) * HDK_ + dg * 8];
        float4 e0 = *reinterpret_cast<const float4*>(dl);
        float4 e1 = *reinterpret_cast<const float4*>(dl + 4);
        float e[8] = {e0.x, e0.y, e0.z, e0.w, e1.x, e1.y, e1.z, e1.w};
        bf16x8 outv;
#pragma unroll
        for (int j = 0; j < 8; ++j) {
            outv[j] = f2bf_bits(S[j]);
            S[j] = S[j] * e[j] + bf2f(u[j]);
        }
        *reinterpret_cast<bf16x8*>(p) = outv;
    }
}

// ---------------------------------------------------------------------------
// o_pass (MFMA): o[t][vc] += sum_d qg[t][d] * S'[vc][d]
// C[m=vc 128][n=t 64] = mfma(A = S'[vc][d], B = qg[t][d] as B[d][t]); K=256
// grid (4 vt, 32 c, 8 bh); epilogue transposes via LDS, coalesced f32 RMW
// ---------------------------------------------------------------------------
__global__ __launch_bounds__(256) void o_pass(const __hip_bfloat16* __restrict__ qg,
                                              const __hip_bfloat16* __restrict__ U,
                                              float* __restrict__ o) {
    __shared__ __align__(16) char smem[128 * 68 * 4];
    short* Av = (short*)smem;               // 128x64 bf16 = 16 KB
    short* Bv = (short*)smem + 128 * 64;    // 64x64 bf16 = 8 KB
    float* oT = (float*)smem;               // 128x68 f32 (epilogue, aliases)
    const int vt = blockIdx.x, c = blockIdx.y, bh = blockIdx.z;
    const int b = bh >> 2, h = bh & 3;
    const int vc0 = vt * 128;
    const int t0 = b * 2048 + c * 64;
    const int tid = threadIdx.x;
    const int wave = tid >> 6, lane = tid & 63;
    const int wr = wave >> 1, wc = wave & 1;   // wr: vc half (64), wc: t half (32)
    const int l15 = lane & 15, kb = lane >> 4;
    const int lr8 = lane >> 3, lc8 = (lane & 7) * 8;
    const size_t Ub = ((size_t)bh * NCH + c) * 131072;

    f32x4 acc[4][2];
#pragma unroll
    for (int mf = 0; mf < 4; ++mf)
#pragma unroll
        for (int nf = 0; nf < 2; ++nf) acc[mf][nf] = (f32x4){0.f, 0.f, 0.f, 0.f};

    for (int ks = 0; ks < 4; ++ks) {
        const int d0 = ks * 64;
#pragma unroll
        for (int j = 0; j < 4; ++j) {
            int inst = wave * 4 + j;
            int r = inst * 8 + lr8;
            gl_lds16(&U[Ub + (size_t)(vc0 + r) * 256 + d0 + lc8], &Av[inst * 512]);
        }
#pragma unroll
        for (int j = 0; j < 2; ++j) {
            int inst = wave * 2 + j;
            int r = inst * 8 + lr8;
            gl_lds16(&qg[(size_t)(t0 + r) * DKC + h * HDK_ + d0 + lc8], &Bv[inst * 512]);
        }
        __syncthreads();
#pragma unroll
        for (int kk = 0; kk < 2; ++kk) {
            bf16x8 af[4], bfr[2];
#pragma unroll
            for (int mf = 0; mf < 4; ++mf)
                af[mf] = *reinterpret_cast<const bf16x8*>(&Av[(wr * 64 + mf * 16 + l15) * 64 + kk * 32 + kb * 8]);
#pragma unroll
            for (int nf = 0; nf < 2; ++nf)
                bfr[nf] = *reinterpret_cast<const bf16x8*>(&Bv[(wc * 32 + nf * 16 + l15) * 64 + kk * 32 + kb * 8]);
#pragma unroll
            for (int mf = 0; mf < 4; ++mf)
#pragma unroll
                for (int nf = 0; nf < 2; ++nf)
                    acc[mf][nf] = __builtin_amdgcn_mfma_f32_16x16x32_bf16(af[mf], bfr[nf], acc[mf][nf], 0, 0, 0);
        }
        __syncthreads();
    }
    // acc element (mf,nf,r): vc = wr*64+mf*16+kb*4+r, t = wc*32+nf*16+l15
#pragma unroll
    for (int mf = 0; mf < 4; ++mf)
#pragma unroll
        for (int nf = 0; nf < 2; ++nf)
#pragma unroll
            for (int r = 0; r < 4; ++r)
                oT[(wr * 64 + mf * 16 + kb * 4 + r) * 68 + wc * 32 + nf * 16 + l15] = acc[mf][nf][r];
    __syncthreads();
#pragma unroll
    for (int j = 0; j < 8; ++j) {
        int t = (tid >> 5) + j * 8;          // 0..63
        int vc4 = (tid & 31) * 4;            // 0..124
        float4 add = make_float4(oT[(vc4 + 0) * 68 + t], oT[(vc4 + 1) * 68 + t],
                                 oT[(vc4 + 2) * 68 + t], oT[(vc4 + 3) * 68 + t]);
        size_t oi = (size_t)(t0 + t) * DVC + h * HDV_ + vc0 + vc4;
        float4 cur = *reinterpret_cast<const float4*>(&o[oi]);
        cur.x += add.x; cur.y += add.y; cur.z += add.z; cur.w += add.w;
        *reinterpret_cast<float4*>(&o[oi]) = cur;
    }
}

// ---------------------------------------------------------------------------
// RMSNorm * rms_w * silu(xg)  ->  gated (bf16)
// ---------------------------------------------------------------------------
__global__ __launch_bounds__(256) void rms_gate(const float* __restrict__ o,
                                                const float* __restrict__ xg,
                                                const float* __restrict__ rms_w,
                                                __hip_bfloat16* __restrict__ gated) {
    __shared__ float wsum[4];
    const int th = blockIdx.x;
    const int t = th >> 2, h = th & 3;
    const int tid = threadIdx.x;
    const size_t base = (size_t)t * DVC + h * HDV_;
    float v0 = o[base + tid], v1 = o[base + 256 + tid];
    float s = v0 * v0 + v1 * v1;
#pragma unroll
    for (int off = 32; off >= 1; off >>= 1) s += __shfl_down(s, off, 64);
    if ((tid & 63) == 0) wsum[tid >> 6] = s;
    __syncthreads();
    float tot = wsum[0] + wsum[1] + wsum[2] + wsum[3];
    float rms = rsqrtf(tot * (1.f / 512.f) + 1e-5f);
    float g0 = xg[base + tid], g1 = xg[base + 256 + tid];
    float s0 = g0 / (1.f + expf(-g0));
    float s1 = g1 / (1.f + expf(-g1));
    gated[base + tid]       = __float2bfloat16(v0 * rms * rms_w[tid] * s0);
    gated[base + 256 + tid] = __float2bfloat16(v1 * rms * rms_w[256 + tid] * s1);
}

// ---------------------------------------------------------------------------
extern "C" void kernel_launch(void* const* d_in, const int* in_sizes, int n_in,
                              void* d_out, int out_size, void* d_ws, size_t ws_size,
                              hipStream_t stream) {
    const float* x    = (const float*)d_in[0];
    const float* Wq   = (const float*)d_in[1];
    const float* Wk   = (const float*)d_in[2];
    const float* Wv   = (const float*)d_in[3];
    const float* Wg   = (const float*)d_in[4];
    const float* Wgk1 = (const float*)d_in[5];
    const float* Wgk2 = (const float*)d_in[6];
    const float* bgk2 = (const float*)d_in[7];
    const float* Wo   = (const float*)d_in[8];
    const float* rmsw = (const float*)d_in[9];
    float* out = (float*)d_out;
    float* ws = (float*)d_ws;

    const size_t M1 = 1ull << 20;   // floats
    // [0,16M floats): q,kbf,g + xb/Wt* early; U' bf16 (64MB) overlays after gla_chunk
    float* q   = ws;                 // [0,4M)
    float* kbf = ws + 4 * M1;        // [4M,8M)
    float* g   = ws + 8 * M1;        // [8M,12M)
    __hip_bfloat16* xb  = (__hip_bfloat16*)(ws + 12 * M1);            // 8 MB
    __hip_bfloat16* Wtq = (__hip_bfloat16*)(ws + 14 * M1);            // 2 MB
    __hip_bfloat16* Wtk = (__hip_bfloat16*)(ws + 14 * M1 + 524288);   // 2 MB
    __hip_bfloat16* Wtv = (__hip_bfloat16*)(ws + 15 * M1);            // 4 MB
    __hip_bfloat16* Wtg = (__hip_bfloat16*)(ws + 16 * M1);            // 4 MB
    __hip_bfloat16* U   = (__hip_bfloat16*)ws;                        // [0,16M floats) = 64 MB
    float* v    = ws + 17 * M1;      // [17M,25M) 32 MB
    float* xg   = ws + 25 * M1;      // [25M,33M) 32 MB
    __hip_bfloat16* qgb = (__hip_bfloat16*)(ws + 33 * M1);   // 8 MB  [33M,35M)
    __hip_bfloat16* kgT = (__hip_bfloat16*)(ws + 35 * M1);   // 8 MB  [35M,37M)
    __hip_bfloat16* vT  = (__hip_bfloat16*)(ws + 37 * M1);   // 16 MB [37M,41M)
    float* o    = ws + 41 * M1;      // [41M,49M) 32 MB
    float* t1   = ws + 49 * M1;             // 256 KB
    float* dlast = ws + 49 * M1 + 65536;    // 256 KB
    // after gla_chunk, v dead -> overlay:
    __hip_bfloat16* WtO   = (__hip_bfloat16*)(ws + 17 * M1); // 4 MB
    __hip_bfloat16* gated = (__hip_bfloat16*)(ws + 18 * M1); // 16 MB

    conv_bf16<<<4096, 256, 0, stream>>>(x, xb);
    convT<<<dim3(32, 32), 256, 0, stream>>>(Wq, Wtq, DM, DKC);
    convT<<<dim3(32, 32), 256, 0, stream>>>(Wk, Wtk, DM, DKC);
    convT<<<dim3(64, 32), 256, 0, stream>>>(Wv, Wtv, DM, DVC);
    convT<<<dim3(64, 32), 256, 0, stream>>>(Wg, Wtg, DM, DVC);

    gemm_bf16<<<dim3(8, 32),  256, 0, stream>>>(xb, Wtq, q,   TOK, DKC, DM);
    gemm_bf16<<<dim3(8, 32),  256, 0, stream>>>(xb, Wtk, kbf, TOK, DKC, DM);
    gemm_bf16<<<dim3(16, 32), 256, 0, stream>>>(xb, Wtv, v,   TOK, DVC, DM);
    gemm_bf16<<<dim3(16, 32), 256, 0, stream>>>(xb, Wtg, xg,  TOK, DVC, DM);

    transpose_v<<<dim3(64, 128), 256, 0, stream>>>(v, vT);
    lowrank1<<<TOK, 256, 0, stream>>>(x, Wgk1, t1);
    gate_k<<<(TOK * DKC) / 256, 256, 0, stream>>>(t1, Wgk2, bgk2, g);
    gla_chunk<<<dim3(NCH, 8), 256, 0, stream>>>(q, kbf, v, g, qgb, kgT, o, dlast);

    u_pass<<<dim3(8, NCH, 8), 256, 0, stream>>>(vT, kgT, U);
    scan_pass<<<512, 256, 0, stream>>>(U, dlast);
    o_pass<<<dim3(4, NCH, 8), 256, 0, stream>>>(qgb, U, o);

    convT<<<dim3(32, 64), 256, 0, stream>>>(Wo, WtO, DVC, DM);
    rms_gate<<<TOK * NH, 256, 0, stream>>>(o, xg, rmsw, gated);
    gemm_bf16<<<dim3(8, 32), 256, 0, stream>>>(gated, WtO, out, TOK, DM, DVC);
}

// Round 6
// 336.990 us; speedup vs baseline: 4.6634x; 1.1984x over previous
//
#include <hip/hip_runtime.h>
#include <hip/hip_bf16.h>
#include <math.h>

#define TOK  4096
#define DM   1024
#define DKC  1024
#define DVC  2048
#define NH   4
#define HDK_ 256
#define HDV_ 512
#define NCH  32
#define CHK  64

typedef __attribute__((ext_vector_type(8))) short bf16x8;
typedef __attribute__((ext_vector_type(4))) float f32x4;

__device__ inline float bf2f(short s) {
    unsigned int b = ((unsigned int)(unsigned short)s) << 16;
    return __uint_as_float(b);
}
__device__ inline short f2bf_bits(float f) {
    __hip_bfloat16 h = __float2bfloat16(f);
    return *reinterpret_cast<short*>(&h);
}

// async global->LDS, 16B per lane; lds dest = base + lane*16 (wave-uniform base)
__device__ __forceinline__ void gl_lds16(const void* g, void* l) {
    __builtin_amdgcn_global_load_lds((const __attribute__((address_space(1))) void*)g,
                                     (__attribute__((address_space(3))) void*)l, 16, 0, 0);
}

// ---------------------------------------------------------------------------
// x (f32) -> bf16 copy
// ---------------------------------------------------------------------------
__global__ __launch_bounds__(256) void conv_bf16(const float* __restrict__ in,
                                                 __hip_bfloat16* __restrict__ out) {
    size_t i = ((size_t)blockIdx.x * 256 + threadIdx.x) * 4;
    float4 v = *reinterpret_cast<const float4*>(&in[i]);
    out[i + 0] = __float2bfloat16(v.x);
    out[i + 1] = __float2bfloat16(v.y);
    out[i + 2] = __float2bfloat16(v.z);
    out[i + 3] = __float2bfloat16(v.w);
}

// ---------------------------------------------------------------------------
// W[K][N] f32 -> Wt[N][K] bf16 (tiled transpose); grid = dim3(N/32, K/32)
// ---------------------------------------------------------------------------
__global__ __launch_bounds__(256) void convT(const float* __restrict__ W,
                                             __hip_bfloat16* __restrict__ Wt,
                                             int K, int N) {
    __shared__ float tile[32][33];
    int n0 = blockIdx.x * 32, k0 = blockIdx.y * 32;
    int tx = threadIdx.x & 31, ty = threadIdx.x >> 5;
#pragma unroll
    for (int i = 0; i < 32; i += 8)
        tile[ty + i][tx] = W[(size_t)(k0 + ty + i) * N + n0 + tx];
    __syncthreads();
#pragma unroll
    for (int i = 0; i < 32; i += 8)
        Wt[(size_t)(n0 + ty + i) * K + k0 + tx] = __float2bfloat16(tile[tx][ty + i]);
}

// ---------------------------------------------------------------------------
// v f32 [4096t][2048vcg] -> vT bf16 [bh=8][512vc][2048t]
// ---------------------------------------------------------------------------
__global__ __launch_bounds__(256) void transpose_v(const float* __restrict__ v,
                                                   __hip_bfloat16* __restrict__ vT) {
    __shared__ float tile[32][33];
    const int tg0 = blockIdx.y * 32;
    const int vg0 = blockIdx.x * 32;
    const int tx = threadIdx.x & 31, ty = threadIdx.x >> 5;
#pragma unroll
    for (int i = 0; i < 32; i += 8)
        tile[ty + i][tx] = v[(size_t)(tg0 + ty + i) * DVC + vg0 + tx];
    __syncthreads();
    const int b = tg0 >> 11, tl0 = tg0 & 2047;
    const int h = vg0 >> 9, vl0 = vg0 & 511;
    const int bh = b * NH + h;
#pragma unroll
    for (int i = 0; i < 32; i += 8)
        vT[((size_t)bh * 512 + vl0 + ty + i) * 2048 + tl0 + tx] =
            __float2bfloat16(tile[tx][ty + i]);
}

// ---------------------------------------------------------------------------
// bf16 MFMA GEMM (m97-style): C[M,N] f32 = A[M,K]bf16 @ Wt[N,K]bf16^T
// ---------------------------------------------------------------------------
__global__ __launch_bounds__(256) void gemm_bf16(const __hip_bfloat16* __restrict__ A,
                                                 const __hip_bfloat16* __restrict__ Wt,
                                                 float* __restrict__ C,
                                                 int M, int N, int K) {
    __shared__ __align__(16) short Al[128 * 64];
    __shared__ __align__(16) short Bl[128 * 64];
    const int tid = threadIdx.x;
    const int wave = tid >> 6, lane = tid & 63;
    const int wr = wave >> 1, wc = wave & 1;
    const int m0 = blockIdx.y * 128, n0 = blockIdx.x * 128;
    const int l15 = lane & 15, kb = lane >> 4;
    const int lr8 = lane >> 3, lc8 = (lane & 7) * 8;
    f32x4 acc[4][4];
#pragma unroll
    for (int mf = 0; mf < 4; ++mf)
#pragma unroll
        for (int nf = 0; nf < 4; ++nf) acc[mf][nf] = (f32x4){0.f, 0.f, 0.f, 0.f};

    for (int k0 = 0; k0 < K; k0 += 64) {
#pragma unroll
        for (int j = 0; j < 4; ++j) {
            int inst = wave * 4 + j;
            int r = inst * 8 + lr8;
            gl_lds16(&A[(size_t)(m0 + r) * K + k0 + lc8], &Al[inst * 512]);
            gl_lds16(&Wt[(size_t)(n0 + r) * K + k0 + lc8], &Bl[inst * 512]);
        }
        __syncthreads();
#pragma unroll
        for (int kk = 0; kk < 2; ++kk) {
            bf16x8 af[4], bfr[4];
#pragma unroll
            for (int mf = 0; mf < 4; ++mf)
                af[mf] = *reinterpret_cast<const bf16x8*>(&Al[(wr * 64 + mf * 16 + l15) * 64 + kk * 32 + kb * 8]);
#pragma unroll
            for (int nf = 0; nf < 4; ++nf)
                bfr[nf] = *reinterpret_cast<const bf16x8*>(&Bl[(wc * 64 + nf * 16 + l15) * 64 + kk * 32 + kb * 8]);
#pragma unroll
            for (int mf = 0; mf < 4; ++mf)
#pragma unroll
                for (int nf = 0; nf < 4; ++nf)
                    acc[mf][nf] = __builtin_amdgcn_mfma_f32_16x16x32_bf16(af[mf], bfr[nf], acc[mf][nf], 0, 0, 0);
        }
        __syncthreads();
    }
#pragma unroll
    for (int mf = 0; mf < 4; ++mf)
#pragma unroll
        for (int nf = 0; nf < 4; ++nf)
#pragma unroll
            for (int r = 0; r < 4; ++r)
                C[(size_t)(m0 + wr * 64 + mf * 16 + kb * 4 + r) * N + n0 + wc * 64 + nf * 16 + l15] =
                    acc[mf][nf][r];
}

// ---------------------------------------------------------------------------
// t1 = x @ Wgk1
// ---------------------------------------------------------------------------
__global__ __launch_bounds__(256) void lowrank1(const float* __restrict__ x,
                                                const float* __restrict__ W1,
                                                float* __restrict__ t1) {
    __shared__ float red[16][17];
    const int t = blockIdx.x;
    const int tid = threadIdx.x;
    const int o = tid & 15;
    const int p = tid >> 4;
    float s = 0.f;
#pragma unroll 8
    for (int m = 0; m < 64; ++m) {
        int kk = p * 64 + m;
        s += x[(size_t)t * DM + kk] * W1[kk * 16 + o];
    }
    red[p][o] = s;
    __syncthreads();
    if (tid < 16) {
        float tot = 0.f;
#pragma unroll
        for (int pp = 0; pp < 16; ++pp) tot += red[pp][tid];
        t1[(size_t)t * 16 + tid] = tot;
    }
}

// ---------------------------------------------------------------------------
// g = log_sigmoid(t1 @ Wgk2 + b) / 16
// ---------------------------------------------------------------------------
__global__ __launch_bounds__(256) void gate_k(const float* __restrict__ t1,
                                              const float* __restrict__ W2,
                                              const float* __restrict__ b2,
                                              float* __restrict__ g) {
    const size_t idx = (size_t)blockIdx.x * 256 + threadIdx.x;
    const int t = (int)(idx >> 10), c = (int)(idx & 1023);
    float acc = b2[c];
#pragma unroll
    for (int r = 0; r < 16; ++r) acc += t1[(size_t)t * 16 + r] * W2[r * 1024 + c];
    float ls = fminf(acc, 0.f) - log1pf(expf(-fabsf(acc)));
    g[idx] = ls * (1.f / 16.f);
}

// ---------------------------------------------------------------------------
// gla_chunk (MFMA version): per (chunk, bh)
//   stage1: cumsum in regs; qg,kd -> swizzled LDS bf16; qg,kgT,dlast -> global
//   stage2: A = tril(mfma(qg, kd)) -> Am bf16 (swizzled LDS)
//   stage3: o_intra = mfma(Am, vT) -> o (f32, direct store)
// LDS: qg(32K)+kd(32K) aliased by V(64K), +Am(8K) = 72KB -> 2 blocks/CU
// ---------------------------------------------------------------------------
__global__ __launch_bounds__(256) void gla_chunk(const float* __restrict__ q,
                                                 const float* __restrict__ k,
                                                 const __hip_bfloat16* __restrict__ vT,
                                                 const float* __restrict__ g,
                                                 __hip_bfloat16* __restrict__ qg,
                                                 __hip_bfloat16* __restrict__ kgT,
                                                 float* __restrict__ o,
                                                 float* __restrict__ dlast) {
    __shared__ __align__(16) short SM[36864];   // 72 KB
    short* qg_l = SM;            // [0,16384) shorts   (rows t: 256 shorts, 512B)
    short* kd_l = SM + 16384;    // [16384,32768)
    short* V_l  = SM;            // alias: 512 rows x 64 shorts (128B rows)
    short* Am_l = SM + 32768;    // [32768,36864): 64x64 (128B rows)

    const int chunk = blockIdx.x, bh = blockIdx.y;
    const int b = bh >> 2, h = bh & 3;
    const int t0 = b * 2048 + chunk * 64;
    const int tt0 = chunk * 64;              // t-offset inside vT's per-b 2048
    const int tid = threadIdx.x;
    const float scale = 0.0625f;

    // ---- stage 1: thread = d column ----
    {
        const int d = tid;
        const float* gcol = g + (size_t)t0 * DKC + h * HDK_ + d;
        const float* qcol = q + (size_t)t0 * DKC + h * HDK_ + d;
        const float* kcol = k + (size_t)t0 * DKC + h * HDK_ + d;
        float run = 0.f;
#pragma unroll
        for (int i = 0; i < 64; ++i) run += gcol[(size_t)i * DKC];
        const float ebl = expf(run);
        dlast[((size_t)bh * NCH + chunk) * HDK_ + d] = ebl;

        bf16x8 kreg[8];
        run = 0.f;
#pragma unroll
        for (int i = 0; i < 64; ++i) {
            run += gcol[(size_t)i * DKC];
            float eb = expf(run);
            float qv = qcol[(size_t)i * DKC] * eb * scale;
            float kdv = kcol[(size_t)i * DKC] * expf(-run);
            qg[(size_t)(t0 + i) * DKC + h * HDK_ + d] = __float2bfloat16(qv);
            int bq = ((i * 512 + d * 2) ^ ((i & 7) << 4)) >> 1;
            qg_l[bq] = f2bf_bits(qv);
            kd_l[bq] = f2bf_bits(kdv);
            kreg[i >> 3][i & 7] = f2bf_bits(kdv * ebl);   // kg = kd * exp(b_last)
        }
        __hip_bfloat16* kdst = kgT + ((size_t)(bh * HDK_ + d)) * 2048 + chunk * 64;
#pragma unroll
        for (int j = 0; j < 8; ++j)
            *reinterpret_cast<bf16x8*>(&kdst[j * 8]) = kreg[j];
    }
    __syncthreads();

    const int wv = tid >> 6, lane = tid & 63;
    const int l15 = lane & 15, kb = lane >> 4;

    // ---- stage 2: A = tril(qg @ kd^T), wave wv owns t-strip [wv*16, wv*16+16) ----
    {
        f32x4 accA[4];
#pragma unroll
        for (int sf = 0; sf < 4; ++sf) accA[sf] = (f32x4){0.f, 0.f, 0.f, 0.f};
        const int trow = wv * 16 + l15;
#pragma unroll
        for (int ks = 0; ks < 8; ++ks) {
            bf16x8 af = *reinterpret_cast<const bf16x8*>(
                &qg_l[((trow * 512 + (ks * 32 + kb * 8) * 2) ^ ((trow & 7) << 4)) >> 1]);
#pragma unroll
            for (int sf = 0; sf < 4; ++sf) {
                int srow = sf * 16 + l15;
                bf16x8 bfr = *reinterpret_cast<const bf16x8*>(
                    &kd_l[((srow * 512 + (ks * 32 + kb * 8) * 2) ^ ((srow & 7) << 4)) >> 1]);
                accA[sf] = __builtin_amdgcn_mfma_f32_16x16x32_bf16(af, bfr, accA[sf], 0, 0, 0);
            }
        }
#pragma unroll
        for (int sf = 0; sf < 4; ++sf)
#pragma unroll
            for (int r = 0; r < 4; ++r) {
                int t = wv * 16 + kb * 4 + r, s = sf * 16 + l15;
                float val = (t >= s) ? accA[sf][r] : 0.f;
                Am_l[((t * 128 + s * 2) ^ ((t & 7) << 4)) >> 1] = f2bf_bits(val);
            }
    }
    __syncthreads();   // stage-2 reads done; Am written

    // ---- stage 3: stage V (overwrites qg/kd region), then o = Am @ vT^T ----
    {
        const int lr8 = lane >> 3, slot = lane & 7;
#pragma unroll
        for (int i8 = 0; i8 < 16; ++i8) {
            int vrow0 = wv * 128 + i8 * 8;
            // rule-21: linear LDS dest, pre-swizzled global source slot
            const __hip_bfloat16* src =
                &vT[((size_t)bh * 512 + vrow0 + lr8) * 2048 + tt0 + (slot ^ (lr8 & 7)) * 8];
            gl_lds16(src, &V_l[vrow0 * 64]);
        }
    }
    __syncthreads();

    {
        f32x4 accO[4][8];
#pragma unroll
        for (int tf = 0; tf < 4; ++tf)
#pragma unroll
            for (int vf = 0; vf < 8; ++vf) accO[tf][vf] = (f32x4){0.f, 0.f, 0.f, 0.f};
#pragma unroll
        for (int kk = 0; kk < 2; ++kk) {
            bf16x8 af[4];
#pragma unroll
            for (int tf = 0; tf < 4; ++tf) {
                int row = tf * 16 + l15;
                af[tf] = *reinterpret_cast<const bf16x8*>(
                    &Am_l[((row * 128 + (kk * 32 + kb * 8) * 2) ^ ((row & 7) << 4)) >> 1]);
            }
#pragma unroll
            for (int vf = 0; vf < 8; ++vf) {
                int rv = wv * 128 + vf * 16 + l15;
                bf16x8 bfr = *reinterpret_cast<const bf16x8*>(
                    &V_l[((rv * 128 + (kk * 32 + kb * 8) * 2) ^ ((rv & 7) << 4)) >> 1]);
#pragma unroll
                for (int tf = 0; tf < 4; ++tf)
                    accO[tf][vf] = __builtin_amdgcn_mfma_f32_16x16x32_bf16(af[tf], bfr, accO[tf][vf], 0, 0, 0);
            }
        }
#pragma unroll
        for (int tf = 0; tf < 4; ++tf)
#pragma unroll
            for (int vf = 0; vf < 8; ++vf)
#pragma unroll
                for (int r = 0; r < 4; ++r) {
                    int t = tf * 16 + kb * 4 + r;
                    int vv = wv * 128 + vf * 16 + l15;
                    o[(size_t)(t0 + t) * DVC + h * HDV_ + vv] = accO[tf][vf][r];
                }
    }
}

// ---------------------------------------------------------------------------
// u_pass (MFMA): U'[bh][c][vc][d] bf16 = sum_t v[t][vc]*kg[t][d]
// ---------------------------------------------------------------------------
__global__ __launch_bounds__(256) void u_pass(const __hip_bfloat16* __restrict__ vT,
                                              const __hip_bfloat16* __restrict__ kgT,
                                              __hip_bfloat16* __restrict__ U) {
    __shared__ __align__(16) short Av[128 * 64];
    __shared__ __align__(16) short Bv[128 * 64];
    const int bx = blockIdx.x, c = blockIdx.y, bh = blockIdx.z;
    const int vc0 = (bx >> 1) * 128, d0 = (bx & 1) * 128;
    const int tid = threadIdx.x;
    const int wave = tid >> 6, lane = tid & 63;
    const int wr = wave >> 1, wc = wave & 1;
    const int l15 = lane & 15, kb = lane >> 4;
    const int lr8 = lane >> 3, lc8 = (lane & 7) * 8;

#pragma unroll
    for (int j = 0; j < 4; ++j) {
        int inst = wave * 4 + j;
        int r = inst * 8 + lr8;
        gl_lds16(&vT[((size_t)bh * 512 + vc0 + r) * 2048 + c * 64 + lc8], &Av[inst * 512]);
        gl_lds16(&kgT[((size_t)bh * HDK_ + d0 + r) * 2048 + c * 64 + lc8], &Bv[inst * 512]);
    }
    __syncthreads();

    f32x4 acc[4][4];
#pragma unroll
    for (int mf = 0; mf < 4; ++mf)
#pragma unroll
        for (int nf = 0; nf < 4; ++nf) acc[mf][nf] = (f32x4){0.f, 0.f, 0.f, 0.f};
#pragma unroll
    for (int kk = 0; kk < 2; ++kk) {
        bf16x8 af[4], bfr[4];
#pragma unroll
        for (int mf = 0; mf < 4; ++mf)
            af[mf] = *reinterpret_cast<const bf16x8*>(&Av[(wr * 64 + mf * 16 + l15) * 64 + kk * 32 + kb * 8]);
#pragma unroll
        for (int nf = 0; nf < 4; ++nf)
            bfr[nf] = *reinterpret_cast<const bf16x8*>(&Bv[(wc * 64 + nf * 16 + l15) * 64 + kk * 32 + kb * 8]);
#pragma unroll
        for (int mf = 0; mf < 4; ++mf)
#pragma unroll
            for (int nf = 0; nf < 4; ++nf)
                acc[mf][nf] = __builtin_amdgcn_mfma_f32_16x16x32_bf16(af[mf], bfr[nf], acc[mf][nf], 0, 0, 0);
    }
    const size_t Ub = ((size_t)bh * NCH + c) * 131072;
#pragma unroll
    for (int mf = 0; mf < 4; ++mf)
#pragma unroll
        for (int nf = 0; nf < 4; ++nf)
#pragma unroll
            for (int r = 0; r < 4; ++r) {
                int vc = vc0 + wr * 64 + mf * 16 + kb * 4 + r;
                int d = d0 + wc * 64 + nf * 16 + l15;
                U[Ub + (size_t)vc * 256 + d] = __float2bfloat16(acc[mf][nf][r]);
            }
}

// ---------------------------------------------------------------------------
// scan_pass on U'[bh][c][vc][d]: exclusive scan over chunks, decay e(d)
// ---------------------------------------------------------------------------
__global__ __launch_bounds__(256) void scan_pass(__hip_bfloat16* __restrict__ U,
                                                 const float* __restrict__ dlast) {
    int gid = blockIdx.x * 256 + threadIdx.x;   // 131072
    int bh = gid >> 14;
    int rem = gid & 16383;
    int vc = rem >> 5;
    int dg = rem & 31;
    float S[8];
#pragma unroll
    for (int j = 0; j < 8; ++j) S[j] = 0.f;
    size_t base = (size_t)bh * NCH * 131072 + (size_t)vc * 256 + dg * 8;
    for (int c = 0; c < NCH; ++c) {
        __hip_bfloat16* p = U + base + (size_t)c * 131072;
        bf16x8 u = *reinterpret_cast<bf16x8*>(p);
        const float* dl = &dlast[((size_t)bh * NCH + c) * HDK_ + dg * 8];
        float4 e0 = *reinterpret_cast<const float4*>(dl);
        float4 e1 = *reinterpret_cast<const float4*>(dl + 4);
        float e[8] = {e0.x, e0.y, e0.z, e0.w, e1.x, e1.y, e1.z, e1.w};
        bf16x8 outv;
#pragma unroll
        for (int j = 0; j < 8; ++j) {
            outv[j] = f2bf_bits(S[j]);
            S[j] = S[j] * e[j] + bf2f(u[j]);
        }
        *reinterpret_cast<bf16x8*>(p) = outv;
    }
}

// ---------------------------------------------------------------------------
// o_pass (MFMA): o[t][vc] += sum_d qg[t][d] * S'[vc][d]
// ---------------------------------------------------------------------------
__global__ __launch_bounds__(256) void o_pass(const __hip_bfloat16* __restrict__ qg,
                                              const __hip_bfloat16* __restrict__ U,
                                              float* __restrict__ o) {
    __shared__ __align__(16) char smem[128 * 68 * 4];
    short* Av = (short*)smem;               // 128x64 bf16 = 16 KB
    short* Bv = (short*)smem + 128 * 64;    // 64x64 bf16 = 8 KB
    float* oT = (float*)smem;               // 128x68 f32 (epilogue, aliases)
    const int vt = blockIdx.x, c = blockIdx.y, bh = blockIdx.z;
    const int b = bh >> 2, h = bh & 3;
    const int vc0 = vt * 128;
    const int t0 = b * 2048 + c * 64;
    const int tid = threadIdx.x;
    const int wave = tid >> 6, lane = tid & 63;
    const int wr = wave >> 1, wc = wave & 1;
    const int l15 = lane & 15, kb = lane >> 4;
    const int lr8 = lane >> 3, lc8 = (lane & 7) * 8;
    const size_t Ub = ((size_t)bh * NCH + c) * 131072;

    f32x4 acc[4][2];
#pragma unroll
    for (int mf = 0; mf < 4; ++mf)
#pragma unroll
        for (int nf = 0; nf < 2; ++nf) acc[mf][nf] = (f32x4){0.f, 0.f, 0.f, 0.f};

    for (int ks = 0; ks < 4; ++ks) {
        const int d0 = ks * 64;
#pragma unroll
        for (int j = 0; j < 4; ++j) {
            int inst = wave * 4 + j;
            int r = inst * 8 + lr8;
            gl_lds16(&U[Ub + (size_t)(vc0 + r) * 256 + d0 + lc8], &Av[inst * 512]);
        }
#pragma unroll
        for (int j = 0; j < 2; ++j) {
            int inst = wave * 2 + j;
            int r = inst * 8 + lr8;
            gl_lds16(&qg[(size_t)(t0 + r) * DKC + h * HDK_ + d0 + lc8], &Bv[inst * 512]);
        }
        __syncthreads();
#pragma unroll
        for (int kk = 0; kk < 2; ++kk) {
            bf16x8 af[4], bfr[2];
#pragma unroll
            for (int mf = 0; mf < 4; ++mf)
                af[mf] = *reinterpret_cast<const bf16x8*>(&Av[(wr * 64 + mf * 16 + l15) * 64 + kk * 32 + kb * 8]);
#pragma unroll
            for (int nf = 0; nf < 2; ++nf)
                bfr[nf] = *reinterpret_cast<const bf16x8*>(&Bv[(wc * 32 + nf * 16 + l15) * 64 + kk * 32 + kb * 8]);
#pragma unroll
            for (int mf = 0; mf < 4; ++mf)
#pragma unroll
                for (int nf = 0; nf < 2; ++nf)
                    acc[mf][nf] = __builtin_amdgcn_mfma_f32_16x16x32_bf16(af[mf], bfr[nf], acc[mf][nf], 0, 0, 0);
        }
        __syncthreads();
    }
#pragma unroll
    for (int mf = 0; mf < 4; ++mf)
#pragma unroll
        for (int nf = 0; nf < 2; ++nf)
#pragma unroll
            for (int r = 0; r < 4; ++r)
                oT[(wr * 64 + mf * 16 + kb * 4 + r) * 68 + wc * 32 + nf * 16 + l15] = acc[mf][nf][r];
    __syncthreads();
#pragma unroll
    for (int j = 0; j < 8; ++j) {
        int t = (tid >> 5) + j * 8;
        int vc4 = (tid & 31) * 4;
        float4 add = make_float4(oT[(vc4 + 0) * 68 + t], oT[(vc4 + 1) * 68 + t],
                                 oT[(vc4 + 2) * 68 + t], oT[(vc4 + 3) * 68 + t]);
        size_t oi = (size_t)(t0 + t) * DVC + h * HDV_ + vc0 + vc4;
        float4 cur = *reinterpret_cast<const float4*>(&o[oi]);
        cur.x += add.x; cur.y += add.y; cur.z += add.z; cur.w += add.w;
        *reinterpret_cast<float4*>(&o[oi]) = cur;
    }
}

// ---------------------------------------------------------------------------
// RMSNorm * rms_w * silu(xg)  ->  gated (bf16)
// ---------------------------------------------------------------------------
__global__ __launch_bounds__(256) void rms_gate(const float* __restrict__ o,
                                                const float* __restrict__ xg,
                                                const float* __restrict__ rms_w,
                                                __hip_bfloat16* __restrict__ gated) {
    __shared__ float wsum[4];
    const int th = blockIdx.x;
    const int t = th >> 2, h = th & 3;
    const int tid = threadIdx.x;
    const size_t base = (size_t)t * DVC + h * HDV_;
    float v0 = o[base + tid], v1 = o[base + 256 + tid];
    float s = v0 * v0 + v1 * v1;
#pragma unroll
    for (int off = 32; off >= 1; off >>= 1) s += __shfl_down(s, off, 64);
    if ((tid & 63) == 0) wsum[tid >> 6] = s;
    __syncthreads();
    float tot = wsum[0] + wsum[1] + wsum[2] + wsum[3];
    float rms = rsqrtf(tot * (1.f / 512.f) + 1e-5f);
    float g0 = xg[base + tid], g1 = xg[base + 256 + tid];
    float s0 = g0 / (1.f + expf(-g0));
    float s1 = g1 / (1.f + expf(-g1));
    gated[base + tid]       = __float2bfloat16(v0 * rms * rms_w[tid] * s0);
    gated[base + 256 + tid] = __float2bfloat16(v1 * rms * rms_w[256 + tid] * s1);
}

// ---------------------------------------------------------------------------
extern "C" void kernel_launch(void* const* d_in, const int* in_sizes, int n_in,
                              void* d_out, int out_size, void* d_ws, size_t ws_size,
                              hipStream_t stream) {
    const float* x    = (const float*)d_in[0];
    const float* Wq   = (const float*)d_in[1];
    const float* Wk   = (const float*)d_in[2];
    const float* Wv   = (const float*)d_in[3];
    const float* Wg   = (const float*)d_in[4];
    const float* Wgk1 = (const float*)d_in[5];
    const float* Wgk2 = (const float*)d_in[6];
    const float* bgk2 = (const float*)d_in[7];
    const float* Wo   = (const float*)d_in[8];
    const float* rmsw = (const float*)d_in[9];
    float* out = (float*)d_out;
    float* ws = (float*)d_ws;

    const size_t M1 = 1ull << 20;   // floats
    float* q   = ws;                 // [0,4M)
    float* kbf = ws + 4 * M1;        // [4M,8M)
    float* g   = ws + 8 * M1;        // [8M,12M)
    __hip_bfloat16* xb  = (__hip_bfloat16*)(ws + 12 * M1);            // 8 MB
    __hip_bfloat16* Wtq = (__hip_bfloat16*)(ws + 14 * M1);            // 2 MB
    __hip_bfloat16* Wtk = (__hip_bfloat16*)(ws + 14 * M1 + 524288);   // 2 MB
    __hip_bfloat16* Wtv = (__hip_bfloat16*)(ws + 15 * M1);            // 4 MB
    __hip_bfloat16* Wtg = (__hip_bfloat16*)(ws + 16 * M1);            // 4 MB
    __hip_bfloat16* U   = (__hip_bfloat16*)ws;                        // [0,16M floats) = 64 MB
    float* v    = ws + 17 * M1;      // [17M,25M) 32 MB
    float* xg   = ws + 25 * M1;      // [25M,33M) 32 MB
    __hip_bfloat16* qgb = (__hip_bfloat16*)(ws + 33 * M1);   // 8 MB
    __hip_bfloat16* kgT = (__hip_bfloat16*)(ws + 35 * M1);   // 8 MB
    __hip_bfloat16* vT  = (__hip_bfloat16*)(ws + 37 * M1);   // 16 MB
    float* o    = ws + 41 * M1;      // [41M,49M) 32 MB
    float* t1   = ws + 49 * M1;             // 256 KB
    float* dlast = ws + 49 * M1 + 65536;    // 256 KB
    __hip_bfloat16* WtO   = (__hip_bfloat16*)(ws + 17 * M1); // 4 MB (v dead)
    __hip_bfloat16* gated = (__hip_bfloat16*)(ws + 18 * M1); // 16 MB

    conv_bf16<<<4096, 256, 0, stream>>>(x, xb);
    convT<<<dim3(32, 32), 256, 0, stream>>>(Wq, Wtq, DM, DKC);
    convT<<<dim3(32, 32), 256, 0, stream>>>(Wk, Wtk, DM, DKC);
    convT<<<dim3(64, 32), 256, 0, stream>>>(Wv, Wtv, DM, DVC);
    convT<<<dim3(64, 32), 256, 0, stream>>>(Wg, Wtg, DM, DVC);

    gemm_bf16<<<dim3(8, 32),  256, 0, stream>>>(xb, Wtq, q,   TOK, DKC, DM);
    gemm_bf16<<<dim3(8, 32),  256, 0, stream>>>(xb, Wtk, kbf, TOK, DKC, DM);
    gemm_bf16<<<dim3(16, 32), 256, 0, stream>>>(xb, Wtv, v,   TOK, DVC, DM);
    gemm_bf16<<<dim3(16, 32), 256, 0, stream>>>(xb, Wtg, xg,  TOK, DVC, DM);

    transpose_v<<<dim3(64, 128), 256, 0, stream>>>(v, vT);
    lowrank1<<<TOK, 256, 0, stream>>>(x, Wgk1, t1);
    gate_k<<<(TOK * DKC) / 256, 256, 0, stream>>>(t1, Wgk2, bgk2, g);
    gla_chunk<<<dim3(NCH, 8), 256, 0, stream>>>(q, kbf, vT, g, qgb, kgT, o, dlast);

    u_pass<<<dim3(8, NCH, 8), 256, 0, stream>>>(vT, kgT, U);
    scan_pass<<<512, 256, 0, stream>>>(U, dlast);
    o_pass<<<dim3(4, NCH, 8), 256, 0, stream>>>(qgb, U, o);

    convT<<<dim3(32, 64), 256, 0, stream>>>(Wo, WtO, DVC, DM);
    rms_gate<<<TOK * NH, 256, 0, stream>>>(o, xg, rmsw, gated);
    gemm_bf16<<<dim3(8, 32), 256, 0, stream>>>(gated, WtO, out, TOK, DM, DVC);
}

// Round 8
// 301.301 us; speedup vs baseline: 5.2158x; 1.1185x over previous
//
#include <hip/hip_runtime.h>
#include <hip/hip_bf16.h>
#include <math.h>

#define TOK  4096
#define DM   1024
#define DKC  1024
#define DVC  2048
#define NH   4
#define HDK_ 256
#define HDV_ 512
#define NCH  32
#define CHK  64

typedef __attribute__((ext_vector_type(8))) short bf16x8;
typedef __attribute__((ext_vector_type(4))) float f32x4;

__device__ inline float bf2f(short s) {
    unsigned int b = ((unsigned int)(unsigned short)s) << 16;
    return __uint_as_float(b);
}
__device__ inline short f2bf_bits(float f) {
    __hip_bfloat16 h = __float2bfloat16(f);
    return *reinterpret_cast<short*>(&h);
}

// async global->LDS, 16B per lane; lds dest = base + lane*16 (wave-uniform base)
__device__ __forceinline__ void gl_lds16(const void* g, void* l) {
    __builtin_amdgcn_global_load_lds((const __attribute__((address_space(1))) void*)g,
                                     (__attribute__((address_space(3))) void*)l, 16, 0, 0);
}

// ---------------------------------------------------------------------------
// x (f32) -> bf16 copy
// ---------------------------------------------------------------------------
__global__ __launch_bounds__(256) void conv_bf16(const float* __restrict__ in,
                                                 __hip_bfloat16* __restrict__ out) {
    size_t i = ((size_t)blockIdx.x * 256 + threadIdx.x) * 4;
    float4 v = *reinterpret_cast<const float4*>(&in[i]);
    out[i + 0] = __float2bfloat16(v.x);
    out[i + 1] = __float2bfloat16(v.y);
    out[i + 2] = __float2bfloat16(v.z);
    out[i + 3] = __float2bfloat16(v.w);
}

// ---------------------------------------------------------------------------
// W[K][N] f32 -> Wt[N][K] bf16 (tiled transpose); grid = dim3(N/32, K/32)
// ---------------------------------------------------------------------------
__global__ __launch_bounds__(256) void convT(const float* __restrict__ W,
                                             __hip_bfloat16* __restrict__ Wt,
                                             int K, int N) {
    __shared__ float tile[32][33];
    int n0 = blockIdx.x * 32, k0 = blockIdx.y * 32;
    int tx = threadIdx.x & 31, ty = threadIdx.x >> 5;
#pragma unroll
    for (int i = 0; i < 32; i += 8)
        tile[ty + i][tx] = W[(size_t)(k0 + ty + i) * N + n0 + tx];
    __syncthreads();
#pragma unroll
    for (int i = 0; i < 32; i += 8)
        Wt[(size_t)(n0 + ty + i) * K + k0 + tx] = __float2bfloat16(tile[tx][ty + i]);
}

// ---------------------------------------------------------------------------
// v bf16 [4096t][2048] -> vT bf16 [bh=8][512vc][2048t]
// ---------------------------------------------------------------------------
__global__ __launch_bounds__(256) void transpose_v(const __hip_bfloat16* __restrict__ v,
                                                   __hip_bfloat16* __restrict__ vT) {
    __shared__ short tile[32][33];
    const int tg0 = blockIdx.y * 32;
    const int vg0 = blockIdx.x * 32;
    const int tx = threadIdx.x & 31, ty = threadIdx.x >> 5;
    const short* vs = (const short*)v;
#pragma unroll
    for (int i = 0; i < 32; i += 8)
        tile[ty + i][tx] = vs[(size_t)(tg0 + ty + i) * DVC + vg0 + tx];
    __syncthreads();
    const int b = tg0 >> 11, tl0 = tg0 & 2047;
    const int h = vg0 >> 9, vl0 = vg0 & 511;
    const int bh = b * NH + h;
    short* vTs = (short*)vT;
#pragma unroll
    for (int i = 0; i < 32; i += 8)
        vTs[((size_t)bh * 512 + vl0 + ty + i) * 2048 + tl0 + tx] = tile[tx][ty + i];
}

// ---------------------------------------------------------------------------
// FUSED projection GEMM: A=xb[4096][1024] @ WtAll[6144][1024]^T
// n-segment -> {q,k:1024 | v:2048 | xg:2048} bf16 outputs. grid (48, 32).
// ---------------------------------------------------------------------------
__global__ __launch_bounds__(256) void gemm_multi(const __hip_bfloat16* __restrict__ A,
                                                  const __hip_bfloat16* __restrict__ Wt,
                                                  __hip_bfloat16* __restrict__ qo,
                                                  __hip_bfloat16* __restrict__ ko,
                                                  __hip_bfloat16* __restrict__ vo,
                                                  __hip_bfloat16* __restrict__ xgo) {
    __shared__ __align__(16) short Al[128 * 64];
    __shared__ __align__(16) short Bl[128 * 64];
    const int K = 1024;
    const int tid = threadIdx.x;
    const int wave = tid >> 6, lane = tid & 63;
    const int wr = wave >> 1, wc = wave & 1;
    const int m0 = blockIdx.y * 128, n0 = blockIdx.x * 128;
    const int l15 = lane & 15, kb = lane >> 4;
    const int lr8 = lane >> 3, lc8 = (lane & 7) * 8;

    __hip_bfloat16* dst; int ldd, nloc0;
    if (n0 < 1024)      { dst = qo;  ldd = 1024; nloc0 = n0; }
    else if (n0 < 2048) { dst = ko;  ldd = 1024; nloc0 = n0 - 1024; }
    else if (n0 < 4096) { dst = vo;  ldd = 2048; nloc0 = n0 - 2048; }
    else                { dst = xgo; ldd = 2048; nloc0 = n0 - 4096; }

    f32x4 acc[4][4];
#pragma unroll
    for (int mf = 0; mf < 4; ++mf)
#pragma unroll
        for (int nf = 0; nf < 4; ++nf) acc[mf][nf] = (f32x4){0.f, 0.f, 0.f, 0.f};

    for (int k0 = 0; k0 < K; k0 += 64) {
#pragma unroll
        for (int j = 0; j < 4; ++j) {
            int inst = wave * 4 + j;
            int r = inst * 8 + lr8;
            gl_lds16(&A[(size_t)(m0 + r) * K + k0 + lc8], &Al[inst * 512]);
            gl_lds16(&Wt[(size_t)(n0 + r) * K + k0 + lc8], &Bl[inst * 512]);
        }
        __syncthreads();
#pragma unroll
        for (int kk = 0; kk < 2; ++kk) {
            bf16x8 af[4], bfr[4];
#pragma unroll
            for (int mf = 0; mf < 4; ++mf)
                af[mf] = *reinterpret_cast<const bf16x8*>(&Al[(wr * 64 + mf * 16 + l15) * 64 + kk * 32 + kb * 8]);
#pragma unroll
            for (int nf = 0; nf < 4; ++nf)
                bfr[nf] = *reinterpret_cast<const bf16x8*>(&Bl[(wc * 64 + nf * 16 + l15) * 64 + kk * 32 + kb * 8]);
#pragma unroll
            for (int mf = 0; mf < 4; ++mf)
#pragma unroll
                for (int nf = 0; nf < 4; ++nf)
                    acc[mf][nf] = __builtin_amdgcn_mfma_f32_16x16x32_bf16(af[mf], bfr[nf], acc[mf][nf], 0, 0, 0);
        }
        __syncthreads();
    }
#pragma unroll
    for (int mf = 0; mf < 4; ++mf)
#pragma unroll
        for (int nf = 0; nf < 4; ++nf)
#pragma unroll
            for (int r = 0; r < 4; ++r)
                dst[(size_t)(m0 + wr * 64 + mf * 16 + kb * 4 + r) * ldd +
                    nloc0 + wc * 64 + nf * 16 + l15] = __float2bfloat16(acc[mf][nf][r]);
}

// ---------------------------------------------------------------------------
// bf16 MFMA GEMM with f32 C (final Wo projection)
// ---------------------------------------------------------------------------
__global__ __launch_bounds__(256) void gemm_bf16(const __hip_bfloat16* __restrict__ A,
                                                 const __hip_bfloat16* __restrict__ Wt,
                                                 float* __restrict__ C,
                                                 int M, int N, int K) {
    __shared__ __align__(16) short Al[128 * 64];
    __shared__ __align__(16) short Bl[128 * 64];
    const int tid = threadIdx.x;
    const int wave = tid >> 6, lane = tid & 63;
    const int wr = wave >> 1, wc = wave & 1;
    const int m0 = blockIdx.y * 128, n0 = blockIdx.x * 128;
    const int l15 = lane & 15, kb = lane >> 4;
    const int lr8 = lane >> 3, lc8 = (lane & 7) * 8;
    f32x4 acc[4][4];
#pragma unroll
    for (int mf = 0; mf < 4; ++mf)
#pragma unroll
        for (int nf = 0; nf < 4; ++nf) acc[mf][nf] = (f32x4){0.f, 0.f, 0.f, 0.f};

    for (int k0 = 0; k0 < K; k0 += 64) {
#pragma unroll
        for (int j = 0; j < 4; ++j) {
            int inst = wave * 4 + j;
            int r = inst * 8 + lr8;
            gl_lds16(&A[(size_t)(m0 + r) * K + k0 + lc8], &Al[inst * 512]);
            gl_lds16(&Wt[(size_t)(n0 + r) * K + k0 + lc8], &Bl[inst * 512]);
        }
        __syncthreads();
#pragma unroll
        for (int kk = 0; kk < 2; ++kk) {
            bf16x8 af[4], bfr[4];
#pragma unroll
            for (int mf = 0; mf < 4; ++mf)
                af[mf] = *reinterpret_cast<const bf16x8*>(&Al[(wr * 64 + mf * 16 + l15) * 64 + kk * 32 + kb * 8]);
#pragma unroll
            for (int nf = 0; nf < 4; ++nf)
                bfr[nf] = *reinterpret_cast<const bf16x8*>(&Bl[(wc * 64 + nf * 16 + l15) * 64 + kk * 32 + kb * 8]);
#pragma unroll
            for (int mf = 0; mf < 4; ++mf)
#pragma unroll
                for (int nf = 0; nf < 4; ++nf)
                    acc[mf][nf] = __builtin_amdgcn_mfma_f32_16x16x32_bf16(af[mf], bfr[nf], acc[mf][nf], 0, 0, 0);
        }
        __syncthreads();
    }
#pragma unroll
    for (int mf = 0; mf < 4; ++mf)
#pragma unroll
        for (int nf = 0; nf < 4; ++nf)
#pragma unroll
            for (int r = 0; r < 4; ++r)
                C[(size_t)(m0 + wr * 64 + mf * 16 + kb * 4 + r) * N + n0 + wc * 64 + nf * 16 + l15] =
                    acc[mf][nf][r];
}

// ---------------------------------------------------------------------------
// t1 = x @ Wgk1
// ---------------------------------------------------------------------------
__global__ __launch_bounds__(256) void lowrank1(const float* __restrict__ x,
                                                const float* __restrict__ W1,
                                                float* __restrict__ t1) {
    __shared__ float red[16][17];
    const int t = blockIdx.x;
    const int tid = threadIdx.x;
    const int o = tid & 15;
    const int p = tid >> 4;
    float s = 0.f;
#pragma unroll 8
    for (int m = 0; m < 64; ++m) {
        int kk = p * 64 + m;
        s += x[(size_t)t * DM + kk] * W1[kk * 16 + o];
    }
    red[p][o] = s;
    __syncthreads();
    if (tid < 16) {
        float tot = 0.f;
#pragma unroll
        for (int pp = 0; pp < 16; ++pp) tot += red[pp][tid];
        t1[(size_t)t * 16 + tid] = tot;
    }
}

// ---------------------------------------------------------------------------
// g = log_sigmoid(t1 @ Wgk2 + b) / 16
// ---------------------------------------------------------------------------
__global__ __launch_bounds__(256) void gate_k(const float* __restrict__ t1,
                                              const float* __restrict__ W2,
                                              const float* __restrict__ b2,
                                              float* __restrict__ g) {
    const size_t idx = (size_t)blockIdx.x * 256 + threadIdx.x;
    const int t = (int)(idx >> 10), c = (int)(idx & 1023);
    float acc = b2[c];
#pragma unroll
    for (int r = 0; r < 16; ++r) acc += t1[(size_t)t * 16 + r] * W2[r * 1024 + c];
    float ls = fminf(acc, 0.f) - log1pf(expf(-fabsf(acc)));
    g[idx] = ls * (1.f / 16.f);
}

// ---------------------------------------------------------------------------
// gla_chunk (MFMA): q,k inputs bf16
// ---------------------------------------------------------------------------
__global__ __launch_bounds__(256) void gla_chunk(const __hip_bfloat16* __restrict__ qb,
                                                 const __hip_bfloat16* __restrict__ kb,
                                                 const __hip_bfloat16* __restrict__ vT,
                                                 const float* __restrict__ g,
                                                 __hip_bfloat16* __restrict__ qg,
                                                 __hip_bfloat16* __restrict__ kgT,
                                                 float* __restrict__ o,
                                                 float* __restrict__ dlast) {
    __shared__ __align__(16) short SM[36864];   // 72 KB
    short* qg_l = SM;            // rows t: 256 shorts (512B)
    short* kd_l = SM + 16384;
    short* V_l  = SM;            // alias: 512 rows x 64 shorts (128B rows)
    short* Am_l = SM + 32768;    // 64x64 (128B rows)

    const int chunk = blockIdx.x, bh = blockIdx.y;
    const int b = bh >> 2, h = bh & 3;
    const int t0 = b * 2048 + chunk * 64;
    const int tt0 = chunk * 64;
    const int tid = threadIdx.x;
    const float scale = 0.0625f;

    // ---- stage 1: thread = d column ----
    {
        const int d = tid;
        const float* gcol = g + (size_t)t0 * DKC + h * HDK_ + d;
        const __hip_bfloat16* qcol = qb + (size_t)t0 * DKC + h * HDK_ + d;
        const __hip_bfloat16* kcol = kb + (size_t)t0 * DKC + h * HDK_ + d;
        float run = 0.f;
#pragma unroll
        for (int i = 0; i < 64; ++i) run += gcol[(size_t)i * DKC];
        const float ebl = expf(run);
        dlast[((size_t)bh * NCH + chunk) * HDK_ + d] = ebl;

        bf16x8 kreg[8];
        run = 0.f;
#pragma unroll
        for (int i = 0; i < 64; ++i) {
            run += gcol[(size_t)i * DKC];
            float eb = expf(run);
            float qv = __bfloat162float(qcol[(size_t)i * DKC]) * eb * scale;
            float kdv = __bfloat162float(kcol[(size_t)i * DKC]) * expf(-run);
            qg[(size_t)(t0 + i) * DKC + h * HDK_ + d] = __float2bfloat16(qv);
            int bq = ((i * 512 + d * 2) ^ ((i & 7) << 4)) >> 1;
            qg_l[bq] = f2bf_bits(qv);
            kd_l[bq] = f2bf_bits(kdv);
            kreg[i >> 3][i & 7] = f2bf_bits(kdv * ebl);   // kg = kd * exp(b_last)
        }
        __hip_bfloat16* kdst = kgT + ((size_t)(bh * HDK_ + d)) * 2048 + chunk * 64;
#pragma unroll
        for (int j = 0; j < 8; ++j)
            *reinterpret_cast<bf16x8*>(&kdst[j * 8]) = kreg[j];
    }
    __syncthreads();

    const int wv = tid >> 6, lane = tid & 63;
    const int l15 = lane & 15, kb_ = lane >> 4;

    // ---- stage 2: A = tril(qg @ kd^T) ----
    {
        f32x4 accA[4];
#pragma unroll
        for (int sf = 0; sf < 4; ++sf) accA[sf] = (f32x4){0.f, 0.f, 0.f, 0.f};
        const int trow = wv * 16 + l15;
#pragma unroll
        for (int ks = 0; ks < 8; ++ks) {
            bf16x8 af = *reinterpret_cast<const bf16x8*>(
                &qg_l[((trow * 512 + (ks * 32 + kb_ * 8) * 2) ^ ((trow & 7) << 4)) >> 1]);
#pragma unroll
            for (int sf = 0; sf < 4; ++sf) {
                int srow = sf * 16 + l15;
                bf16x8 bfr = *reinterpret_cast<const bf16x8*>(
                    &kd_l[((srow * 512 + (ks * 32 + kb_ * 8) * 2) ^ ((srow & 7) << 4)) >> 1]);
                accA[sf] = __builtin_amdgcn_mfma_f32_16x16x32_bf16(af, bfr, accA[sf], 0, 0, 0);
            }
        }
#pragma unroll
        for (int sf = 0; sf < 4; ++sf)
#pragma unroll
            for (int r = 0; r < 4; ++r) {
                int t = wv * 16 + kb_ * 4 + r, s = sf * 16 + l15;
                float val = (t >= s) ? accA[sf][r] : 0.f;
                Am_l[((t * 128 + s * 2) ^ ((t & 7) << 4)) >> 1] = f2bf_bits(val);
            }
    }
    __syncthreads();

    // ---- stage 3: stage V, then o = Am @ vT^T ----
    {
        const int lr8 = lane >> 3, slot = lane & 7;
#pragma unroll
        for (int i8 = 0; i8 < 16; ++i8) {
            int vrow0 = wv * 128 + i8 * 8;
            const __hip_bfloat16* src =
                &vT[((size_t)bh * 512 + vrow0 + lr8) * 2048 + tt0 + (slot ^ (lr8 & 7)) * 8];
            gl_lds16(src, &V_l[vrow0 * 64]);
        }
    }
    __syncthreads();

    {
        f32x4 accO[4][8];
#pragma unroll
        for (int tf = 0; tf < 4; ++tf)
#pragma unroll
            for (int vf = 0; vf < 8; ++vf) accO[tf][vf] = (f32x4){0.f, 0.f, 0.f, 0.f};
#pragma unroll
        for (int kk = 0; kk < 2; ++kk) {
            bf16x8 af[4];
#pragma unroll
            for (int tf = 0; tf < 4; ++tf) {
                int row = tf * 16 + l15;
                af[tf] = *reinterpret_cast<const bf16x8*>(
                    &Am_l[((row * 128 + (kk * 32 + kb_ * 8) * 2) ^ ((row & 7) << 4)) >> 1]);
            }
#pragma unroll
            for (int vf = 0; vf < 8; ++vf) {
                int rv = wv * 128 + vf * 16 + l15;
                bf16x8 bfr = *reinterpret_cast<const bf16x8*>(
                    &V_l[((rv * 128 + (kk * 32 + kb_ * 8) * 2) ^ ((rv & 7) << 4)) >> 1]);
#pragma unroll
                for (int tf = 0; tf < 4; ++tf)
                    accO[tf][vf] = __builtin_amdgcn_mfma_f32_16x16x32_bf16(af[tf], bfr, accO[tf][vf], 0, 0, 0);
            }
        }
#pragma unroll
        for (int tf = 0; tf < 4; ++tf)
#pragma unroll
            for (int vf = 0; vf < 8; ++vf)
#pragma unroll
                for (int r = 0; r < 4; ++r) {
                    int t = tf * 16 + kb_ * 4 + r;
                    int vv = wv * 128 + vf * 16 + l15;
                    o[(size_t)(t0 + t) * DVC + h * HDV_ + vv] = accO[tf][vf][r];
                }
    }
}

// ---------------------------------------------------------------------------
// u_pass (MFMA): U'[bh][c][vc][d] bf16 = sum_t v[t][vc]*kg[t][d]
// ---------------------------------------------------------------------------
__global__ __launch_bounds__(256) void u_pass(const __hip_bfloat16* __restrict__ vT,
                                              const __hip_bfloat16* __restrict__ kgT,
                                              __hip_bfloat16* __restrict__ U) {
    __shared__ __align__(16) short Av[128 * 64];
    __shared__ __align__(16) short Bv[128 * 64];
    const int bx = blockIdx.x, c = blockIdx.y, bh = blockIdx.z;
    const int vc0 = (bx >> 1) * 128, d0 = (bx & 1) * 128;
    const int tid = threadIdx.x;
    const int wave = tid >> 6, lane = tid & 63;
    const int wr = wave >> 1, wc = wave & 1;
    const int l15 = lane & 15, kb = lane >> 4;
    const int lr8 = lane >> 3, lc8 = (lane & 7) * 8;

#pragma unroll
    for (int j = 0; j < 4; ++j) {
        int inst = wave * 4 + j;
        int r = inst * 8 + lr8;
        gl_lds16(&vT[((size_t)bh * 512 + vc0 + r) * 2048 + c * 64 + lc8], &Av[inst * 512]);
        gl_lds16(&kgT[((size_t)bh * HDK_ + d0 + r) * 2048 + c * 64 + lc8], &Bv[inst * 512]);
    }
    __syncthreads();

    f32x4 acc[4][4];
#pragma unroll
    for (int mf = 0; mf < 4; ++mf)
#pragma unroll
        for (int nf = 0; nf < 4; ++nf) acc[mf][nf] = (f32x4){0.f, 0.f, 0.f, 0.f};
#pragma unroll
    for (int kk = 0; kk < 2; ++kk) {
        bf16x8 af[4], bfr[4];
#pragma unroll
        for (int mf = 0; mf < 4; ++mf)
            af[mf] = *reinterpret_cast<const bf16x8*>(&Av[(wr * 64 + mf * 16 + l15) * 64 + kk * 32 + kb * 8]);
#pragma unroll
        for (int nf = 0; nf < 4; ++nf)
            bfr[nf] = *reinterpret_cast<const bf16x8*>(&Bv[(wc * 64 + nf * 16 + l15) * 64 + kk * 32 + kb * 8]);
#pragma unroll
        for (int mf = 0; mf < 4; ++mf)
#pragma unroll
            for (int nf = 0; nf < 4; ++nf)
                acc[mf][nf] = __builtin_amdgcn_mfma_f32_16x16x32_bf16(af[mf], bfr[nf], acc[mf][nf], 0, 0, 0);
    }
    const size_t Ub = ((size_t)bh * NCH + c) * 131072;
#pragma unroll
    for (int mf = 0; mf < 4; ++mf)
#pragma unroll
        for (int nf = 0; nf < 4; ++nf)
#pragma unroll
            for (int r = 0; r < 4; ++r) {
                int vc = vc0 + wr * 64 + mf * 16 + kb * 4 + r;
                int d = d0 + wc * 64 + nf * 16 + l15;
                U[Ub + (size_t)vc * 256 + d] = __float2bfloat16(acc[mf][nf][r]);
            }
}

// ---------------------------------------------------------------------------
// scan_pass on U'[bh][c][vc][d]: exclusive scan over chunks, decay e(d)
// ---------------------------------------------------------------------------
__global__ __launch_bounds__(256) void scan_pass(__hip_bfloat16* __restrict__ U,
                                                 const float* __restrict__ dlast) {
    int gid = blockIdx.x * 256 + threadIdx.x;   // 131072
    int bh = gid >> 14;
    int rem = gid & 16383;
    int vc = rem >> 5;
    int dg = rem & 31;
    float S[8];
#pragma unroll
    for (int j = 0; j < 8; ++j) S[j] = 0.f;
    size_t base = (size_t)bh * NCH * 131072 + (size_t)vc * 256 + dg * 8;
    for (int c = 0; c < NCH; ++c) {
        __hip_bfloat16* p = U + base + (size_t)c * 131072;
        bf16x8 u = *reinterpret_cast<bf16x8*>(p);
        const float* dl = &dlast[((size_t)bh * NCH + c) * HDK_ + dg * 8];
        float4 e0 = *reinterpret_cast<const float4*>(dl);
        float4 e1 = *reinterpret_cast<const float4*>(dl + 4);
        float e[8] = {e0.x, e0.y, e0.z, e0.w, e1.x, e1.y, e1.z, e1.w};
        bf16x8 outv;
#pragma unroll
        for (int j = 0; j < 8; ++j) {
            outv[j] = f2bf_bits(S[j]);
            S[j] = S[j] * e[j] + bf2f(u[j]);
        }
        *reinterpret_cast<bf16x8*>(p) = outv;
    }
}

// ---------------------------------------------------------------------------
// o_pass (MFMA): o[t][vc] += sum_d qg[t][d] * S'[vc][d]
// ---------------------------------------------------------------------------
__global__ __launch_bounds__(256) void o_pass(const __hip_bfloat16* __restrict__ qg,
                                              const __hip_bfloat16* __restrict__ U,
                                              float* __restrict__ o) {
    __shared__ __align__(16) char smem[128 * 68 * 4];
    short* Av = (short*)smem;
    short* Bv = (short*)smem + 128 * 64;
    float* oT = (float*)smem;
    const int vt = blockIdx.x, c = blockIdx.y, bh = blockIdx.z;
    const int b = bh >> 2, h = bh & 3;
    const int vc0 = vt * 128;
    const int t0 = b * 2048 + c * 64;
    const int tid = threadIdx.x;
    const int wave = tid >> 6, lane = tid & 63;
    const int wr = wave >> 1, wc = wave & 1;
    const int l15 = lane & 15, kb = lane >> 4;
    const int lr8 = lane >> 3, lc8 = (lane & 7) * 8;
    const size_t Ub = ((size_t)bh * NCH + c) * 131072;

    f32x4 acc[4][2];
#pragma unroll
    for (int mf = 0; mf < 4; ++mf)
#pragma unroll
        for (int nf = 0; nf < 2; ++nf) acc[mf][nf] = (f32x4){0.f, 0.f, 0.f, 0.f};

    for (int ks = 0; ks < 4; ++ks) {
        const int d0 = ks * 64;
#pragma unroll
        for (int j = 0; j < 4; ++j) {
            int inst = wave * 4 + j;
            int r = inst * 8 + lr8;
            gl_lds16(&U[Ub + (size_t)(vc0 + r) * 256 + d0 + lc8], &Av[inst * 512]);
        }
#pragma unroll
        for (int j = 0; j < 2; ++j) {
            int inst = wave * 2 + j;
            int r = inst * 8 + lr8;
            gl_lds16(&qg[(size_t)(t0 + r) * DKC + h * HDK_ + d0 + lc8], &Bv[inst * 512]);
        }
        __syncthreads();
#pragma unroll
        for (int kk = 0; kk < 2; ++kk) {
            bf16x8 af[4], bfr[2];
#pragma unroll
            for (int mf = 0; mf < 4; ++mf)
                af[mf] = *reinterpret_cast<const bf16x8*>(&Av[(wr * 64 + mf * 16 + l15) * 64 + kk * 32 + kb * 8]);
#pragma unroll
            for (int nf = 0; nf < 2; ++nf)
                bfr[nf] = *reinterpret_cast<const bf16x8*>(&Bv[(wc * 32 + nf * 16 + l15) * 64 + kk * 32 + kb * 8]);
#pragma unroll
            for (int mf = 0; mf < 4; ++mf)
#pragma unroll
                for (int nf = 0; nf < 2; ++nf)
                    acc[mf][nf] = __builtin_amdgcn_mfma_f32_16x16x32_bf16(af[mf], bfr[nf], acc[mf][nf], 0, 0, 0);
        }
        __syncthreads();
    }
#pragma unroll
    for (int mf = 0; mf < 4; ++mf)
#pragma unroll
        for (int nf = 0; nf < 2; ++nf)
#pragma unroll
            for (int r = 0; r < 4; ++r)
                oT[(wr * 64 + mf * 16 + kb * 4 + r) * 68 + wc * 32 + nf * 16 + l15] = acc[mf][nf][r];
    __syncthreads();
#pragma unroll
    for (int j = 0; j < 8; ++j) {
        int t = (tid >> 5) + j * 8;
        int vc4 = (tid & 31) * 4;
        float4 add = make_float4(oT[(vc4 + 0) * 68 + t], oT[(vc4 + 1) * 68 + t],
                                 oT[(vc4 + 2) * 68 + t], oT[(vc4 + 3) * 68 + t]);
        size_t oi = (size_t)(t0 + t) * DVC + h * HDV_ + vc0 + vc4;
        float4 cur = *reinterpret_cast<const float4*>(&o[oi]);
        cur.x += add.x; cur.y += add.y; cur.z += add.z; cur.w += add.w;
        *reinterpret_cast<float4*>(&o[oi]) = cur;
    }
}

// ---------------------------------------------------------------------------
// RMSNorm * rms_w * silu(xg bf16)  ->  gated (bf16)
// ---------------------------------------------------------------------------
__global__ __launch_bounds__(256) void rms_gate(const float* __restrict__ o,
                                                const __hip_bfloat16* __restrict__ xg,
                                                const float* __restrict__ rms_w,
                                                __hip_bfloat16* __restrict__ gated) {
    __shared__ float wsum[4];
    const int th = blockIdx.x;
    const int t = th >> 2, h = th & 3;
    const int tid = threadIdx.x;
    const size_t base = (size_t)t * DVC + h * HDV_;
    float v0 = o[base + tid], v1 = o[base + 256 + tid];
    float s = v0 * v0 + v1 * v1;
#pragma unroll
    for (int off = 32; off >= 1; off >>= 1) s += __shfl_down(s, off, 64);
    if ((tid & 63) == 0) wsum[tid >> 6] = s;
    __syncthreads();
    float tot = wsum[0] + wsum[1] + wsum[2] + wsum[3];
    float rms = rsqrtf(tot * (1.f / 512.f) + 1e-5f);
    float g0 = __bfloat162float(xg[base + tid]);
    float g1 = __bfloat162float(xg[base + 256 + tid]);
    float s0 = g0 / (1.f + expf(-g0));
    float s1 = g1 / (1.f + expf(-g1));
    gated[base + tid]       = __float2bfloat16(v0 * rms * rms_w[tid] * s0);
    gated[base + 256 + tid] = __float2bfloat16(v1 * rms * rms_w[256 + tid] * s1);
}

// ---------------------------------------------------------------------------
extern "C" void kernel_launch(void* const* d_in, const int* in_sizes, int n_in,
                              void* d_out, int out_size, void* d_ws, size_t ws_size,
                              hipStream_t stream) {
    const float* x    = (const float*)d_in[0];
    const float* Wq   = (const float*)d_in[1];
    const float* Wk   = (const float*)d_in[2];
    const float* Wv   = (const float*)d_in[3];
    const float* Wg   = (const float*)d_in[4];
    const float* Wgk1 = (const float*)d_in[5];
    const float* Wgk2 = (const float*)d_in[6];
    const float* bgk2 = (const float*)d_in[7];
    const float* Wo   = (const float*)d_in[8];
    const float* rmsw = (const float*)d_in[9];
    float* out = (float*)d_out;
    float* ws = (float*)d_ws;

    const size_t M1 = 1ull << 20;   // floats
    // Region A [0,17M floats = 68MB): dead by u_pass time; U (64MB) overlays [0,16M)
    __hip_bfloat16* xb    = (__hip_bfloat16*)ws;              // [0,2M)   8 MB
    __hip_bfloat16* WtAll = (__hip_bfloat16*)(ws + 2 * M1);   // [2M,5M)  12 MB (6144x1024)
    __hip_bfloat16* q_b   = (__hip_bfloat16*)(ws + 5 * M1);   // [5M,7M)  8 MB
    __hip_bfloat16* k_b   = (__hip_bfloat16*)(ws + 7 * M1);   // [7M,9M)  8 MB
    __hip_bfloat16* v_b   = (__hip_bfloat16*)(ws + 9 * M1);   // [9M,13M) 16 MB
    float*          g     = ws + 13 * M1;                     // [13M,17M) 16 MB
    __hip_bfloat16* U     = (__hip_bfloat16*)ws;              // [0,16M) 64 MB overlay
    __hip_bfloat16* xg_b  = (__hip_bfloat16*)(ws + 17 * M1);  // [17M,21M) 16 MB
    __hip_bfloat16* qgb   = (__hip_bfloat16*)(ws + 21 * M1);  // [21M,23M) 8 MB
    __hip_bfloat16* kgT   = (__hip_bfloat16*)(ws + 23 * M1);  // [23M,25M) 8 MB
    __hip_bfloat16* vT    = (__hip_bfloat16*)(ws + 25 * M1);  // [25M,29M) 16 MB
    float*          o     = ws + 29 * M1;                     // [29M,37M) 32 MB
    float*          t1    = ws + 37 * M1;                     // 256 KB
    float*          dlast = ws + 37 * M1 + 65536;             // 256 KB
    // overlays after u_pass/o_pass:
    __hip_bfloat16* WtO   = (__hip_bfloat16*)(ws + 23 * M1);  // over kgT (dead after u_pass)
    __hip_bfloat16* gated = (__hip_bfloat16*)(ws + 25 * M1);  // over vT  (dead after u_pass)

    conv_bf16<<<4096, 256, 0, stream>>>(x, xb);
    convT<<<dim3(32, 32), 256, 0, stream>>>(Wq, WtAll,                    DM, DKC);
    convT<<<dim3(32, 32), 256, 0, stream>>>(Wk, WtAll + 1024 * 1024,      DM, DKC);
    convT<<<dim3(64, 32), 256, 0, stream>>>(Wv, WtAll + 2048 * 1024,      DM, DVC);
    convT<<<dim3(64, 32), 256, 0, stream>>>(Wg, WtAll + 4096 * 1024,      DM, DVC);

    gemm_multi<<<dim3(48, 32), 256, 0, stream>>>(xb, WtAll, q_b, k_b, v_b, xg_b);

    transpose_v<<<dim3(64, 128), 256, 0, stream>>>(v_b, vT);
    lowrank1<<<TOK, 256, 0, stream>>>(x, Wgk1, t1);
    gate_k<<<(TOK * DKC) / 256, 256, 0, stream>>>(t1, Wgk2, bgk2, g);
    gla_chunk<<<dim3(NCH, 8), 256, 0, stream>>>(q_b, k_b, vT, g, qgb, kgT, o, dlast);

    u_pass<<<dim3(8, NCH, 8), 256, 0, stream>>>(vT, kgT, U);
    scan_pass<<<512, 256, 0, stream>>>(U, dlast);
    o_pass<<<dim3(4, NCH, 8), 256, 0, stream>>>(qgb, U, o);

    convT<<<dim3(32, 64), 256, 0, stream>>>(Wo, WtO, DVC, DM);
    rms_gate<<<TOK * NH, 256, 0, stream>>>(o, xg_b, rmsw, gated);
    gemm_bf16<<<dim3(8, 32), 256, 0, stream>>>(gated, WtO, out, TOK, DM, DVC);
}

// Round 10
// 280.794 us; speedup vs baseline: 5.5967x; 1.0730x over previous
//
#include <hip/hip_runtime.h>
#include <hip/hip_bf16.h>
#include <math.h>

#define TOK  4096
#define DM   1024
#define DKC  1024
#define DVC  2048
#define NH   4
#define HDK_ 256
#define HDV_ 512
#define NCH  32
#define CHK  64

typedef __attribute__((ext_vector_type(8))) short bf16x8;
typedef __attribute__((ext_vector_type(4))) float f32x4;

__device__ inline float bf2f(short s) {
    unsigned int b = ((unsigned int)(unsigned short)s) << 16;
    return __uint_as_float(b);
}
__device__ inline short f2bf_bits(float f) {
    __hip_bfloat16 h = __float2bfloat16(f);
    return *reinterpret_cast<short*>(&h);
}

// async global->LDS, 16B per lane; lds dest = base + lane*16 (wave-uniform base)
__device__ __forceinline__ void gl_lds16(const void* g, void* l) {
    __builtin_amdgcn_global_load_lds((const __attribute__((address_space(1))) void*)g,
                                     (__attribute__((address_space(3))) void*)l, 16, 0, 0);
}

// ---------------------------------------------------------------------------
// x (f32) -> bf16 copy
// ---------------------------------------------------------------------------
__global__ __launch_bounds__(256) void conv_bf16(const float* __restrict__ in,
                                                 __hip_bfloat16* __restrict__ out) {
    size_t i = ((size_t)blockIdx.x * 256 + threadIdx.x) * 4;
    float4 v = *reinterpret_cast<const float4*>(&in[i]);
    out[i + 0] = __float2bfloat16(v.x);
    out[i + 1] = __float2bfloat16(v.y);
    out[i + 2] = __float2bfloat16(v.z);
    out[i + 3] = __float2bfloat16(v.w);
}

// ---------------------------------------------------------------------------
// W[K][N] f32 -> Wt[N][K] bf16 (tiled transpose); grid = dim3(N/32, K/32)
// ---------------------------------------------------------------------------
__global__ __launch_bounds__(256) void convT(const float* __restrict__ W,
                                             __hip_bfloat16* __restrict__ Wt,
                                             int K, int N) {
    __shared__ float tile[32][33];
    int n0 = blockIdx.x * 32, k0 = blockIdx.y * 32;
    int tx = threadIdx.x & 31, ty = threadIdx.x >> 5;
#pragma unroll
    for (int i = 0; i < 32; i += 8)
        tile[ty + i][tx] = W[(size_t)(k0 + ty + i) * N + n0 + tx];
    __syncthreads();
#pragma unroll
    for (int i = 0; i < 32; i += 8)
        Wt[(size_t)(n0 + ty + i) * K + k0 + tx] = __float2bfloat16(tile[tx][ty + i]);
}

// ---------------------------------------------------------------------------
// v bf16 [4096t][2048] -> vT bf16 [bh=8][512vc][2048t]
// ---------------------------------------------------------------------------
__global__ __launch_bounds__(256) void transpose_v(const __hip_bfloat16* __restrict__ v,
                                                   __hip_bfloat16* __restrict__ vT) {
    __shared__ short tile[32][33];
    const int tg0 = blockIdx.y * 32;
    const int vg0 = blockIdx.x * 32;
    const int tx = threadIdx.x & 31, ty = threadIdx.x >> 5;
    const short* vs = (const short*)v;
#pragma unroll
    for (int i = 0; i < 32; i += 8)
        tile[ty + i][tx] = vs[(size_t)(tg0 + ty + i) * DVC + vg0 + tx];
    __syncthreads();
    const int b = tg0 >> 11, tl0 = tg0 & 2047;
    const int h = vg0 >> 9, vl0 = vg0 & 511;
    const int bh = b * NH + h;
    short* vTs = (short*)vT;
#pragma unroll
    for (int i = 0; i < 32; i += 8)
        vTs[((size_t)bh * 512 + vl0 + ty + i) * 2048 + tl0 + tx] = tile[tx][ty + i];
}

// ---------------------------------------------------------------------------
// FUSED projection GEMM: A=xb[4096][1024] @ WtAll[6144][1024]^T
// n-segment -> {q,k:1024 | v:2048 | xg:2048} bf16 outputs. grid (48, 32).
// ---------------------------------------------------------------------------
__global__ __launch_bounds__(256) void gemm_multi(const __hip_bfloat16* __restrict__ A,
                                                  const __hip_bfloat16* __restrict__ Wt,
                                                  __hip_bfloat16* __restrict__ qo,
                                                  __hip_bfloat16* __restrict__ ko,
                                                  __hip_bfloat16* __restrict__ vo,
                                                  __hip_bfloat16* __restrict__ xgo) {
    __shared__ __align__(16) short Al[128 * 64];
    __shared__ __align__(16) short Bl[128 * 64];
    const int K = 1024;
    const int tid = threadIdx.x;
    const int wave = tid >> 6, lane = tid & 63;
    const int wr = wave >> 1, wc = wave & 1;
    const int m0 = blockIdx.y * 128, n0 = blockIdx.x * 128;
    const int l15 = lane & 15, kb = lane >> 4;
    const int lr8 = lane >> 3, lc8 = (lane & 7) * 8;

    __hip_bfloat16* dst; int ldd, nloc0;
    if (n0 < 1024)      { dst = qo;  ldd = 1024; nloc0 = n0; }
    else if (n0 < 2048) { dst = ko;  ldd = 1024; nloc0 = n0 - 1024; }
    else if (n0 < 4096) { dst = vo;  ldd = 2048; nloc0 = n0 - 2048; }
    else                { dst = xgo; ldd = 2048; nloc0 = n0 - 4096; }

    f32x4 acc[4][4];
#pragma unroll
    for (int mf = 0; mf < 4; ++mf)
#pragma unroll
        for (int nf = 0; nf < 4; ++nf) acc[mf][nf] = (f32x4){0.f, 0.f, 0.f, 0.f};

    for (int k0 = 0; k0 < K; k0 += 64) {
#pragma unroll
        for (int j = 0; j < 4; ++j) {
            int inst = wave * 4 + j;
            int r = inst * 8 + lr8;
            gl_lds16(&A[(size_t)(m0 + r) * K + k0 + lc8], &Al[inst * 512]);
            gl_lds16(&Wt[(size_t)(n0 + r) * K + k0 + lc8], &Bl[inst * 512]);
        }
        __syncthreads();
#pragma unroll
        for (int kk = 0; kk < 2; ++kk) {
            bf16x8 af[4], bfr[4];
#pragma unroll
            for (int mf = 0; mf < 4; ++mf)
                af[mf] = *reinterpret_cast<const bf16x8*>(&Al[(wr * 64 + mf * 16 + l15) * 64 + kk * 32 + kb * 8]);
#pragma unroll
            for (int nf = 0; nf < 4; ++nf)
                bfr[nf] = *reinterpret_cast<const bf16x8*>(&Bl[(wc * 64 + nf * 16 + l15) * 64 + kk * 32 + kb * 8]);
#pragma unroll
            for (int mf = 0; mf < 4; ++mf)
#pragma unroll
                for (int nf = 0; nf < 4; ++nf)
                    acc[mf][nf] = __builtin_amdgcn_mfma_f32_16x16x32_bf16(af[mf], bfr[nf], acc[mf][nf], 0, 0, 0);
        }
        __syncthreads();
    }
#pragma unroll
    for (int mf = 0; mf < 4; ++mf)
#pragma unroll
        for (int nf = 0; nf < 4; ++nf)
#pragma unroll
            for (int r = 0; r < 4; ++r)
                dst[(size_t)(m0 + wr * 64 + mf * 16 + kb * 4 + r) * ldd +
                    nloc0 + wc * 64 + nf * 16 + l15] = __float2bfloat16(acc[mf][nf][r]);
}

// ---------------------------------------------------------------------------
// Double-buffered bf16 MFMA GEMM, f32 C (final Wo projection).
// 1 block/CU shape (N=1024): counted vmcnt(8) keeps next-tile loads in flight
// across the MFMA phase instead of draining to 0 every K-step.
// ---------------------------------------------------------------------------
__global__ __launch_bounds__(256) void gemm_bf16(const __hip_bfloat16* __restrict__ A,
                                                 const __hip_bfloat16* __restrict__ Wt,
                                                 float* __restrict__ C,
                                                 int M, int N, int K) {
    __shared__ __align__(16) short Buf[2][2][128 * 64];   // [dbuf][A/B] 64 KB
    const int tid = threadIdx.x;
    const int wave = tid >> 6, lane = tid & 63;
    const int wr = wave >> 1, wc = wave & 1;
    const int m0 = blockIdx.y * 128, n0 = blockIdx.x * 128;
    const int l15 = lane & 15, kb = lane >> 4;
    const int lr8 = lane >> 3, lc8 = (lane & 7) * 8;
    const int NT = K >> 6;

    f32x4 acc[4][4];
#pragma unroll
    for (int mf = 0; mf < 4; ++mf)
#pragma unroll
        for (int nf = 0; nf < 4; ++nf) acc[mf][nf] = (f32x4){0.f, 0.f, 0.f, 0.f};

#define STAGE_G(kt, bi)                                                          \
    {                                                                            \
        int k0s = (kt) * 64;                                                     \
        _Pragma("unroll")                                                        \
        for (int j = 0; j < 4; ++j) {                                            \
            int inst = wave * 4 + j;                                             \
            int r = inst * 8 + lr8;                                              \
            gl_lds16(&A[(size_t)(m0 + r) * K + k0s + lc8], &Buf[bi][0][inst * 512]); \
            gl_lds16(&Wt[(size_t)(n0 + r) * K + k0s + lc8], &Buf[bi][1][inst * 512]); \
        }                                                                        \
    }

    STAGE_G(0, 0);
    STAGE_G(1, 1);

    for (int t = 0; t < NT; ++t) {
        if (t + 1 < NT) asm volatile("s_waitcnt vmcnt(8)" ::: "memory");
        else            asm volatile("s_waitcnt vmcnt(0)" ::: "memory");
        __builtin_amdgcn_sched_barrier(0);
        __builtin_amdgcn_s_barrier();
        const short* Ab = Buf[t & 1][0];
        const short* Bb = Buf[t & 1][1];
#pragma unroll
        for (int kk = 0; kk < 2; ++kk) {
            bf16x8 af[4], bfr[4];
#pragma unroll
            for (int mf = 0; mf < 4; ++mf)
                af[mf] = *reinterpret_cast<const bf16x8*>(&Ab[(wr * 64 + mf * 16 + l15) * 64 + kk * 32 + kb * 8]);
#pragma unroll
            for (int nf = 0; nf < 4; ++nf)
                bfr[nf] = *reinterpret_cast<const bf16x8*>(&Bb[(wc * 64 + nf * 16 + l15) * 64 + kk * 32 + kb * 8]);
#pragma unroll
            for (int mf = 0; mf < 4; ++mf)
#pragma unroll
                for (int nf = 0; nf < 4; ++nf)
                    acc[mf][nf] = __builtin_amdgcn_mfma_f32_16x16x32_bf16(af[mf], bfr[nf], acc[mf][nf], 0, 0, 0);
        }
        asm volatile("s_waitcnt lgkmcnt(0)" ::: "memory");
        __builtin_amdgcn_sched_barrier(0);
        __builtin_amdgcn_s_barrier();
        if (t + 2 < NT) STAGE_G(t + 2, t & 1);
    }
#undef STAGE_G

#pragma unroll
    for (int mf = 0; mf < 4; ++mf)
#pragma unroll
        for (int nf = 0; nf < 4; ++nf)
#pragma unroll
            for (int r = 0; r < 4; ++r)
                C[(size_t)(m0 + wr * 64 + mf * 16 + kb * 4 + r) * N + n0 + wc * 64 + nf * 16 + l15] =
                    acc[mf][nf][r];
}

// ---------------------------------------------------------------------------
// t1 = x @ Wgk1
// ---------------------------------------------------------------------------
__global__ __launch_bounds__(256) void lowrank1(const float* __restrict__ x,
                                                const float* __restrict__ W1,
                                                float* __restrict__ t1) {
    __shared__ float red[16][17];
    const int t = blockIdx.x;
    const int tid = threadIdx.x;
    const int o = tid & 15;
    const int p = tid >> 4;
    float s = 0.f;
#pragma unroll 8
    for (int m = 0; m < 64; ++m) {
        int kk = p * 64 + m;
        s += x[(size_t)t * DM + kk] * W1[kk * 16 + o];
    }
    red[p][o] = s;
    __syncthreads();
    if (tid < 16) {
        float tot = 0.f;
#pragma unroll
        for (int pp = 0; pp < 16; ++pp) tot += red[pp][tid];
        t1[(size_t)t * 16 + tid] = tot;
    }
}

// ---------------------------------------------------------------------------
// g = log_sigmoid(t1 @ Wgk2 + b) / 16
// ---------------------------------------------------------------------------
__global__ __launch_bounds__(256) void gate_k(const float* __restrict__ t1,
                                              const float* __restrict__ W2,
                                              const float* __restrict__ b2,
                                              float* __restrict__ g) {
    const size_t idx = (size_t)blockIdx.x * 256 + threadIdx.x;
    const int t = (int)(idx >> 10), c = (int)(idx & 1023);
    float acc = b2[c];
#pragma unroll
    for (int r = 0; r < 16; ++r) acc += t1[(size_t)t * 16 + r] * W2[r * 1024 + c];
    float ls = fminf(acc, 0.f) - log1pf(expf(-fabsf(acc)));
    g[idx] = ls * (1.f / 16.f);
}

// ---------------------------------------------------------------------------
// gla_chunk (MFMA): q,k inputs bf16; intra output o1 bf16
// ---------------------------------------------------------------------------
__global__ __launch_bounds__(256) void gla_chunk(const __hip_bfloat16* __restrict__ qb,
                                                 const __hip_bfloat16* __restrict__ kb,
                                                 const __hip_bfloat16* __restrict__ vT,
                                                 const float* __restrict__ g,
                                                 __hip_bfloat16* __restrict__ qg,
                                                 __hip_bfloat16* __restrict__ kgT,
                                                 __hip_bfloat16* __restrict__ o1,
                                                 float* __restrict__ dlast) {
    __shared__ __align__(16) short SM[36864];   // 72 KB
    short* qg_l = SM;            // rows t: 256 shorts (512B)
    short* kd_l = SM + 16384;
    short* V_l  = SM;            // alias: 512 rows x 64 shorts (128B rows)
    short* Am_l = SM + 32768;    // 64x64 (128B rows)

    const int chunk = blockIdx.x, bh = blockIdx.y;
    const int b = bh >> 2, h = bh & 3;
    const int t0 = b * 2048 + chunk * 64;
    const int tt0 = chunk * 64;
    const int tid = threadIdx.x;
    const float scale = 0.0625f;

    // ---- stage 1: thread = d column ----
    {
        const int d = tid;
        const float* gcol = g + (size_t)t0 * DKC + h * HDK_ + d;
        const __hip_bfloat16* qcol = qb + (size_t)t0 * DKC + h * HDK_ + d;
        const __hip_bfloat16* kcol = kb + (size_t)t0 * DKC + h * HDK_ + d;
        float run = 0.f;
#pragma unroll
        for (int i = 0; i < 64; ++i) run += gcol[(size_t)i * DKC];
        const float ebl = expf(run);
        dlast[((size_t)bh * NCH + chunk) * HDK_ + d] = ebl;

        bf16x8 kreg[8];
        run = 0.f;
#pragma unroll
        for (int i = 0; i < 64; ++i) {
            run += gcol[(size_t)i * DKC];
            float eb = expf(run);
            float qv = __bfloat162float(qcol[(size_t)i * DKC]) * eb * scale;
            float kdv = __bfloat162float(kcol[(size_t)i * DKC]) * expf(-run);
            qg[(size_t)(t0 + i) * DKC + h * HDK_ + d] = __float2bfloat16(qv);
            int bq = ((i * 512 + d * 2) ^ ((i & 7) << 4)) >> 1;
            qg_l[bq] = f2bf_bits(qv);
            kd_l[bq] = f2bf_bits(kdv);
            kreg[i >> 3][i & 7] = f2bf_bits(kdv * ebl);   // kg = kd * exp(b_last)
        }
        __hip_bfloat16* kdst = kgT + ((size_t)(bh * HDK_ + d)) * 2048 + chunk * 64;
#pragma unroll
        for (int j = 0; j < 8; ++j)
            *reinterpret_cast<bf16x8*>(&kdst[j * 8]) = kreg[j];
    }
    __syncthreads();

    const int wv = tid >> 6, lane = tid & 63;
    const int l15 = lane & 15, kb_ = lane >> 4;

    // ---- stage 2: A = tril(qg @ kd^T) ----
    {
        f32x4 accA[4];
#pragma unroll
        for (int sf = 0; sf < 4; ++sf) accA[sf] = (f32x4){0.f, 0.f, 0.f, 0.f};
        const int trow = wv * 16 + l15;
#pragma unroll
        for (int ks = 0; ks < 8; ++ks) {
            bf16x8 af = *reinterpret_cast<const bf16x8*>(
                &qg_l[((trow * 512 + (ks * 32 + kb_ * 8) * 2) ^ ((trow & 7) << 4)) >> 1]);
#pragma unroll
            for (int sf = 0; sf < 4; ++sf) {
                int srow = sf * 16 + l15;
                bf16x8 bfr = *reinterpret_cast<const bf16x8*>(
                    &kd_l[((srow * 512 + (ks * 32 + kb_ * 8) * 2) ^ ((srow & 7) << 4)) >> 1]);
                accA[sf] = __builtin_amdgcn_mfma_f32_16x16x32_bf16(af, bfr, accA[sf], 0, 0, 0);
            }
        }
#pragma unroll
        for (int sf = 0; sf < 4; ++sf)
#pragma unroll
            for (int r = 0; r < 4; ++r) {
                int t = wv * 16 + kb_ * 4 + r, s = sf * 16 + l15;
                float val = (t >= s) ? accA[sf][r] : 0.f;
                Am_l[((t * 128 + s * 2) ^ ((t & 7) << 4)) >> 1] = f2bf_bits(val);
            }
    }
    __syncthreads();

    // ---- stage 3: stage V, then o1 = Am @ vT^T (bf16 out) ----
    {
        const int lr8 = lane >> 3, slot = lane & 7;
#pragma unroll
        for (int i8 = 0; i8 < 16; ++i8) {
            int vrow0 = wv * 128 + i8 * 8;
            const __hip_bfloat16* src =
                &vT[((size_t)bh * 512 + vrow0 + lr8) * 2048 + tt0 + (slot ^ (lr8 & 7)) * 8];
            gl_lds16(src, &V_l[vrow0 * 64]);
        }
    }
    __syncthreads();

    {
        f32x4 accO[4][8];
#pragma unroll
        for (int tf = 0; tf < 4; ++tf)
#pragma unroll
            for (int vf = 0; vf < 8; ++vf) accO[tf][vf] = (f32x4){0.f, 0.f, 0.f, 0.f};
#pragma unroll
        for (int kk = 0; kk < 2; ++kk) {
            bf16x8 af[4];
#pragma unroll
            for (int tf = 0; tf < 4; ++tf) {
                int row = tf * 16 + l15;
                af[tf] = *reinterpret_cast<const bf16x8*>(
                    &Am_l[((row * 128 + (kk * 32 + kb_ * 8) * 2) ^ ((row & 7) << 4)) >> 1]);
            }
#pragma unroll
            for (int vf = 0; vf < 8; ++vf) {
                int rv = wv * 128 + vf * 16 + l15;
                bf16x8 bfr = *reinterpret_cast<const bf16x8*>(
                    &V_l[((rv * 128 + (kk * 32 + kb_ * 8) * 2) ^ ((rv & 7) << 4)) >> 1]);
#pragma unroll
                for (int tf = 0; tf < 4; ++tf)
                    accO[tf][vf] = __builtin_amdgcn_mfma_f32_16x16x32_bf16(af[tf], bfr, accO[tf][vf], 0, 0, 0);
            }
        }
#pragma unroll
        for (int tf = 0; tf < 4; ++tf)
#pragma unroll
            for (int vf = 0; vf < 8; ++vf)
#pragma unroll
                for (int r = 0; r < 4; ++r) {
                    int t = tf * 16 + kb_ * 4 + r;
                    int vv = wv * 128 + vf * 16 + l15;
                    o1[(size_t)(t0 + t) * DVC + h * HDV_ + vv] = __float2bfloat16(accO[tf][vf][r]);
                }
    }
}

// ---------------------------------------------------------------------------
// u_pass (MFMA): U'[bh][c][vc][d] bf16 = sum_t v[t][vc]*kg[t][d]
// ---------------------------------------------------------------------------
__global__ __launch_bounds__(256) void u_pass(const __hip_bfloat16* __restrict__ vT,
                                              const __hip_bfloat16* __restrict__ kgT,
                                              __hip_bfloat16* __restrict__ U) {
    __shared__ __align__(16) short Av[128 * 64];
    __shared__ __align__(16) short Bv[128 * 64];
    const int bx = blockIdx.x, c = blockIdx.y, bh = blockIdx.z;
    const int vc0 = (bx >> 1) * 128, d0 = (bx & 1) * 128;
    const int tid = threadIdx.x;
    const int wave = tid >> 6, lane = tid & 63;
    const int wr = wave >> 1, wc = wave & 1;
    const int l15 = lane & 15, kb = lane >> 4;
    const int lr8 = lane >> 3, lc8 = (lane & 7) * 8;

#pragma unroll
    for (int j = 0; j < 4; ++j) {
        int inst = wave * 4 + j;
        int r = inst * 8 + lr8;
        gl_lds16(&vT[((size_t)bh * 512 + vc0 + r) * 2048 + c * 64 + lc8], &Av[inst * 512]);
        gl_lds16(&kgT[((size_t)bh * HDK_ + d0 + r) * 2048 + c * 64 + lc8], &Bv[inst * 512]);
    }
    __syncthreads();

    f32x4 acc[4][4];
#pragma unroll
    for (int mf = 0; mf < 4; ++mf)
#pragma unroll
        for (int nf = 0; nf < 4; ++nf) acc[mf][nf] = (f32x4){0.f, 0.f, 0.f, 0.f};
#pragma unroll
    for (int kk = 0; kk < 2; ++kk) {
        bf16x8 af[4], bfr[4];
#pragma unroll
        for (int mf = 0; mf < 4; ++mf)
            af[mf] = *reinterpret_cast<const bf16x8*>(&Av[(wr * 64 + mf * 16 + l15) * 64 + kk * 32 + kb * 8]);
#pragma unroll
        for (int nf = 0; nf < 4; ++nf)
            bfr[nf] = *reinterpret_cast<const bf16x8*>(&Bv[(wc * 64 + nf * 16 + l15) * 64 + kk * 32 + kb * 8]);
#pragma unroll
        for (int mf = 0; mf < 4; ++mf)
#pragma unroll
            for (int nf = 0; nf < 4; ++nf)
                acc[mf][nf] = __builtin_amdgcn_mfma_f32_16x16x32_bf16(af[mf], bfr[nf], acc[mf][nf], 0, 0, 0);
    }
    const size_t Ub = ((size_t)bh * NCH + c) * 131072;
#pragma unroll
    for (int mf = 0; mf < 4; ++mf)
#pragma unroll
        for (int nf = 0; nf < 4; ++nf)
#pragma unroll
            for (int r = 0; r < 4; ++r) {
                int vc = vc0 + wr * 64 + mf * 16 + kb * 4 + r;
                int d = d0 + wc * 64 + nf * 16 + l15;
                U[Ub + (size_t)vc * 256 + d] = __float2bfloat16(acc[mf][nf][r]);
            }
}

// ---------------------------------------------------------------------------
// scan_pass on U'[bh][c][vc][d]: exclusive scan over chunks, decay e(d)
// ---------------------------------------------------------------------------
__global__ __launch_bounds__(256) void scan_pass(__hip_bfloat16* __restrict__ U,
                                                 const float* __restrict__ dlast) {
    int gid = blockIdx.x * 256 + threadIdx.x;   // 131072
    int bh = gid >> 14;
    int rem = gid & 16383;
    int vc = rem >> 5;
    int dg = rem & 31;
    float S[8];
#pragma unroll
    for (int j = 0; j < 8; ++j) S[j] = 0.f;
    size_t base = (size_t)bh * NCH * 131072 + (size_t)vc * 256 + dg * 8;
    for (int c = 0; c < NCH; ++c) {
        __hip_bfloat16* p = U + base + (size_t)c * 131072;
        bf16x8 u = *reinterpret_cast<bf16x8*>(p);
        const float* dl = &dlast[((size_t)bh * NCH + c) * HDK_ + dg * 8];
        float4 e0 = *reinterpret_cast<const float4*>(dl);
        float4 e1 = *reinterpret_cast<const float4*>(dl + 4);
        float e[8] = {e0.x, e0.y, e0.z, e0.w, e1.x, e1.y, e1.z, e1.w};
        bf16x8 outv;
#pragma unroll
        for (int j = 0; j < 8; ++j) {
            outv[j] = f2bf_bits(S[j]);
            S[j] = S[j] * e[j] + bf2f(u[j]);
        }
        *reinterpret_cast<bf16x8*>(p) = outv;
    }
}

// ---------------------------------------------------------------------------
// o_pass (MFMA): o2[t][vc] (bf16) = o1[t][vc] + sum_d qg[t][d] * S'[vc][d]
// ---------------------------------------------------------------------------
__global__ __launch_bounds__(256) void o_pass(const __hip_bfloat16* __restrict__ qg,
                                              const __hip_bfloat16* __restrict__ U,
                                              const __hip_bfloat16* __restrict__ o1,
                                              __hip_bfloat16* __restrict__ o2) {
    __shared__ __align__(16) char smem[64 * 132 * 4];   // 33.8 KB
    short* Av = (short*)smem;               // 128x64 bf16 = 16 KB
    short* Bv = (short*)smem + 128 * 64;    // 64x64 bf16 = 8 KB
    float* oT = (float*)smem;               // [64 t][132] f32 (epilogue, aliases)
    const int vt = blockIdx.x, c = blockIdx.y, bh = blockIdx.z;
    const int b = bh >> 2, h = bh & 3;
    const int vc0 = vt * 128;
    const int t0 = b * 2048 + c * 64;
    const int tid = threadIdx.x;
    const int wave = tid >> 6, lane = tid & 63;
    const int wr = wave >> 1, wc = wave & 1;
    const int l15 = lane & 15, kb = lane >> 4;
    const int lr8 = lane >> 3, lc8 = (lane & 7) * 8;
    const size_t Ub = ((size_t)bh * NCH + c) * 131072;

    f32x4 acc[4][2];
#pragma unroll
    for (int mf = 0; mf < 4; ++mf)
#pragma unroll
        for (int nf = 0; nf < 2; ++nf) acc[mf][nf] = (f32x4){0.f, 0.f, 0.f, 0.f};

    for (int ks = 0; ks < 4; ++ks) {
        const int d0 = ks * 64;
#pragma unroll
        for (int j = 0; j < 4; ++j) {
            int inst = wave * 4 + j;
            int r = inst * 8 + lr8;
            gl_lds16(&U[Ub + (size_t)(vc0 + r) * 256 + d0 + lc8], &Av[inst * 512]);
        }
#pragma unroll
        for (int j = 0; j < 2; ++j) {
            int inst = wave * 2 + j;
            int r = inst * 8 + lr8;
            gl_lds16(&qg[(size_t)(t0 + r) * DKC + h * HDK_ + d0 + lc8], &Bv[inst * 512]);
        }
        __syncthreads();
#pragma unroll
        for (int kk = 0; kk < 2; ++kk) {
            bf16x8 af[4], bfr[2];
#pragma unroll
            for (int mf = 0; mf < 4; ++mf)
                af[mf] = *reinterpret_cast<const bf16x8*>(&Av[(wr * 64 + mf * 16 + l15) * 64 + kk * 32 + kb * 8]);
#pragma unroll
            for (int nf = 0; nf < 2; ++nf)
                bfr[nf] = *reinterpret_cast<const bf16x8*>(&Bv[(wc * 32 + nf * 16 + l15) * 64 + kk * 32 + kb * 8]);
#pragma unroll
            for (int mf = 0; mf < 4; ++mf)
#pragma unroll
                for (int nf = 0; nf < 2; ++nf)
                    acc[mf][nf] = __builtin_amdgcn_mfma_f32_16x16x32_bf16(af[mf], bfr[nf], acc[mf][nf], 0, 0, 0);
        }
        __syncthreads();
    }
    // acc (mf,nf,r): vc = wr*64+mf*16+kb*4+r, t = wc*32+nf*16+l15 -> oT[t][vc]
#pragma unroll
    for (int mf = 0; mf < 4; ++mf)
#pragma unroll
        for (int nf = 0; nf < 2; ++nf)
#pragma unroll
            for (int r = 0; r < 4; ++r)
                oT[(wc * 32 + nf * 16 + l15) * 132 + wr * 64 + mf * 16 + kb * 4 + r] = acc[mf][nf][r];
    __syncthreads();
#pragma unroll
    for (int j = 0; j < 4; ++j) {
        int t = (tid >> 4) + j * 16;         // 0..63
        int vc8 = (tid & 15) * 8;            // 0..120
        float4 a0 = *reinterpret_cast<const float4*>(&oT[t * 132 + vc8]);
        float4 a1 = *reinterpret_cast<const float4*>(&oT[t * 132 + vc8 + 4]);
        size_t oi = (size_t)(t0 + t) * DVC + h * HDV_ + vc0 + vc8;
        bf16x8 iv = *reinterpret_cast<const bf16x8*>(&o1[oi]);
        bf16x8 outv;
        outv[0] = f2bf_bits(a0.x + bf2f(iv[0]));
        outv[1] = f2bf_bits(a0.y + bf2f(iv[1]));
        outv[2] = f2bf_bits(a0.z + bf2f(iv[2]));
        outv[3] = f2bf_bits(a0.w + bf2f(iv[3]));
        outv[4] = f2bf_bits(a1.x + bf2f(iv[4]));
        outv[5] = f2bf_bits(a1.y + bf2f(iv[5]));
        outv[6] = f2bf_bits(a1.z + bf2f(iv[6]));
        outv[7] = f2bf_bits(a1.w + bf2f(iv[7]));
        *reinterpret_cast<bf16x8*>((__hip_bfloat16*)o2 + oi) = outv;
    }
}

// ---------------------------------------------------------------------------
// RMSNorm * rms_w * silu(xg)  (all bf16 in, bf16 out, vectorized pairs)
// ---------------------------------------------------------------------------
__global__ __launch_bounds__(256) void rms_gate(const __hip_bfloat16* __restrict__ o2,
                                                const __hip_bfloat16* __restrict__ xg,
                                                const float* __restrict__ rms_w,
                                                __hip_bfloat16* __restrict__ gated) {
    __shared__ float wsum[4];
    const int th = blockIdx.x;
    const int t = th >> 2, h = th & 3;
    const int tid = threadIdx.x;
    const size_t base = (size_t)t * DVC + h * HDV_;
    short2 ov = reinterpret_cast<const short2*>((const short*)o2 + base)[tid];
    float v0 = bf2f(ov.x), v1 = bf2f(ov.y);
    float s = v0 * v0 + v1 * v1;
#pragma unroll
    for (int off = 32; off >= 1; off >>= 1) s += __shfl_down(s, off, 64);
    if ((tid & 63) == 0) wsum[tid >> 6] = s;
    __syncthreads();
    float tot = wsum[0] + wsum[1] + wsum[2] + wsum[3];
    float rms = rsqrtf(tot * (1.f / 512.f) + 1e-5f);
    short2 gv = reinterpret_cast<const short2*>((const short*)xg + base)[tid];
    float g0 = bf2f(gv.x), g1 = bf2f(gv.y);
    float s0 = g0 / (1.f + expf(-g0));
    float s1 = g1 / (1.f + expf(-g1));
    float2 w = reinterpret_cast<const float2*>(rms_w)[tid];
    short2 outp;
    outp.x = f2bf_bits(v0 * rms * w.x * s0);
    outp.y = f2bf_bits(v1 * rms * w.y * s1);
    reinterpret_cast<short2*>((short*)gated + base)[tid] = outp;
}

// ---------------------------------------------------------------------------
extern "C" void kernel_launch(void* const* d_in, const int* in_sizes, int n_in,
                              void* d_out, int out_size, void* d_ws, size_t ws_size,
                              hipStream_t stream) {
    const float* x    = (const float*)d_in[0];
    const float* Wq   = (const float*)d_in[1];
    const float* Wk   = (const float*)d_in[2];
    const float* Wv   = (const float*)d_in[3];
    const float* Wg   = (const float*)d_in[4];
    const float* Wgk1 = (const float*)d_in[5];
    const float* Wgk2 = (const float*)d_in[6];
    const float* bgk2 = (const float*)d_in[7];
    const float* Wo   = (const float*)d_in[8];
    const float* rmsw = (const float*)d_in[9];
    float* out = (float*)d_out;
    float* ws = (float*)d_ws;

    const size_t M1 = 1ull << 20;   // floats
    // Region A [0,17M floats): dead by u_pass time; U (64MB) overlays [0,16M)
    __hip_bfloat16* xb    = (__hip_bfloat16*)ws;              // [0,2M)   8 MB
    __hip_bfloat16* WtAll = (__hip_bfloat16*)(ws + 2 * M1);   // [2M,5M)  12 MB (6144x1024)
    __hip_bfloat16* q_b   = (__hip_bfloat16*)(ws + 5 * M1);   // [5M,7M)  8 MB
    __hip_bfloat16* k_b   = (__hip_bfloat16*)(ws + 7 * M1);   // [7M,9M)  8 MB
    __hip_bfloat16* v_b   = (__hip_bfloat16*)(ws + 9 * M1);   // [9M,13M) 16 MB
    float*          g     = ws + 13 * M1;                     // [13M,17M) 16 MB
    __hip_bfloat16* U     = (__hip_bfloat16*)ws;              // [0,16M) 64 MB overlay
    __hip_bfloat16* xg_b  = (__hip_bfloat16*)(ws + 17 * M1);  // [17M,21M) 16 MB
    __hip_bfloat16* qgb   = (__hip_bfloat16*)(ws + 21 * M1);  // [21M,23M) 8 MB
    __hip_bfloat16* kgT   = (__hip_bfloat16*)(ws + 23 * M1);  // [23M,25M) 8 MB
    __hip_bfloat16* vT    = (__hip_bfloat16*)(ws + 25 * M1);  // [25M,29M) 16 MB
    __hip_bfloat16* o1    = (__hip_bfloat16*)(ws + 29 * M1);  // [29M,33M) 16 MB
    __hip_bfloat16* o2    = (__hip_bfloat16*)(ws + 33 * M1);  // [33M,37M) 16 MB
    float*          t1    = ws + 37 * M1;                     // 256 KB
    float*          dlast = ws + 37 * M1 + 65536;             // 256 KB
    // overlays after u_pass/o_pass:
    __hip_bfloat16* WtO   = (__hip_bfloat16*)(ws + 23 * M1);  // over kgT (dead after u_pass)
    __hip_bfloat16* gated = (__hip_bfloat16*)(ws + 25 * M1);  // over vT  (dead after u_pass)

    conv_bf16<<<4096, 256, 0, stream>>>(x, xb);
    convT<<<dim3(32, 32), 256, 0, stream>>>(Wq, WtAll,                    DM, DKC);
    convT<<<dim3(32, 32), 256, 0, stream>>>(Wk, WtAll + 1024 * 1024,      DM, DKC);
    convT<<<dim3(64, 32), 256, 0, stream>>>(Wv, WtAll + 2048 * 1024,      DM, DVC);
    convT<<<dim3(64, 32), 256, 0, stream>>>(Wg, WtAll + 4096 * 1024,      DM, DVC);

    gemm_multi<<<dim3(48, 32), 256, 0, stream>>>(xb, WtAll, q_b, k_b, v_b, xg_b);

    transpose_v<<<dim3(64, 128), 256, 0, stream>>>(v_b, vT);
    lowrank1<<<TOK, 256, 0, stream>>>(x, Wgk1, t1);
    gate_k<<<(TOK * DKC) / 256, 256, 0, stream>>>(t1, Wgk2, bgk2, g);
    gla_chunk<<<dim3(NCH, 8), 256, 0, stream>>>(q_b, k_b, vT, g, qgb, kgT, o1, dlast);

    u_pass<<<dim3(8, NCH, 8), 256, 0, stream>>>(vT, kgT, U);
    scan_pass<<<512, 256, 0, stream>>>(U, dlast);
    o_pass<<<dim3(4, NCH, 8), 256, 0, stream>>>(qgb, U, o1, o2);

    convT<<<dim3(32, 64), 256, 0, stream>>>(Wo, WtO, DVC, DM);
    rms_gate<<<TOK * NH, 256, 0, stream>>>(o2, xg_b, rmsw, gated);
    gemm_bf16<<<dim3(8, 32), 256, 0, stream>>>(gated, WtO, out, TOK, DM, DVC);
}

// Round 11
// 279.971 us; speedup vs baseline: 5.6132x; 1.0029x over previous
//
#include <hip/hip_runtime.h>
#include <hip/hip_bf16.h>
#include <math.h>

#define TOK  4096
#define DM   1024
#define DKC  1024
#define DVC  2048
#define NH   4
#define HDK_ 256
#define HDV_ 512
#define NCH  32
#define CHK  64

typedef __attribute__((ext_vector_type(8))) short bf16x8;
typedef __attribute__((ext_vector_type(4))) float f32x4;

__device__ inline float bf2f(short s) {
    unsigned int b = ((unsigned int)(unsigned short)s) << 16;
    return __uint_as_float(b);
}
__device__ inline short f2bf_bits(float f) {
    __hip_bfloat16 h = __float2bfloat16(f);
    return *reinterpret_cast<short*>(&h);
}

// async global->LDS, 16B per lane; lds dest = base + lane*16 (wave-uniform base)
__device__ __forceinline__ void gl_lds16(const void* g, void* l) {
    __builtin_amdgcn_global_load_lds((const __attribute__((address_space(1))) void*)g,
                                     (__attribute__((address_space(3))) void*)l, 16, 0, 0);
}

// ---------------------------------------------------------------------------
// x (f32) -> bf16 copy
// ---------------------------------------------------------------------------
__global__ __launch_bounds__(256) void conv_bf16(const float* __restrict__ in,
                                                 __hip_bfloat16* __restrict__ out) {
    size_t i = ((size_t)blockIdx.x * 256 + threadIdx.x) * 4;
    float4 v = *reinterpret_cast<const float4*>(&in[i]);
    out[i + 0] = __float2bfloat16(v.x);
    out[i + 1] = __float2bfloat16(v.y);
    out[i + 2] = __float2bfloat16(v.z);
    out[i + 3] = __float2bfloat16(v.w);
}

// ---------------------------------------------------------------------------
// W[K][N] f32 -> Wt[N][K] bf16 (tiled transpose); grid = dim3(N/32, K/32)
// ---------------------------------------------------------------------------
__global__ __launch_bounds__(256) void convT(const float* __restrict__ W,
                                             __hip_bfloat16* __restrict__ Wt,
                                             int K, int N) {
    __shared__ float tile[32][33];
    int n0 = blockIdx.x * 32, k0 = blockIdx.y * 32;
    int tx = threadIdx.x & 31, ty = threadIdx.x >> 5;
#pragma unroll
    for (int i = 0; i < 32; i += 8)
        tile[ty + i][tx] = W[(size_t)(k0 + ty + i) * N + n0 + tx];
    __syncthreads();
#pragma unroll
    for (int i = 0; i < 32; i += 8)
        Wt[(size_t)(n0 + ty + i) * K + k0 + tx] = __float2bfloat16(tile[tx][ty + i]);
}

// ---------------------------------------------------------------------------
// v bf16 [4096t][2048] -> vT bf16 [bh=8][512vc][2048t]
// ---------------------------------------------------------------------------
__global__ __launch_bounds__(256) void transpose_v(const __hip_bfloat16* __restrict__ v,
                                                   __hip_bfloat16* __restrict__ vT) {
    __shared__ short tile[32][33];
    const int tg0 = blockIdx.y * 32;
    const int vg0 = blockIdx.x * 32;
    const int tx = threadIdx.x & 31, ty = threadIdx.x >> 5;
    const short* vs = (const short*)v;
#pragma unroll
    for (int i = 0; i < 32; i += 8)
        tile[ty + i][tx] = vs[(size_t)(tg0 + ty + i) * DVC + vg0 + tx];
    __syncthreads();
    const int b = tg0 >> 11, tl0 = tg0 & 2047;
    const int h = vg0 >> 9, vl0 = vg0 & 511;
    const int bh = b * NH + h;
    short* vTs = (short*)vT;
#pragma unroll
    for (int i = 0; i < 32; i += 8)
        vTs[((size_t)bh * 512 + vl0 + ty + i) * 2048 + tl0 + tx] = tile[tx][ty + i];
}

// ---------------------------------------------------------------------------
// FUSED projection GEMM: A=xb[4096][1024] @ WtAll[6144][1024]^T
// Double-buffered, counted vmcnt(8); LDS-transposed coalesced bf16 epilogue.
// n-segment -> {q,k:1024 | v:2048 | xg:2048} bf16 outputs. grid (48, 32).
// ---------------------------------------------------------------------------
__global__ __launch_bounds__(256) void gemm_multi(const __hip_bfloat16* __restrict__ A,
                                                  const __hip_bfloat16* __restrict__ Wt,
                                                  __hip_bfloat16* __restrict__ qo,
                                                  __hip_bfloat16* __restrict__ ko,
                                                  __hip_bfloat16* __restrict__ vo,
                                                  __hip_bfloat16* __restrict__ xgo) {
    __shared__ __align__(16) short Buf[2][2][128 * 64];   // 64 KB
    short* Cl = &Buf[0][0][0];     // epilogue alias: 128 rows x 136 shorts (34.8 KB)
    const int K = 1024, NT = 16;
    const int tid = threadIdx.x;
    const int wave = tid >> 6, lane = tid & 63;
    const int wr = wave >> 1, wc = wave & 1;
    const int m0 = blockIdx.y * 128, n0 = blockIdx.x * 128;
    const int l15 = lane & 15, kb = lane >> 4;
    const int lr8 = lane >> 3, lc8 = (lane & 7) * 8;

    __hip_bfloat16* dst; int ldd, nloc0;
    if (n0 < 1024)      { dst = qo;  ldd = 1024; nloc0 = n0; }
    else if (n0 < 2048) { dst = ko;  ldd = 1024; nloc0 = n0 - 1024; }
    else if (n0 < 4096) { dst = vo;  ldd = 2048; nloc0 = n0 - 2048; }
    else                { dst = xgo; ldd = 2048; nloc0 = n0 - 4096; }

    f32x4 acc[4][4];
#pragma unroll
    for (int mf = 0; mf < 4; ++mf)
#pragma unroll
        for (int nf = 0; nf < 4; ++nf) acc[mf][nf] = (f32x4){0.f, 0.f, 0.f, 0.f};

#define STAGE_M(kt, bi)                                                          \
    {                                                                            \
        int k0s = (kt) * 64;                                                     \
        _Pragma("unroll")                                                        \
        for (int j = 0; j < 4; ++j) {                                            \
            int inst = wave * 4 + j;                                             \
            int r = inst * 8 + lr8;                                              \
            gl_lds16(&A[(size_t)(m0 + r) * K + k0s + lc8], &Buf[bi][0][inst * 512]);  \
            gl_lds16(&Wt[(size_t)(n0 + r) * K + k0s + lc8], &Buf[bi][1][inst * 512]); \
        }                                                                        \
    }

    STAGE_M(0, 0);
    STAGE_M(1, 1);

    for (int t = 0; t < NT; ++t) {
        if (t + 1 < NT) asm volatile("s_waitcnt vmcnt(8)" ::: "memory");
        else            asm volatile("s_waitcnt vmcnt(0)" ::: "memory");
        __builtin_amdgcn_sched_barrier(0);
        __builtin_amdgcn_s_barrier();
        const short* Ab = Buf[t & 1][0];
        const short* Bb = Buf[t & 1][1];
#pragma unroll
        for (int kk = 0; kk < 2; ++kk) {
            bf16x8 af[4], bfr[4];
#pragma unroll
            for (int mf = 0; mf < 4; ++mf)
                af[mf] = *reinterpret_cast<const bf16x8*>(&Ab[(wr * 64 + mf * 16 + l15) * 64 + kk * 32 + kb * 8]);
#pragma unroll
            for (int nf = 0; nf < 4; ++nf)
                bfr[nf] = *reinterpret_cast<const bf16x8*>(&Bb[(wc * 64 + nf * 16 + l15) * 64 + kk * 32 + kb * 8]);
#pragma unroll
            for (int mf = 0; mf < 4; ++mf)
#pragma unroll
                for (int nf = 0; nf < 4; ++nf)
                    acc[mf][nf] = __builtin_amdgcn_mfma_f32_16x16x32_bf16(af[mf], bfr[nf], acc[mf][nf], 0, 0, 0);
        }
        asm volatile("s_waitcnt lgkmcnt(0)" ::: "memory");
        __builtin_amdgcn_sched_barrier(0);
        __builtin_amdgcn_s_barrier();
        if (t + 2 < NT) STAGE_M(t + 2, t & 1);
    }
#undef STAGE_M

    // epilogue: acc -> LDS (bf16, row pad 136 for 16B-aligned rows) -> coalesced stores
#pragma unroll
    for (int mf = 0; mf < 4; ++mf)
#pragma unroll
        for (int nf = 0; nf < 4; ++nf)
#pragma unroll
            for (int r = 0; r < 4; ++r)
                Cl[(wr * 64 + mf * 16 + kb * 4 + r) * 136 + wc * 64 + nf * 16 + l15] =
                    f2bf_bits(acc[mf][nf][r]);
    __syncthreads();
#pragma unroll
    for (int j = 0; j < 8; ++j) {
        int row = (tid >> 4) + j * 16;       // 0..127
        int col8 = (tid & 15) * 8;           // 0..120
        bf16x8 v = *reinterpret_cast<const bf16x8*>(&Cl[row * 136 + col8]);
        *reinterpret_cast<bf16x8*>(&dst[(size_t)(m0 + row) * ldd + nloc0 + col8]) = v;
    }
}

// ---------------------------------------------------------------------------
// Double-buffered bf16 MFMA GEMM, f32 C (final Wo projection).
// ---------------------------------------------------------------------------
__global__ __launch_bounds__(256) void gemm_bf16(const __hip_bfloat16* __restrict__ A,
                                                 const __hip_bfloat16* __restrict__ Wt,
                                                 float* __restrict__ C,
                                                 int M, int N, int K) {
    __shared__ __align__(16) short Buf[2][2][128 * 64];   // [dbuf][A/B] 64 KB
    const int tid = threadIdx.x;
    const int wave = tid >> 6, lane = tid & 63;
    const int wr = wave >> 1, wc = wave & 1;
    const int m0 = blockIdx.y * 128, n0 = blockIdx.x * 128;
    const int l15 = lane & 15, kb = lane >> 4;
    const int lr8 = lane >> 3, lc8 = (lane & 7) * 8;
    const int NT = K >> 6;

    f32x4 acc[4][4];
#pragma unroll
    for (int mf = 0; mf < 4; ++mf)
#pragma unroll
        for (int nf = 0; nf < 4; ++nf) acc[mf][nf] = (f32x4){0.f, 0.f, 0.f, 0.f};

#define STAGE_G(kt, bi)                                                          \
    {                                                                            \
        int k0s = (kt) * 64;                                                     \
        _Pragma("unroll")                                                        \
        for (int j = 0; j < 4; ++j) {                                            \
            int inst = wave * 4 + j;                                             \
            int r = inst * 8 + lr8;                                              \
            gl_lds16(&A[(size_t)(m0 + r) * K + k0s + lc8], &Buf[bi][0][inst * 512]); \
            gl_lds16(&Wt[(size_t)(n0 + r) * K + k0s + lc8], &Buf[bi][1][inst * 512]); \
        }                                                                        \
    }

    STAGE_G(0, 0);
    STAGE_G(1, 1);

    for (int t = 0; t < NT; ++t) {
        if (t + 1 < NT) asm volatile("s_waitcnt vmcnt(8)" ::: "memory");
        else            asm volatile("s_waitcnt vmcnt(0)" ::: "memory");
        __builtin_amdgcn_sched_barrier(0);
        __builtin_amdgcn_s_barrier();
        const short* Ab = Buf[t & 1][0];
        const short* Bb = Buf[t & 1][1];
#pragma unroll
        for (int kk = 0; kk < 2; ++kk) {
            bf16x8 af[4], bfr[4];
#pragma unroll
            for (int mf = 0; mf < 4; ++mf)
                af[mf] = *reinterpret_cast<const bf16x8*>(&Ab[(wr * 64 + mf * 16 + l15) * 64 + kk * 32 + kb * 8]);
#pragma unroll
            for (int nf = 0; nf < 4; ++nf)
                bfr[nf] = *reinterpret_cast<const bf16x8*>(&Bb[(wc * 64 + nf * 16 + l15) * 64 + kk * 32 + kb * 8]);
#pragma unroll
            for (int mf = 0; mf < 4; ++mf)
#pragma unroll
                for (int nf = 0; nf < 4; ++nf)
                    acc[mf][nf] = __builtin_amdgcn_mfma_f32_16x16x32_bf16(af[mf], bfr[nf], acc[mf][nf], 0, 0, 0);
        }
        asm volatile("s_waitcnt lgkmcnt(0)" ::: "memory");
        __builtin_amdgcn_sched_barrier(0);
        __builtin_amdgcn_s_barrier();
        if (t + 2 < NT) STAGE_G(t + 2, t & 1);
    }
#undef STAGE_G

#pragma unroll
    for (int mf = 0; mf < 4; ++mf)
#pragma unroll
        for (int nf = 0; nf < 4; ++nf)
#pragma unroll
            for (int r = 0; r < 4; ++r)
                C[(size_t)(m0 + wr * 64 + mf * 16 + kb * 4 + r) * N + n0 + wc * 64 + nf * 16 + l15] =
                    acc[mf][nf][r];
}

// ---------------------------------------------------------------------------
// t1 = x @ Wgk1
// ---------------------------------------------------------------------------
__global__ __launch_bounds__(256) void lowrank1(const float* __restrict__ x,
                                                const float* __restrict__ W1,
                                                float* __restrict__ t1) {
    __shared__ float red[16][17];
    const int t = blockIdx.x;
    const int tid = threadIdx.x;
    const int o = tid & 15;
    const int p = tid >> 4;
    float s = 0.f;
#pragma unroll 8
    for (int m = 0; m < 64; ++m) {
        int kk = p * 64 + m;
        s += x[(size_t)t * DM + kk] * W1[kk * 16 + o];
    }
    red[p][o] = s;
    __syncthreads();
    if (tid < 16) {
        float tot = 0.f;
#pragma unroll
        for (int pp = 0; pp < 16; ++pp) tot += red[pp][tid];
        t1[(size_t)t * 16 + tid] = tot;
    }
}

// ---------------------------------------------------------------------------
// g = log_sigmoid(t1 @ Wgk2 + b) / 16
// ---------------------------------------------------------------------------
__global__ __launch_bounds__(256) void gate_k(const float* __restrict__ t1,
                                              const float* __restrict__ W2,
                                              const float* __restrict__ b2,
                                              float* __restrict__ g) {
    const size_t idx = (size_t)blockIdx.x * 256 + threadIdx.x;
    const int t = (int)(idx >> 10), c = (int)(idx & 1023);
    float acc = b2[c];
#pragma unroll
    for (int r = 0; r < 16; ++r) acc += t1[(size_t)t * 16 + r] * W2[r * 1024 + c];
    float ls = fminf(acc, 0.f) - log1pf(expf(-fabsf(acc)));
    g[idx] = ls * (1.f / 16.f);
}

// ---------------------------------------------------------------------------
// gla_chunk (MFMA): q,k inputs bf16; intra output o1 bf16
// ---------------------------------------------------------------------------
__global__ __launch_bounds__(256) void gla_chunk(const __hip_bfloat16* __restrict__ qb,
                                                 const __hip_bfloat16* __restrict__ kb,
                                                 const __hip_bfloat16* __restrict__ vT,
                                                 const float* __restrict__ g,
                                                 __hip_bfloat16* __restrict__ qg,
                                                 __hip_bfloat16* __restrict__ kgT,
                                                 __hip_bfloat16* __restrict__ o1,
                                                 float* __restrict__ dlast) {
    __shared__ __align__(16) short SM[36864];   // 72 KB
    short* qg_l = SM;            // rows t: 256 shorts (512B)
    short* kd_l = SM + 16384;
    short* V_l  = SM;            // alias: 512 rows x 64 shorts (128B rows)
    short* Am_l = SM + 32768;    // 64x64 (128B rows)

    const int chunk = blockIdx.x, bh = blockIdx.y;
    const int b = bh >> 2, h = bh & 3;
    const int t0 = b * 2048 + chunk * 64;
    const int tt0 = chunk * 64;
    const int tid = threadIdx.x;
    const float scale = 0.0625f;

    // ---- stage 1: thread = d column ----
    {
        const int d = tid;
        const float* gcol = g + (size_t)t0 * DKC + h * HDK_ + d;
        const __hip_bfloat16* qcol = qb + (size_t)t0 * DKC + h * HDK_ + d;
        const __hip_bfloat16* kcol = kb + (size_t)t0 * DKC + h * HDK_ + d;
        float run = 0.f;
#pragma unroll
        for (int i = 0; i < 64; ++i) run += gcol[(size_t)i * DKC];
        const float ebl = expf(run);
        dlast[((size_t)bh * NCH + chunk) * HDK_ + d] = ebl;

        bf16x8 kreg[8];
        run = 0.f;
#pragma unroll
        for (int i = 0; i < 64; ++i) {
            run += gcol[(size_t)i * DKC];
            float eb = expf(run);
            float qv = __bfloat162float(qcol[(size_t)i * DKC]) * eb * scale;
            float kdv = __bfloat162float(kcol[(size_t)i * DKC]) * expf(-run);
            qg[(size_t)(t0 + i) * DKC + h * HDK_ + d] = __float2bfloat16(qv);
            int bq = ((i * 512 + d * 2) ^ ((i & 7) << 4)) >> 1;
            qg_l[bq] = f2bf_bits(qv);
            kd_l[bq] = f2bf_bits(kdv);
            kreg[i >> 3][i & 7] = f2bf_bits(kdv * ebl);   // kg = kd * exp(b_last)
        }
        __hip_bfloat16* kdst = kgT + ((size_t)(bh * HDK_ + d)) * 2048 + chunk * 64;
#pragma unroll
        for (int j = 0; j < 8; ++j)
            *reinterpret_cast<bf16x8*>(&kdst[j * 8]) = kreg[j];
    }
    __syncthreads();

    const int wv = tid >> 6, lane = tid & 63;
    const int l15 = lane & 15, kb_ = lane >> 4;

    // ---- stage 2: A = tril(qg @ kd^T) ----
    {
        f32x4 accA[4];
#pragma unroll
        for (int sf = 0; sf < 4; ++sf) accA[sf] = (f32x4){0.f, 0.f, 0.f, 0.f};
        const int trow = wv * 16 + l15;
#pragma unroll
        for (int ks = 0; ks < 8; ++ks) {
            bf16x8 af = *reinterpret_cast<const bf16x8*>(
                &qg_l[((trow * 512 + (ks * 32 + kb_ * 8) * 2) ^ ((trow & 7) << 4)) >> 1]);
#pragma unroll
            for (int sf = 0; sf < 4; ++sf) {
                int srow = sf * 16 + l15;
                bf16x8 bfr = *reinterpret_cast<const bf16x8*>(
                    &kd_l[((srow * 512 + (ks * 32 + kb_ * 8) * 2) ^ ((srow & 7) << 4)) >> 1]);
                accA[sf] = __builtin_amdgcn_mfma_f32_16x16x32_bf16(af, bfr, accA[sf], 0, 0, 0);
            }
        }
#pragma unroll
        for (int sf = 0; sf < 4; ++sf)
#pragma unroll
            for (int r = 0; r < 4; ++r) {
                int t = wv * 16 + kb_ * 4 + r, s = sf * 16 + l15;
                float val = (t >= s) ? accA[sf][r] : 0.f;
                Am_l[((t * 128 + s * 2) ^ ((t & 7) << 4)) >> 1] = f2bf_bits(val);
            }
    }
    __syncthreads();

    // ---- stage 3: stage V, then o1 = Am @ vT^T (bf16 out) ----
    {
        const int lr8 = lane >> 3, slot = lane & 7;
#pragma unroll
        for (int i8 = 0; i8 < 16; ++i8) {
            int vrow0 = wv * 128 + i8 * 8;
            const __hip_bfloat16* src =
                &vT[((size_t)bh * 512 + vrow0 + lr8) * 2048 + tt0 + (slot ^ (lr8 & 7)) * 8];
            gl_lds16(src, &V_l[vrow0 * 64]);
        }
    }
    __syncthreads();

    {
        f32x4 accO[4][8];
#pragma unroll
        for (int tf = 0; tf < 4; ++tf)
#pragma unroll
            for (int vf = 0; vf < 8; ++vf) accO[tf][vf] = (f32x4){0.f, 0.f, 0.f, 0.f};
#pragma unroll
        for (int kk = 0; kk < 2; ++kk) {
            bf16x8 af[4];
#pragma unroll
            for (int tf = 0; tf < 4; ++tf) {
                int row = tf * 16 + l15;
                af[tf] = *reinterpret_cast<const bf16x8*>(
                    &Am_l[((row * 128 + (kk * 32 + kb_ * 8) * 2) ^ ((row & 7) << 4)) >> 1]);
            }
#pragma unroll
            for (int vf = 0; vf < 8; ++vf) {
                int rv = wv * 128 + vf * 16 + l15;
                bf16x8 bfr = *reinterpret_cast<const bf16x8*>(
                    &V_l[((rv * 128 + (kk * 32 + kb_ * 8) * 2) ^ ((rv & 7) << 4)) >> 1]);
#pragma unroll
                for (int tf = 0; tf < 4; ++tf)
                    accO[tf][vf] = __builtin_amdgcn_mfma_f32_16x16x32_bf16(af[tf], bfr, accO[tf][vf], 0, 0, 0);
            }
        }
#pragma unroll
        for (int tf = 0; tf < 4; ++tf)
#pragma unroll
            for (int vf = 0; vf < 8; ++vf)
#pragma unroll
                for (int r = 0; r < 4; ++r) {
                    int t = tf * 16 + kb_ * 4 + r;
                    int vv = wv * 128 + vf * 16 + l15;
                    o1[(size_t)(t0 + t) * DVC + h * HDV_ + vv] = __float2bfloat16(accO[tf][vf][r]);
                }
    }
}

// ---------------------------------------------------------------------------
// u_pass (MFMA): U'[bh][c][vc][d] bf16 = sum_t v[t][vc]*kg[t][d]
// ---------------------------------------------------------------------------
__global__ __launch_bounds__(256) void u_pass(const __hip_bfloat16* __restrict__ vT,
                                              const __hip_bfloat16* __restrict__ kgT,
                                              __hip_bfloat16* __restrict__ U) {
    __shared__ __align__(16) short Av[128 * 64];
    __shared__ __align__(16) short Bv[128 * 64];
    const int bx = blockIdx.x, c = blockIdx.y, bh = blockIdx.z;
    const int vc0 = (bx >> 1) * 128, d0 = (bx & 1) * 128;
    const int tid = threadIdx.x;
    const int wave = tid >> 6, lane = tid & 63;
    const int wr = wave >> 1, wc = wave & 1;
    const int l15 = lane & 15, kb = lane >> 4;
    const int lr8 = lane >> 3, lc8 = (lane & 7) * 8;

#pragma unroll
    for (int j = 0; j < 4; ++j) {
        int inst = wave * 4 + j;
        int r = inst * 8 + lr8;
        gl_lds16(&vT[((size_t)bh * 512 + vc0 + r) * 2048 + c * 64 + lc8], &Av[inst * 512]);
        gl_lds16(&kgT[((size_t)bh * HDK_ + d0 + r) * 2048 + c * 64 + lc8], &Bv[inst * 512]);
    }
    __syncthreads();

    f32x4 acc[4][4];
#pragma unroll
    for (int mf = 0; mf < 4; ++mf)
#pragma unroll
        for (int nf = 0; nf < 4; ++nf) acc[mf][nf] = (f32x4){0.f, 0.f, 0.f, 0.f};
#pragma unroll
    for (int kk = 0; kk < 2; ++kk) {
        bf16x8 af[4], bfr[4];
#pragma unroll
        for (int mf = 0; mf < 4; ++mf)
            af[mf] = *reinterpret_cast<const bf16x8*>(&Av[(wr * 64 + mf * 16 + l15) * 64 + kk * 32 + kb * 8]);
#pragma unroll
        for (int nf = 0; nf < 4; ++nf)
            bfr[nf] = *reinterpret_cast<const bf16x8*>(&Bv[(wc * 64 + nf * 16 + l15) * 64 + kk * 32 + kb * 8]);
#pragma unroll
        for (int mf = 0; mf < 4; ++mf)
#pragma unroll
            for (int nf = 0; nf < 4; ++nf)
                acc[mf][nf] = __builtin_amdgcn_mfma_f32_16x16x32_bf16(af[mf], bfr[nf], acc[mf][nf], 0, 0, 0);
    }
    const size_t Ub = ((size_t)bh * NCH + c) * 131072;
#pragma unroll
    for (int mf = 0; mf < 4; ++mf)
#pragma unroll
        for (int nf = 0; nf < 4; ++nf)
#pragma unroll
            for (int r = 0; r < 4; ++r) {
                int vc = vc0 + wr * 64 + mf * 16 + kb * 4 + r;
                int d = d0 + wc * 64 + nf * 16 + l15;
                U[Ub + (size_t)vc * 256 + d] = __float2bfloat16(acc[mf][nf][r]);
            }
}

// ---------------------------------------------------------------------------
// scan_pass on U'[bh][c][vc][d]: exclusive scan over chunks, decay e(d)
// ---------------------------------------------------------------------------
__global__ __launch_bounds__(256) void scan_pass(__hip_bfloat16* __restrict__ U,
                                                 const float* __restrict__ dlast) {
    int gid = blockIdx.x * 256 + threadIdx.x;   // 131072
    int bh = gid >> 14;
    int rem = gid & 16383;
    int vc = rem >> 5;
    int dg = rem & 31;
    float S[8];
#pragma unroll
    for (int j = 0; j < 8; ++j) S[j] = 0.f;
    size_t base = (size_t)bh * NCH * 131072 + (size_t)vc * 256 + dg * 8;
    for (int c = 0; c < NCH; ++c) {
        __hip_bfloat16* p = U + base + (size_t)c * 131072;
        bf16x8 u = *reinterpret_cast<bf16x8*>(p);
        const float* dl = &dlast[((size_t)bh * NCH + c) * HDK_ + dg * 8];
        float4 e0 = *reinterpret_cast<const float4*>(dl);
        float4 e1 = *reinterpret_cast<const float4*>(dl + 4);
        float e[8] = {e0.x, e0.y, e0.z, e0.w, e1.x, e1.y, e1.z, e1.w};
        bf16x8 outv;
#pragma unroll
        for (int j = 0; j < 8; ++j) {
            outv[j] = f2bf_bits(S[j]);
            S[j] = S[j] * e[j] + bf2f(u[j]);
        }
        *reinterpret_cast<bf16x8*>(p) = outv;
    }
}

// ---------------------------------------------------------------------------
// o_pass (MFMA): o2[t][vc] (bf16) = o1[t][vc] + sum_d qg[t][d] * S'[vc][d]
// ---------------------------------------------------------------------------
__global__ __launch_bounds__(256) void o_pass(const __hip_bfloat16* __restrict__ qg,
                                              const __hip_bfloat16* __restrict__ U,
                                              const __hip_bfloat16* __restrict__ o1,
                                              __hip_bfloat16* __restrict__ o2) {
    __shared__ __align__(16) char smem[64 * 132 * 4];   // 33.8 KB
    short* Av = (short*)smem;               // 128x64 bf16 = 16 KB
    short* Bv = (short*)smem + 128 * 64;    // 64x64 bf16 = 8 KB
    float* oT = (float*)smem;               // [64 t][132] f32 (epilogue, aliases)
    const int vt = blockIdx.x, c = blockIdx.y, bh = blockIdx.z;
    const int b = bh >> 2, h = bh & 3;
    const int vc0 = vt * 128;
    const int t0 = b * 2048 + c * 64;
    const int tid = threadIdx.x;
    const int wave = tid >> 6, lane = tid & 63;
    const int wr = wave >> 1, wc = wave & 1;
    const int l15 = lane & 15, kb = lane >> 4;
    const int lr8 = lane >> 3, lc8 = (lane & 7) * 8;
    const size_t Ub = ((size_t)bh * NCH + c) * 131072;

    f32x4 acc[4][2];
#pragma unroll
    for (int mf = 0; mf < 4; ++mf)
#pragma unroll
        for (int nf = 0; nf < 2; ++nf) acc[mf][nf] = (f32x4){0.f, 0.f, 0.f, 0.f};

    for (int ks = 0; ks < 4; ++ks) {
        const int d0 = ks * 64;
#pragma unroll
        for (int j = 0; j < 4; ++j) {
            int inst = wave * 4 + j;
            int r = inst * 8 + lr8;
            gl_lds16(&U[Ub + (size_t)(vc0 + r) * 256 + d0 + lc8], &Av[inst * 512]);
        }
#pragma unroll
        for (int j = 0; j < 2; ++j) {
            int inst = wave * 2 + j;
            int r = inst * 8 + lr8;
            gl_lds16(&qg[(size_t)(t0 + r) * DKC + h * HDK_ + d0 + lc8], &Bv[inst * 512]);
        }
        __syncthreads();
#pragma unroll
        for (int kk = 0; kk < 2; ++kk) {
            bf16x8 af[4], bfr[2];
#pragma unroll
            for (int mf = 0; mf < 4; ++mf)
                af[mf] = *reinterpret_cast<const bf16x8*>(&Av[(wr * 64 + mf * 16 + l15) * 64 + kk * 32 + kb * 8]);
#pragma unroll
            for (int nf = 0; nf < 2; ++nf)
                bfr[nf] = *reinterpret_cast<const bf16x8*>(&Bv[(wc * 32 + nf * 16 + l15) * 64 + kk * 32 + kb * 8]);
#pragma unroll
            for (int mf = 0; mf < 4; ++mf)
#pragma unroll
                for (int nf = 0; nf < 2; ++nf)
                    acc[mf][nf] = __builtin_amdgcn_mfma_f32_16x16x32_bf16(af[mf], bfr[nf], acc[mf][nf], 0, 0, 0);
        }
        __syncthreads();
    }
    // acc (mf,nf,r): vc = wr*64+mf*16+kb*4+r, t = wc*32+nf*16+l15 -> oT[t][vc]
#pragma unroll
    for (int mf = 0; mf < 4; ++mf)
#pragma unroll
        for (int nf = 0; nf < 2; ++nf)
#pragma unroll
            for (int r = 0; r < 4; ++r)
                oT[(wc * 32 + nf * 16 + l15) * 132 + wr * 64 + mf * 16 + kb * 4 + r] = acc[mf][nf][r];
    __syncthreads();
#pragma unroll
    for (int j = 0; j < 4; ++j) {
        int t = (tid >> 4) + j * 16;         // 0..63
        int vc8 = (tid & 15) * 8;            // 0..120
        float4 a0 = *reinterpret_cast<const float4*>(&oT[t * 132 + vc8]);
        float4 a1 = *reinterpret_cast<const float4*>(&oT[t * 132 + vc8 + 4]);
        size_t oi = (size_t)(t0 + t) * DVC + h * HDV_ + vc0 + vc8;
        bf16x8 iv = *reinterpret_cast<const bf16x8*>(&o1[oi]);
        bf16x8 outv;
        outv[0] = f2bf_bits(a0.x + bf2f(iv[0]));
        outv[1] = f2bf_bits(a0.y + bf2f(iv[1]));
        outv[2] = f2bf_bits(a0.z + bf2f(iv[2]));
        outv[3] = f2bf_bits(a0.w + bf2f(iv[3]));
        outv[4] = f2bf_bits(a1.x + bf2f(iv[4]));
        outv[5] = f2bf_bits(a1.y + bf2f(iv[5]));
        outv[6] = f2bf_bits(a1.z + bf2f(iv[6]));
        outv[7] = f2bf_bits(a1.w + bf2f(iv[7]));
        *reinterpret_cast<bf16x8*>((__hip_bfloat16*)o2 + oi) = outv;
    }
}

// ---------------------------------------------------------------------------
// RMSNorm * rms_w * silu(xg)  (all bf16 in, bf16 out, vectorized pairs)
// ---------------------------------------------------------------------------
__global__ __launch_bounds__(256) void rms_gate(const __hip_bfloat16* __restrict__ o2,
                                                const __hip_bfloat16* __restrict__ xg,
                                                const float* __restrict__ rms_w,
                                                __hip_bfloat16* __restrict__ gated) {
    __shared__ float wsum[4];
    const int th = blockIdx.x;
    const int t = th >> 2, h = th & 3;
    const int tid = threadIdx.x;
    const size_t base = (size_t)t * DVC + h * HDV_;
    short2 ov = reinterpret_cast<const short2*>((const short*)o2 + base)[tid];
    float v0 = bf2f(ov.x), v1 = bf2f(ov.y);
    float s = v0 * v0 + v1 * v1;
#pragma unroll
    for (int off = 32; off >= 1; off >>= 1) s += __shfl_down(s, off, 64);
    if ((tid & 63) == 0) wsum[tid >> 6] = s;
    __syncthreads();
    float tot = wsum[0] + wsum[1] + wsum[2] + wsum[3];
    float rms = rsqrtf(tot * (1.f / 512.f) + 1e-5f);
    short2 gv = reinterpret_cast<const short2*>((const short*)xg + base)[tid];
    float g0 = bf2f(gv.x), g1 = bf2f(gv.y);
    float s0 = g0 / (1.f + expf(-g0));
    float s1 = g1 / (1.f + expf(-g1));
    float2 w = reinterpret_cast<const float2*>(rms_w)[tid];
    short2 outp;
    outp.x = f2bf_bits(v0 * rms * w.x * s0);
    outp.y = f2bf_bits(v1 * rms * w.y * s1);
    reinterpret_cast<short2*>((short*)gated + base)[tid] = outp;
}

// ---------------------------------------------------------------------------
extern "C" void kernel_launch(void* const* d_in, const int* in_sizes, int n_in,
                              void* d_out, int out_size, void* d_ws, size_t ws_size,
                              hipStream_t stream) {
    const float* x    = (const float*)d_in[0];
    const float* Wq   = (const float*)d_in[1];
    const float* Wk   = (const float*)d_in[2];
    const float* Wv   = (const float*)d_in[3];
    const float* Wg   = (const float*)d_in[4];
    const float* Wgk1 = (const float*)d_in[5];
    const float* Wgk2 = (const float*)d_in[6];
    const float* bgk2 = (const float*)d_in[7];
    const float* Wo   = (const float*)d_in[8];
    const float* rmsw = (const float*)d_in[9];
    float* out = (float*)d_out;
    float* ws = (float*)d_ws;

    const size_t M1 = 1ull << 20;   // floats
    // Region A [0,17M floats): dead by u_pass time; U (64MB) overlays [0,16M)
    __hip_bfloat16* xb    = (__hip_bfloat16*)ws;              // [0,2M)   8 MB
    __hip_bfloat16* WtAll = (__hip_bfloat16*)(ws + 2 * M1);   // [2M,5M)  12 MB (6144x1024)
    __hip_bfloat16* q_b   = (__hip_bfloat16*)(ws + 5 * M1);   // [5M,7M)  8 MB
    __hip_bfloat16* k_b   = (__hip_bfloat16*)(ws + 7 * M1);   // [7M,9M)  8 MB
    __hip_bfloat16* v_b   = (__hip_bfloat16*)(ws + 9 * M1);   // [9M,13M) 16 MB
    float*          g     = ws + 13 * M1;                     // [13M,17M) 16 MB
    __hip_bfloat16* U     = (__hip_bfloat16*)ws;              // [0,16M) 64 MB overlay
    __hip_bfloat16* xg_b  = (__hip_bfloat16*)(ws + 17 * M1);  // [17M,21M) 16 MB
    __hip_bfloat16* qgb   = (__hip_bfloat16*)(ws + 21 * M1);  // [21M,23M) 8 MB
    __hip_bfloat16* kgT   = (__hip_bfloat16*)(ws + 23 * M1);  // [23M,25M) 8 MB
    __hip_bfloat16* vT    = (__hip_bfloat16*)(ws + 25 * M1);  // [25M,29M) 16 MB
    __hip_bfloat16* o1    = (__hip_bfloat16*)(ws + 29 * M1);  // [29M,33M) 16 MB
    __hip_bfloat16* o2    = (__hip_bfloat16*)(ws + 33 * M1);  // [33M,37M) 16 MB
    float*          t1    = ws + 37 * M1;                     // 256 KB
    float*          dlast = ws + 37 * M1 + 65536;             // 256 KB
    // overlays after u_pass/o_pass:
    __hip_bfloat16* WtO   = (__hip_bfloat16*)(ws + 23 * M1);  // over kgT (dead after u_pass)
    __hip_bfloat16* gated = (__hip_bfloat16*)(ws + 25 * M1);  // over vT  (dead after u_pass)

    conv_bf16<<<4096, 256, 0, stream>>>(x, xb);
    convT<<<dim3(32, 32), 256, 0, stream>>>(Wq, WtAll,                    DM, DKC);
    convT<<<dim3(32, 32), 256, 0, stream>>>(Wk, WtAll + 1024 * 1024,      DM, DKC);
    convT<<<dim3(64, 32), 256, 0, stream>>>(Wv, WtAll + 2048 * 1024,      DM, DVC);
    convT<<<dim3(64, 32), 256, 0, stream>>>(Wg, WtAll + 4096 * 1024,      DM, DVC);

    gemm_multi<<<dim3(48, 32), 256, 0, stream>>>(xb, WtAll, q_b, k_b, v_b, xg_b);

    transpose_v<<<dim3(64, 128), 256, 0, stream>>>(v_b, vT);
    lowrank1<<<TOK, 256, 0, stream>>>(x, Wgk1, t1);
    gate_k<<<(TOK * DKC) / 256, 256, 0, stream>>>(t1, Wgk2, bgk2, g);
    gla_chunk<<<dim3(NCH, 8), 256, 0, stream>>>(q_b, k_b, vT, g, qgb, kgT, o1, dlast);

    u_pass<<<dim3(8, NCH, 8), 256, 0, stream>>>(vT, kgT, U);
    scan_pass<<<512, 256, 0, stream>>>(U, dlast);
    o_pass<<<dim3(4, NCH, 8), 256, 0, stream>>>(qgb, U, o1, o2);

    convT<<<dim3(32, 64), 256, 0, stream>>>(Wo, WtO, DVC, DM);
    rms_gate<<<TOK * NH, 256, 0, stream>>>(o2, xg_b, rmsw, gated);
    gemm_bf16<<<dim3(8, 32), 256, 0, stream>>>(gated, WtO, out, TOK, DM, DVC);
}

// Round 12
// 271.385 us; speedup vs baseline: 5.7908x; 1.0316x over previous
//
#include <hip/hip_runtime.h>
#include <hip/hip_bf16.h>
#include <math.h>

#define TOK  4096
#define DM   1024
#define DKC  1024
#define DVC  2048
#define NH   4
#define HDK_ 256
#define HDV_ 512
#define NCH  32
#define CHK  64

typedef __attribute__((ext_vector_type(8))) short bf16x8;
typedef __attribute__((ext_vector_type(4))) float f32x4;

__device__ inline float bf2f(short s) {
    unsigned int b = ((unsigned int)(unsigned short)s) << 16;
    return __uint_as_float(b);
}
__device__ inline short f2bf_bits(float f) {
    __hip_bfloat16 h = __float2bfloat16(f);
    return *reinterpret_cast<short*>(&h);
}

// async global->LDS, 16B per lane; lds dest = base + lane*16 (wave-uniform base)
__device__ __forceinline__ void gl_lds16(const void* g, void* l) {
    __builtin_amdgcn_global_load_lds((const __attribute__((address_space(1))) void*)g,
                                     (__attribute__((address_space(3))) void*)l, 16, 0, 0);
}

// ---------------------------------------------------------------------------
// x (f32) -> bf16 copy
// ---------------------------------------------------------------------------
__global__ __launch_bounds__(256) void conv_bf16(const float* __restrict__ in,
                                                 __hip_bfloat16* __restrict__ out) {
    size_t i = ((size_t)blockIdx.x * 256 + threadIdx.x) * 4;
    float4 v = *reinterpret_cast<const float4*>(&in[i]);
    out[i + 0] = __float2bfloat16(v.x);
    out[i + 1] = __float2bfloat16(v.y);
    out[i + 2] = __float2bfloat16(v.z);
    out[i + 3] = __float2bfloat16(v.w);
}

// ---------------------------------------------------------------------------
// W[K][N] f32 -> Wt[N][K] bf16 (tiled transpose); grid = dim3(N/32, K/32)
// ---------------------------------------------------------------------------
__global__ __launch_bounds__(256) void convT(const float* __restrict__ W,
                                             __hip_bfloat16* __restrict__ Wt,
                                             int K, int N) {
    __shared__ float tile[32][33];
    int n0 = blockIdx.x * 32, k0 = blockIdx.y * 32;
    int tx = threadIdx.x & 31, ty = threadIdx.x >> 5;
#pragma unroll
    for (int i = 0; i < 32; i += 8)
        tile[ty + i][tx] = W[(size_t)(k0 + ty + i) * N + n0 + tx];
    __syncthreads();
#pragma unroll
    for (int i = 0; i < 32; i += 8)
        Wt[(size_t)(n0 + ty + i) * K + k0 + tx] = __float2bfloat16(tile[tx][ty + i]);
}

// ---------------------------------------------------------------------------
// v bf16 [4096t][2048] -> vT bf16 [bh=8][512vc][2048t]
// ---------------------------------------------------------------------------
__global__ __launch_bounds__(256) void transpose_v(const __hip_bfloat16* __restrict__ v,
                                                   __hip_bfloat16* __restrict__ vT) {
    __shared__ short tile[32][33];
    const int tg0 = blockIdx.y * 32;
    const int vg0 = blockIdx.x * 32;
    const int tx = threadIdx.x & 31, ty = threadIdx.x >> 5;
    const short* vs = (const short*)v;
#pragma unroll
    for (int i = 0; i < 32; i += 8)
        tile[ty + i][tx] = vs[(size_t)(tg0 + ty + i) * DVC + vg0 + tx];
    __syncthreads();
    const int b = tg0 >> 11, tl0 = tg0 & 2047;
    const int h = vg0 >> 9, vl0 = vg0 & 511;
    const int bh = b * NH + h;
    short* vTs = (short*)vT;
#pragma unroll
    for (int i = 0; i < 32; i += 8)
        vTs[((size_t)bh * 512 + vl0 + ty + i) * 2048 + tl0 + tx] = tile[tx][ty + i];
}

// ---------------------------------------------------------------------------
// FUSED projection GEMM, 256x256 tile, 512 thr (8 waves 2Mx4N), BK=64.
// 9-slot x 16KB LDS ring of half-tile units {A0,A1,B0,B1}/K-tile.
// Counted vmcnt(2) per tile (never 0 mid-loop); (row&7) XOR swizzle with
// pre-swizzled global source (rule 21). grid (24, 16).
// ---------------------------------------------------------------------------
__global__ __launch_bounds__(512) void gemm256(const __hip_bfloat16* __restrict__ A,
                                               const __hip_bfloat16* __restrict__ Wt,
                                               __hip_bfloat16* __restrict__ qo,
                                               __hip_bfloat16* __restrict__ ko,
                                               __hip_bfloat16* __restrict__ vo,
                                               __hip_bfloat16* __restrict__ xgo) {
    __shared__ __align__(16) short SM[9 * 8192];   // 144 KB ring
    const int K = 1024, NT = 16;
    const int tid = threadIdx.x;
    const int wave = tid >> 6, lane = tid & 63;
    const int wr = wave >> 2;        // M half (0..1)
    const int wc = wave & 3;         // N quarter (0..3)
    const int hc = wc >> 1;          // B half
    const int l15 = lane & 15, kb = lane >> 4;
    const int m0 = blockIdx.y * 256, n0 = blockIdx.x * 256;

    __hip_bfloat16* dst; int ldd, nloc0;
    if (n0 < 1024)      { dst = qo;  ldd = 1024; nloc0 = n0; }
    else if (n0 < 2048) { dst = ko;  ldd = 1024; nloc0 = n0 - 1024; }
    else if (n0 < 4096) { dst = vo;  ldd = 2048; nloc0 = n0 - 2048; }
    else                { dst = xgo; ldd = 2048; nloc0 = n0 - 4096; }

    f32x4 acc[8][4];
#pragma unroll
    for (int mf = 0; mf < 8; ++mf)
#pragma unroll
        for (int nf = 0; nf < 4; ++nf) acc[mf][nf] = (f32x4){0.f, 0.f, 0.f, 0.f};

    // stage one 16KB unit: u = tile*4 + p; p<2: A-half p, else B-half p-2.
    auto stage_unit = [&](int u) {
        int tk = u >> 2, p = u & 3;
        int slot = u % 9;
#pragma unroll
        for (int j = 0; j < 2; ++j) {
            int row = (wave * 2 + j) * 8 + (lane >> 3);   // 0..127
            int srcg = (lane & 7) ^ (row & 7);            // pre-swizzled source granule
            const __hip_bfloat16* src =
                (p < 2) ? &A[(size_t)(m0 + p * 128 + row) * K + tk * 64 + srcg * 8]
                        : &Wt[(size_t)(n0 + (p - 2) * 128 + row) * K + tk * 64 + srcg * 8];
            gl_lds16(src, &SM[slot * 8192 + (wave * 2 + j) * 512]);
        }
    };

    // prologue: units 0..4  (tile0 fully + 1 unit of tile1)
    for (int u = 0; u <= 4; ++u) stage_unit(u);

    for (int t = 0; t < NT; ++t) {
        if (t < NT - 1) asm volatile("s_waitcnt vmcnt(2)" ::: "memory");
        else            asm volatile("s_waitcnt vmcnt(0)" ::: "memory");
        __builtin_amdgcn_sched_barrier(0);
        __builtin_amdgcn_s_barrier();

        // stage ahead: units 4t+5 .. min(4t+8, last)  (ring-safe: u <= 4t+8)
        {
            int umax = 4 * t + 8;
            if (umax > 4 * NT - 1) umax = 4 * NT - 1;
            for (int u = 4 * t + 5; u <= umax; ++u) stage_unit(u);
        }

        const int sA = (4 * t + wr) % 9;
        const int sB = (4 * t + 2 + hc) % 9;
        const short* Abase = &SM[sA * 8192];
        const short* Bbase = &SM[sB * 8192];
#pragma unroll
        for (int kk = 0; kk < 2; ++kk) {
            bf16x8 a[8], bfr[4];
#pragma unroll
            for (int mf = 0; mf < 8; ++mf) {
                int row = mf * 16 + l15;
                int gsw = (kk * 4 + kb) ^ (row & 7);
                a[mf] = *reinterpret_cast<const bf16x8*>(&Abase[row * 64 + gsw * 8]);
            }
#pragma unroll
            for (int nf = 0; nf < 4; ++nf) {
                int row = (wc & 1) * 64 + nf * 16 + l15;
                int gsw = (kk * 4 + kb) ^ (row & 7);
                bfr[nf] = *reinterpret_cast<const bf16x8*>(&Bbase[row * 64 + gsw * 8]);
            }
            __builtin_amdgcn_s_setprio(1);
#pragma unroll
            for (int mf = 0; mf < 8; ++mf)
#pragma unroll
                for (int nf = 0; nf < 4; ++nf)
                    acc[mf][nf] = __builtin_amdgcn_mfma_f32_16x16x32_bf16(a[mf], bfr[nf], acc[mf][nf], 0, 0, 0);
            __builtin_amdgcn_s_setprio(0);
        }
    }

#pragma unroll
    for (int mf = 0; mf < 8; ++mf)
#pragma unroll
        for (int nf = 0; nf < 4; ++nf)
#pragma unroll
            for (int r = 0; r < 4; ++r)
                dst[(size_t)(m0 + wr * 128 + mf * 16 + kb * 4 + r) * ldd +
                    nloc0 + wc * 64 + nf * 16 + l15] = __float2bfloat16(acc[mf][nf][r]);
}

// ---------------------------------------------------------------------------
// Double-buffered bf16 MFMA GEMM, f32 C (final Wo projection).
// ---------------------------------------------------------------------------
__global__ __launch_bounds__(256) void gemm_bf16(const __hip_bfloat16* __restrict__ A,
                                                 const __hip_bfloat16* __restrict__ Wt,
                                                 float* __restrict__ C,
                                                 int M, int N, int K) {
    __shared__ __align__(16) short Buf[2][2][128 * 64];   // [dbuf][A/B] 64 KB
    const int tid = threadIdx.x;
    const int wave = tid >> 6, lane = tid & 63;
    const int wr = wave >> 1, wc = wave & 1;
    const int m0 = blockIdx.y * 128, n0 = blockIdx.x * 128;
    const int l15 = lane & 15, kb = lane >> 4;
    const int lr8 = lane >> 3, lc8 = (lane & 7) * 8;
    const int NT = K >> 6;

    f32x4 acc[4][4];
#pragma unroll
    for (int mf = 0; mf < 4; ++mf)
#pragma unroll
        for (int nf = 0; nf < 4; ++nf) acc[mf][nf] = (f32x4){0.f, 0.f, 0.f, 0.f};

#define STAGE_G(kt, bi)                                                          \
    {                                                                            \
        int k0s = (kt) * 64;                                                     \
        _Pragma("unroll")                                                        \
        for (int j = 0; j < 4; ++j) {                                            \
            int inst = wave * 4 + j;                                             \
            int r = inst * 8 + lr8;                                              \
            gl_lds16(&A[(size_t)(m0 + r) * K + k0s + lc8], &Buf[bi][0][inst * 512]); \
            gl_lds16(&Wt[(size_t)(n0 + r) * K + k0s + lc8], &Buf[bi][1][inst * 512]); \
        }                                                                        \
    }

    STAGE_G(0, 0);
    STAGE_G(1, 1);

    for (int t = 0; t < NT; ++t) {
        if (t + 1 < NT) asm volatile("s_waitcnt vmcnt(8)" ::: "memory");
        else            asm volatile("s_waitcnt vmcnt(0)" ::: "memory");
        __builtin_amdgcn_sched_barrier(0);
        __builtin_amdgcn_s_barrier();
        const short* Ab = Buf[t & 1][0];
        const short* Bb = Buf[t & 1][1];
#pragma unroll
        for (int kk = 0; kk < 2; ++kk) {
            bf16x8 af[4], bfr[4];
#pragma unroll
            for (int mf = 0; mf < 4; ++mf)
                af[mf] = *reinterpret_cast<const bf16x8*>(&Ab[(wr * 64 + mf * 16 + l15) * 64 + kk * 32 + kb * 8]);
#pragma unroll
            for (int nf = 0; nf < 4; ++nf)
                bfr[nf] = *reinterpret_cast<const bf16x8*>(&Bb[(wc * 64 + nf * 16 + l15) * 64 + kk * 32 + kb * 8]);
#pragma unroll
            for (int mf = 0; mf < 4; ++mf)
#pragma unroll
                for (int nf = 0; nf < 4; ++nf)
                    acc[mf][nf] = __builtin_amdgcn_mfma_f32_16x16x32_bf16(af[mf], bfr[nf], acc[mf][nf], 0, 0, 0);
        }
        asm volatile("s_waitcnt lgkmcnt(0)" ::: "memory");
        __builtin_amdgcn_sched_barrier(0);
        __builtin_amdgcn_s_barrier();
        if (t + 2 < NT) STAGE_G(t + 2, t & 1);
    }
#undef STAGE_G

#pragma unroll
    for (int mf = 0; mf < 4; ++mf)
#pragma unroll
        for (int nf = 0; nf < 4; ++nf)
#pragma unroll
            for (int r = 0; r < 4; ++r)
                C[(size_t)(m0 + wr * 64 + mf * 16 + kb * 4 + r) * N + n0 + wc * 64 + nf * 16 + l15] =
                    acc[mf][nf][r];
}

// ---------------------------------------------------------------------------
// t1 = x @ Wgk1
// ---------------------------------------------------------------------------
__global__ __launch_bounds__(256) void lowrank1(const float* __restrict__ x,
                                                const float* __restrict__ W1,
                                                float* __restrict__ t1) {
    __shared__ float red[16][17];
    const int t = blockIdx.x;
    const int tid = threadIdx.x;
    const int o = tid & 15;
    const int p = tid >> 4;
    float s = 0.f;
#pragma unroll 8
    for (int m = 0; m < 64; ++m) {
        int kk = p * 64 + m;
        s += x[(size_t)t * DM + kk] * W1[kk * 16 + o];
    }
    red[p][o] = s;
    __syncthreads();
    if (tid < 16) {
        float tot = 0.f;
#pragma unroll
        for (int pp = 0; pp < 16; ++pp) tot += red[pp][tid];
        t1[(size_t)t * 16 + tid] = tot;
    }
}

// ---------------------------------------------------------------------------
// g = log_sigmoid(t1 @ Wgk2 + b) / 16
// ---------------------------------------------------------------------------
__global__ __launch_bounds__(256) void gate_k(const float* __restrict__ t1,
                                              const float* __restrict__ W2,
                                              const float* __restrict__ b2,
                                              float* __restrict__ g) {
    const size_t idx = (size_t)blockIdx.x * 256 + threadIdx.x;
    const int t = (int)(idx >> 10), c = (int)(idx & 1023);
    float acc = b2[c];
#pragma unroll
    for (int r = 0; r < 16; ++r) acc += t1[(size_t)t * 16 + r] * W2[r * 1024 + c];
    float ls = fminf(acc, 0.f) - log1pf(expf(-fabsf(acc)));
    g[idx] = ls * (1.f / 16.f);
}

// ---------------------------------------------------------------------------
// gla_chunk (MFMA): q,k inputs bf16; intra output o1 bf16
// ---------------------------------------------------------------------------
__global__ __launch_bounds__(256) void gla_chunk(const __hip_bfloat16* __restrict__ qb,
                                                 const __hip_bfloat16* __restrict__ kb,
                                                 const __hip_bfloat16* __restrict__ vT,
                                                 const float* __restrict__ g,
                                                 __hip_bfloat16* __restrict__ qg,
                                                 __hip_bfloat16* __restrict__ kgT,
                                                 __hip_bfloat16* __restrict__ o1,
                                                 float* __restrict__ dlast) {
    __shared__ __align__(16) short SM[36864];   // 72 KB
    short* qg_l = SM;            // rows t: 256 shorts (512B)
    short* kd_l = SM + 16384;
    short* V_l  = SM;            // alias: 512 rows x 64 shorts (128B rows)
    short* Am_l = SM + 32768;    // 64x64 (128B rows)

    const int chunk = blockIdx.x, bh = blockIdx.y;
    const int b = bh >> 2, h = bh & 3;
    const int t0 = b * 2048 + chunk * 64;
    const int tt0 = chunk * 64;
    const int tid = threadIdx.x;
    const float scale = 0.0625f;

    // ---- stage 1: thread = d column ----
    {
        const int d = tid;
        const float* gcol = g + (size_t)t0 * DKC + h * HDK_ + d;
        const __hip_bfloat16* qcol = qb + (size_t)t0 * DKC + h * HDK_ + d;
        const __hip_bfloat16* kcol = kb + (size_t)t0 * DKC + h * HDK_ + d;
        float run = 0.f;
#pragma unroll
        for (int i = 0; i < 64; ++i) run += gcol[(size_t)i * DKC];
        const float ebl = expf(run);
        dlast[((size_t)bh * NCH + chunk) * HDK_ + d] = ebl;

        bf16x8 kreg[8];
        run = 0.f;
#pragma unroll
        for (int i = 0; i < 64; ++i) {
            run += gcol[(size_t)i * DKC];
            float eb = expf(run);
            float qv = __bfloat162float(qcol[(size_t)i * DKC]) * eb * scale;
            float kdv = __bfloat162float(kcol[(size_t)i * DKC]) * expf(-run);
            qg[(size_t)(t0 + i) * DKC + h * HDK_ + d] = __float2bfloat16(qv);
            int bq = ((i * 512 + d * 2) ^ ((i & 7) << 4)) >> 1;
            qg_l[bq] = f2bf_bits(qv);
            kd_l[bq] = f2bf_bits(kdv);
            kreg[i >> 3][i & 7] = f2bf_bits(kdv * ebl);   // kg = kd * exp(b_last)
        }
        __hip_bfloat16* kdst = kgT + ((size_t)(bh * HDK_ + d)) * 2048 + chunk * 64;
#pragma unroll
        for (int j = 0; j < 8; ++j)
            *reinterpret_cast<bf16x8*>(&kdst[j * 8]) = kreg[j];
    }
    __syncthreads();

    const int wv = tid >> 6, lane = tid & 63;
    const int l15 = lane & 15, kb_ = lane >> 4;

    // ---- stage 2: A = tril(qg @ kd^T) ----
    {
        f32x4 accA[4];
#pragma unroll
        for (int sf = 0; sf < 4; ++sf) accA[sf] = (f32x4){0.f, 0.f, 0.f, 0.f};
        const int trow = wv * 16 + l15;
#pragma unroll
        for (int ks = 0; ks < 8; ++ks) {
            bf16x8 af = *reinterpret_cast<const bf16x8*>(
                &qg_l[((trow * 512 + (ks * 32 + kb_ * 8) * 2) ^ ((trow & 7) << 4)) >> 1]);
#pragma unroll
            for (int sf = 0; sf < 4; ++sf) {
                int srow = sf * 16 + l15;
                bf16x8 bfr = *reinterpret_cast<const bf16x8*>(
                    &kd_l[((srow * 512 + (ks * 32 + kb_ * 8) * 2) ^ ((srow & 7) << 4)) >> 1]);
                accA[sf] = __builtin_amdgcn_mfma_f32_16x16x32_bf16(af, bfr, accA[sf], 0, 0, 0);
            }
        }
#pragma unroll
        for (int sf = 0; sf < 4; ++sf)
#pragma unroll
            for (int r = 0; r < 4; ++r) {
                int t = wv * 16 + kb_ * 4 + r, s = sf * 16 + l15;
                float val = (t >= s) ? accA[sf][r] : 0.f;
                Am_l[((t * 128 + s * 2) ^ ((t & 7) << 4)) >> 1] = f2bf_bits(val);
            }
    }
    __syncthreads();

    // ---- stage 3: stage V, then o1 = Am @ vT^T (bf16 out) ----
    {
        const int lr8 = lane >> 3, slot = lane & 7;
#pragma unroll
        for (int i8 = 0; i8 < 16; ++i8) {
            int vrow0 = wv * 128 + i8 * 8;
            const __hip_bfloat16* src =
                &vT[((size_t)bh * 512 + vrow0 + lr8) * 2048 + tt0 + (slot ^ (lr8 & 7)) * 8];
            gl_lds16(src, &V_l[vrow0 * 64]);
        }
    }
    __syncthreads();

    {
        f32x4 accO[4][8];
#pragma unroll
        for (int tf = 0; tf < 4; ++tf)
#pragma unroll
            for (int vf = 0; vf < 8; ++vf) accO[tf][vf] = (f32x4){0.f, 0.f, 0.f, 0.f};
#pragma unroll
        for (int kk = 0; kk < 2; ++kk) {
            bf16x8 af[4];
#pragma unroll
            for (int tf = 0; tf < 4; ++tf) {
                int row = tf * 16 + l15;
                af[tf] = *reinterpret_cast<const bf16x8*>(
                    &Am_l[((row * 128 + (kk * 32 + kb_ * 8) * 2) ^ ((row & 7) << 4)) >> 1]);
            }
#pragma unroll
            for (int vf = 0; vf < 8; ++vf) {
                int rv = wv * 128 + vf * 16 + l15;
                bf16x8 bfr = *reinterpret_cast<const bf16x8*>(
                    &V_l[((rv * 128 + (kk * 32 + kb_ * 8) * 2) ^ ((rv & 7) << 4)) >> 1]);
#pragma unroll
                for (int tf = 0; tf < 4; ++tf)
                    accO[tf][vf] = __builtin_amdgcn_mfma_f32_16x16x32_bf16(af[tf], bfr, accO[tf][vf], 0, 0, 0);
            }
        }
#pragma unroll
        for (int tf = 0; tf < 4; ++tf)
#pragma unroll
            for (int vf = 0; vf < 8; ++vf)
#pragma unroll
                for (int r = 0; r < 4; ++r) {
                    int t = tf * 16 + kb_ * 4 + r;
                    int vv = wv * 128 + vf * 16 + l15;
                    o1[(size_t)(t0 + t) * DVC + h * HDV_ + vv] = __float2bfloat16(accO[tf][vf][r]);
                }
    }
}

// ---------------------------------------------------------------------------
// u_pass (MFMA): U'[bh][c][vc][d] bf16 = sum_t v[t][vc]*kg[t][d]
// ---------------------------------------------------------------------------
__global__ __launch_bounds__(256) void u_pass(const __hip_bfloat16* __restrict__ vT,
                                              const __hip_bfloat16* __restrict__ kgT,
                                              __hip_bfloat16* __restrict__ U) {
    __shared__ __align__(16) short Av[128 * 64];
    __shared__ __align__(16) short Bv[128 * 64];
    const int bx = blockIdx.x, c = blockIdx.y, bh = blockIdx.z;
    const int vc0 = (bx >> 1) * 128, d0 = (bx & 1) * 128;
    const int tid = threadIdx.x;
    const int wave = tid >> 6, lane = tid & 63;
    const int wr = wave >> 1, wc = wave & 1;
    const int l15 = lane & 15, kb = lane >> 4;
    const int lr8 = lane >> 3, lc8 = (lane & 7) * 8;

#pragma unroll
    for (int j = 0; j < 4; ++j) {
        int inst = wave * 4 + j;
        int r = inst * 8 + lr8;
        gl_lds16(&vT[((size_t)bh * 512 + vc0 + r) * 2048 + c * 64 + lc8], &Av[inst * 512]);
        gl_lds16(&kgT[((size_t)bh * HDK_ + d0 + r) * 2048 + c * 64 + lc8], &Bv[inst * 512]);
    }
    __syncthreads();

    f32x4 acc[4][4];
#pragma unroll
    for (int mf = 0; mf < 4; ++mf)
#pragma unroll
        for (int nf = 0; nf < 4; ++nf) acc[mf][nf] = (f32x4){0.f, 0.f, 0.f, 0.f};
#pragma unroll
    for (int kk = 0; kk < 2; ++kk) {
        bf16x8 af[4], bfr[4];
#pragma unroll
        for (int mf = 0; mf < 4; ++mf)
            af[mf] = *reinterpret_cast<const bf16x8*>(&Av[(wr * 64 + mf * 16 + l15) * 64 + kk * 32 + kb * 8]);
#pragma unroll
        for (int nf = 0; nf < 4; ++nf)
            bfr[nf] = *reinterpret_cast<const bf16x8*>(&Bv[(wc * 64 + nf * 16 + l15) * 64 + kk * 32 + kb * 8]);
#pragma unroll
        for (int mf = 0; mf < 4; ++mf)
#pragma unroll
            for (int nf = 0; nf < 4; ++nf)
                acc[mf][nf] = __builtin_amdgcn_mfma_f32_16x16x32_bf16(af[mf], bfr[nf], acc[mf][nf], 0, 0, 0);
    }
    const size_t Ub = ((size_t)bh * NCH + c) * 131072;
#pragma unroll
    for (int mf = 0; mf < 4; ++mf)
#pragma unroll
        for (int nf = 0; nf < 4; ++nf)
#pragma unroll
            for (int r = 0; r < 4; ++r) {
                int vc = vc0 + wr * 64 + mf * 16 + kb * 4 + r;
                int d = d0 + wc * 64 + nf * 16 + l15;
                U[Ub + (size_t)vc * 256 + d] = __float2bfloat16(acc[mf][nf][r]);
            }
}

// ---------------------------------------------------------------------------
// scan_pass on U'[bh][c][vc][d]: exclusive scan over chunks, decay e(d)
// ---------------------------------------------------------------------------
__global__ __launch_bounds__(256) void scan_pass(__hip_bfloat16* __restrict__ U,
                                                 const float* __restrict__ dlast) {
    int gid = blockIdx.x * 256 + threadIdx.x;   // 131072
    int bh = gid >> 14;
    int rem = gid & 16383;
    int vc = rem >> 5;
    int dg = rem & 31;
    float S[8];
#pragma unroll
    for (int j = 0; j < 8; ++j) S[j] = 0.f;
    size_t base = (size_t)bh * NCH * 131072 + (size_t)vc * 256 + dg * 8;
    for (int c = 0; c < NCH; ++c) {
        __hip_bfloat16* p = U + base + (size_t)c * 131072;
        bf16x8 u = *reinterpret_cast<bf16x8*>(p);
        const float* dl = &dlast[((size_t)bh * NCH + c) * HDK_ + dg * 8];
        float4 e0 = *reinterpret_cast<const float4*>(dl);
        float4 e1 = *reinterpret_cast<const float4*>(dl + 4);
        float e[8] = {e0.x, e0.y, e0.z, e0.w, e1.x, e1.y, e1.z, e1.w};
        bf16x8 outv;
#pragma unroll
        for (int j = 0; j < 8; ++j) {
            outv[j] = f2bf_bits(S[j]);
            S[j] = S[j] * e[j] + bf2f(u[j]);
        }
        *reinterpret_cast<bf16x8*>(p) = outv;
    }
}

// ---------------------------------------------------------------------------
// o_pass (MFMA): o2[t][vc] (bf16) = o1[t][vc] + sum_d qg[t][d] * S'[vc][d]
// ---------------------------------------------------------------------------
__global__ __launch_bounds__(256) void o_pass(const __hip_bfloat16* __restrict__ qg,
                                              const __hip_bfloat16* __restrict__ U,
                                              const __hip_bfloat16* __restrict__ o1,
                                              __hip_bfloat16* __restrict__ o2) {
    __shared__ __align__(16) char smem[64 * 132 * 4];   // 33.8 KB
    short* Av = (short*)smem;               // 128x64 bf16 = 16 KB
    short* Bv = (short*)smem + 128 * 64;    // 64x64 bf16 = 8 KB
    float* oT = (float*)smem;               // [64 t][132] f32 (epilogue, aliases)
    const int vt = blockIdx.x, c = blockIdx.y, bh = blockIdx.z;
    const int b = bh >> 2, h = bh & 3;
    const int vc0 = vt * 128;
    const int t0 = b * 2048 + c * 64;
    const int tid = threadIdx.x;
    const int wave = tid >> 6, lane = tid & 63;
    const int wr = wave >> 1, wc = wave & 1;
    const int l15 = lane & 15, kb = lane >> 4;
    const int lr8 = lane >> 3, lc8 = (lane & 7) * 8;
    const size_t Ub = ((size_t)bh * NCH + c) * 131072;

    f32x4 acc[4][2];
#pragma unroll
    for (int mf = 0; mf < 4; ++mf)
#pragma unroll
        for (int nf = 0; nf < 2; ++nf) acc[mf][nf] = (f32x4){0.f, 0.f, 0.f, 0.f};

    for (int ks = 0; ks < 4; ++ks) {
        const int d0 = ks * 64;
#pragma unroll
        for (int j = 0; j < 4; ++j) {
            int inst = wave * 4 + j;
            int r = inst * 8 + lr8;
            gl_lds16(&U[Ub + (size_t)(vc0 + r) * 256 + d0 + lc8], &Av[inst * 512]);
        }
#pragma unroll
        for (int j = 0; j < 2; ++j) {
            int inst = wave * 2 + j;
            int r = inst * 8 + lr8;
            gl_lds16(&qg[(size_t)(t0 + r) * DKC + h * HDK_ + d0 + lc8], &Bv[inst * 512]);
        }
        __syncthreads();
#pragma unroll
        for (int kk = 0; kk < 2; ++kk) {
            bf16x8 af[4], bfr[2];
#pragma unroll
            for (int mf = 0; mf < 4; ++mf)
                af[mf] = *reinterpret_cast<const bf16x8*>(&Av[(wr * 64 + mf * 16 + l15) * 64 + kk * 32 + kb * 8]);
#pragma unroll
            for (int nf = 0; nf < 2; ++nf)
                bfr[nf] = *reinterpret_cast<const bf16x8*>(&Bv[(wc * 32 + nf * 16 + l15) * 64 + kk * 32 + kb * 8]);
#pragma unroll
            for (int mf = 0; mf < 4; ++mf)
#pragma unroll
                for (int nf = 0; nf < 2; ++nf)
                    acc[mf][nf] = __builtin_amdgcn_mfma_f32_16x16x32_bf16(af[mf], bfr[nf], acc[mf][nf], 0, 0, 0);
        }
        __syncthreads();
    }
    // acc (mf,nf,r): vc = wr*64+mf*16+kb*4+r, t = wc*32+nf*16+l15 -> oT[t][vc]
#pragma unroll
    for (int mf = 0; mf < 4; ++mf)
#pragma unroll
        for (int nf = 0; nf < 2; ++nf)
#pragma unroll
            for (int r = 0; r < 4; ++r)
                oT[(wc * 32 + nf * 16 + l15) * 132 + wr * 64 + mf * 16 + kb * 4 + r] = acc[mf][nf][r];
    __syncthreads();
#pragma unroll
    for (int j = 0; j < 4; ++j) {
        int t = (tid >> 4) + j * 16;         // 0..63
        int vc8 = (tid & 15) * 8;            // 0..120
        float4 a0 = *reinterpret_cast<const float4*>(&oT[t * 132 + vc8]);
        float4 a1 = *reinterpret_cast<const float4*>(&oT[t * 132 + vc8 + 4]);
        size_t oi = (size_t)(t0 + t) * DVC + h * HDV_ + vc0 + vc8;
        bf16x8 iv = *reinterpret_cast<const bf16x8*>(&o1[oi]);
        bf16x8 outv;
        outv[0] = f2bf_bits(a0.x + bf2f(iv[0]));
        outv[1] = f2bf_bits(a0.y + bf2f(iv[1]));
        outv[2] = f2bf_bits(a0.z + bf2f(iv[2]));
        outv[3] = f2bf_bits(a0.w + bf2f(iv[3]));
        outv[4] = f2bf_bits(a1.x + bf2f(iv[4]));
        outv[5] = f2bf_bits(a1.y + bf2f(iv[5]));
        outv[6] = f2bf_bits(a1.z + bf2f(iv[6]));
        outv[7] = f2bf_bits(a1.w + bf2f(iv[7]));
        *reinterpret_cast<bf16x8*>((__hip_bfloat16*)o2 + oi) = outv;
    }
}

// ---------------------------------------------------------------------------
// RMSNorm * rms_w * silu(xg)  (all bf16 in, bf16 out, vectorized pairs)
// ---------------------------------------------------------------------------
__global__ __launch_bounds__(256) void rms_gate(const __hip_bfloat16* __restrict__ o2,
                                                const __hip_bfloat16* __restrict__ xg,
                                                const float* __restrict__ rms_w,
                                                __hip_bfloat16* __restrict__ gated) {
    __shared__ float wsum[4];
    const int th = blockIdx.x;
    const int t = th >> 2, h = th & 3;
    const int tid = threadIdx.x;
    const size_t base = (size_t)t * DVC + h * HDV_;
    short2 ov = reinterpret_cast<const short2*>((const short*)o2 + base)[tid];
    float v0 = bf2f(ov.x), v1 = bf2f(ov.y);
    float s = v0 * v0 + v1 * v1;
#pragma unroll
    for (int off = 32; off >= 1; off >>= 1) s += __shfl_down(s, off, 64);
    if ((tid & 63) == 0) wsum[tid >> 6] = s;
    __syncthreads();
    float tot = wsum[0] + wsum[1] + wsum[2] + wsum[3];
    float rms = rsqrtf(tot * (1.f / 512.f) + 1e-5f);
    short2 gv = reinterpret_cast<const short2*>((const short*)xg + base)[tid];
    float g0 = bf2f(gv.x), g1 = bf2f(gv.y);
    float s0 = g0 / (1.f + expf(-g0));
    float s1 = g1 / (1.f + expf(-g1));
    float2 w = reinterpret_cast<const float2*>(rms_w)[tid];
    short2 outp;
    outp.x = f2bf_bits(v0 * rms * w.x * s0);
    outp.y = f2bf_bits(v1 * rms * w.y * s1);
    reinterpret_cast<short2*>((short*)gated + base)[tid] = outp;
}

// ---------------------------------------------------------------------------
extern "C" void kernel_launch(void* const* d_in, const int* in_sizes, int n_in,
                              void* d_out, int out_size, void* d_ws, size_t ws_size,
                              hipStream_t stream) {
    const float* x    = (const float*)d_in[0];
    const float* Wq   = (const float*)d_in[1];
    const float* Wk   = (const float*)d_in[2];
    const float* Wv   = (const float*)d_in[3];
    const float* Wg   = (const float*)d_in[4];
    const float* Wgk1 = (const float*)d_in[5];
    const float* Wgk2 = (const float*)d_in[6];
    const float* bgk2 = (const float*)d_in[7];
    const float* Wo   = (const float*)d_in[8];
    const float* rmsw = (const float*)d_in[9];
    float* out = (float*)d_out;
    float* ws = (float*)d_ws;

    const size_t M1 = 1ull << 20;   // floats
    // Region A [0,17M floats): dead by u_pass time; U (64MB) overlays [0,16M)
    __hip_bfloat16* xb    = (__hip_bfloat16*)ws;              // [0,2M)   8 MB
    __hip_bfloat16* WtAll = (__hip_bfloat16*)(ws + 2 * M1);   // [2M,5M)  12 MB (6144x1024)
    __hip_bfloat16* q_b   = (__hip_bfloat16*)(ws + 5 * M1);   // [5M,7M)  8 MB
    __hip_bfloat16* k_b   = (__hip_bfloat16*)(ws + 7 * M1);   // [7M,9M)  8 MB
    __hip_bfloat16* v_b   = (__hip_bfloat16*)(ws + 9 * M1);   // [9M,13M) 16 MB
    float*          g     = ws + 13 * M1;                     // [13M,17M) 16 MB
    __hip_bfloat16* U     = (__hip_bfloat16*)ws;              // [0,16M) 64 MB overlay
    __hip_bfloat16* xg_b  = (__hip_bfloat16*)(ws + 17 * M1);  // [17M,21M) 16 MB
    __hip_bfloat16* qgb   = (__hip_bfloat16*)(ws + 21 * M1);  // [21M,23M) 8 MB
    __hip_bfloat16* kgT   = (__hip_bfloat16*)(ws + 23 * M1);  // [23M,25M) 8 MB
    __hip_bfloat16* vT    = (__hip_bfloat16*)(ws + 25 * M1);  // [25M,29M) 16 MB
    __hip_bfloat16* o1    = (__hip_bfloat16*)(ws + 29 * M1);  // [29M,33M) 16 MB
    __hip_bfloat16* o2    = (__hip_bfloat16*)(ws + 33 * M1);  // [33M,37M) 16 MB
    float*          t1    = ws + 37 * M1;                     // 256 KB
    float*          dlast = ws + 37 * M1 + 65536;             // 256 KB
    // overlays after u_pass/o_pass:
    __hip_bfloat16* WtO   = (__hip_bfloat16*)(ws + 23 * M1);  // over kgT (dead after u_pass)
    __hip_bfloat16* gated = (__hip_bfloat16*)(ws + 25 * M1);  // over vT  (dead after u_pass)

    conv_bf16<<<4096, 256, 0, stream>>>(x, xb);
    convT<<<dim3(32, 32), 256, 0, stream>>>(Wq, WtAll,                    DM, DKC);
    convT<<<dim3(32, 32), 256, 0, stream>>>(Wk, WtAll + 1024 * 1024,      DM, DKC);
    convT<<<dim3(64, 32), 256, 0, stream>>>(Wv, WtAll + 2048 * 1024,      DM, DVC);
    convT<<<dim3(64, 32), 256, 0, stream>>>(Wg, WtAll + 4096 * 1024,      DM, DVC);

    gemm256<<<dim3(24, 16), 512, 0, stream>>>(xb, WtAll, q_b, k_b, v_b, xg_b);

    transpose_v<<<dim3(64, 128), 256, 0, stream>>>(v_b, vT);
    lowrank1<<<TOK, 256, 0, stream>>>(x, Wgk1, t1);
    gate_k<<<(TOK * DKC) / 256, 256, 0, stream>>>(t1, Wgk2, bgk2, g);
    gla_chunk<<<dim3(NCH, 8), 256, 0, stream>>>(q_b, k_b, vT, g, qgb, kgT, o1, dlast);

    u_pass<<<dim3(8, NCH, 8), 256, 0, stream>>>(vT, kgT, U);
    scan_pass<<<512, 256, 0, stream>>>(U, dlast);
    o_pass<<<dim3(4, NCH, 8), 256, 0, stream>>>(qgb, U, o1, o2);

    convT<<<dim3(32, 64), 256, 0, stream>>>(Wo, WtO, DVC, DM);
    rms_gate<<<TOK * NH, 256, 0, stream>>>(o2, xg_b, rmsw, gated);
    gemm_bf16<<<dim3(8, 32), 256, 0, stream>>>(gated, WtO, out, TOK, DM, DVC);
}